// Round 1
// baseline (1126.609 us; speedup 1.0000x reference)
//
#include <hip/hip_runtime.h>
#include <math.h>

#define B_DIM 2
#define C_DIM 256
#define N_TOK 4096      // 16*16*16
#define HEADS 4
#define HD 64
#define GROUPS 8
#define CPG (C_DIM / GROUPS)   // 32
#define EPS 1e-5f
#define TS 64           // tile size (M, N, K-step, and attention q/k tile)
#define PS 68           // padded LDS row stride (floats); 68*4B rows stay 16B aligned

// ---------------------------------------------------------------------------
// helpers: 4x4 register-tile FMA micro-kernels
// acc[i][j] += sum_r a[i][r] * b[r][j]   (b[r] holds row r, component j)
__device__ __forceinline__ void fma4x4(const float4 a[4], const float4 b[4], float acc[4][4]) {
#pragma unroll
    for (int i = 0; i < 4; ++i) {
        acc[i][0] += a[i].x * b[0].x + a[i].y * b[1].x + a[i].z * b[2].x + a[i].w * b[3].x;
        acc[i][1] += a[i].x * b[0].y + a[i].y * b[1].y + a[i].z * b[2].y + a[i].w * b[3].y;
        acc[i][2] += a[i].x * b[0].z + a[i].y * b[1].z + a[i].z * b[2].z + a[i].w * b[3].z;
        acc[i][3] += a[i].x * b[0].w + a[i].y * b[1].w + a[i].z * b[2].w + a[i].w * b[3].w;
    }
}
// acc[i][j] += dot(a[i], b[j])
__device__ __forceinline__ void dot4x4(const float4 a[4], const float4 b[4], float acc[4][4]) {
#pragma unroll
    for (int i = 0; i < 4; ++i)
#pragma unroll
        for (int j = 0; j < 4; ++j)
            acc[i][j] += a[i].x * b[j].x + a[i].y * b[j].y + a[i].z * b[j].z + a[i].w * b[j].w;
}

// ---------------------------------------------------------------------------
// Kernel 1: GroupNorm statistics. One block per (b, g); group data is a
// contiguous chunk of CPG*N_TOK floats. Writes mean and rstd.
__global__ __launch_bounds__(256) void gn_stats_kernel(const float* __restrict__ x,
                                                       float* __restrict__ stats) {
    const int bg = blockIdx.x;  // b*GROUPS + g
    const float4* p = (const float4*)(x + (size_t)bg * CPG * N_TOK);
    const int n4 = CPG * N_TOK / 4;  // 32768
    float s = 0.f, ss = 0.f;
    for (int i = threadIdx.x; i < n4; i += 256) {
        float4 v = p[i];
        s  += v.x + v.y + v.z + v.w;
        ss += v.x * v.x + v.y * v.y + v.z * v.z + v.w * v.w;
    }
#pragma unroll
    for (int off = 32; off > 0; off >>= 1) {
        s  += __shfl_down(s, off);
        ss += __shfl_down(ss, off);
    }
    __shared__ float ls[4], lss[4];
    const int lane = threadIdx.x & 63, wid = threadIdx.x >> 6;
    if (lane == 0) { ls[wid] = s; lss[wid] = ss; }
    __syncthreads();
    if (threadIdx.x == 0) {
        float S  = ls[0] + ls[1] + ls[2] + ls[3];
        float SS = lss[0] + lss[1] + lss[2] + lss[3];
        const float inv = 1.f / (float)(CPG * N_TOK);
        float mean = S * inv;
        float var  = SS * inv - mean * mean;
        stats[bg * 2 + 0] = mean;
        stats[bg * 2 + 1] = rsqrtf(var + EPS);
    }
}

// ---------------------------------------------------------------------------
// Kernel 2: fused GroupNorm-apply + QKV GEMM.
// qkv[o, n] = sum_c qkv_w[o, c] * xn[c, n] + qkv_b[o]  per batch.
// Output layout: qkv[(s*B + b)*HEADS + h][n][d]  (token-major, d contiguous).
__global__ __launch_bounds__(256) void qkv_gemm_kernel(
    const float* __restrict__ x, const float* __restrict__ stats,
    const float* __restrict__ norm_w, const float* __restrict__ norm_b,
    const float* __restrict__ qkv_w, const float* __restrict__ qkv_b,
    float* __restrict__ qkv) {
    __shared__ float As[TS][PS];  // [o][k]
    __shared__ float Bs[TS][PS];  // [k][n]
    const int n0 = blockIdx.x * TS;
    const int o0 = blockIdx.y * TS;
    const int b  = blockIdx.z;
    const int tx = threadIdx.x & 15, ty = threadIdx.x >> 4;
    float acc[4][4] = {};

    for (int k0 = 0; k0 < C_DIM; k0 += TS) {
#pragma unroll
        for (int r = 0; r < 4; ++r) {
            int idx = threadIdx.x + (r << 8);
            int row = idx >> 4, col = (idx & 15) << 2;
            float4 v = *(const float4*)(qkv_w + (size_t)(o0 + row) * C_DIM + k0 + col);
            *(float4*)&As[row][col] = v;
        }
#pragma unroll
        for (int r = 0; r < 4; ++r) {
            int idx = threadIdx.x + (r << 8);
            int row = idx >> 4, col = (idx & 15) << 2;
            int c = k0 + row;
            int g = c >> 5;
            float mean = stats[(b * GROUPS + g) * 2 + 0];
            float rstd = stats[(b * GROUPS + g) * 2 + 1];
            float w  = norm_w[c] * rstd;
            float bb = norm_b[c] - mean * w;
            float4 v = *(const float4*)(x + ((size_t)b * C_DIM + c) * N_TOK + n0 + col);
            float4 o;
            o.x = v.x * w + bb; o.y = v.y * w + bb; o.z = v.z * w + bb; o.w = v.w * w + bb;
            *(float4*)&Bs[row][col] = o;
        }
        __syncthreads();
#pragma unroll 4
        for (int kk = 0; kk < TS; kk += 4) {
            float4 a[4], bv[4];
#pragma unroll
            for (int i = 0; i < 4; ++i) a[i] = *(const float4*)&As[ty * 4 + i][kk];
#pragma unroll
            for (int r = 0; r < 4; ++r) bv[r] = *(const float4*)&Bs[kk + r][tx * 4];
            fma4x4(a, bv, acc);
        }
        __syncthreads();
    }

    // epilogue: this block's o-range is exactly one (s, head), d = ty*4+i
    const int sidx = o0 >> 8;
    const int head = (o0 >> 6) & 3;
    float bias[4];
#pragma unroll
    for (int i = 0; i < 4; ++i) bias[i] = qkv_b[o0 + ty * 4 + i];
    float* outbase = qkv + (((size_t)sidx * B_DIM + b) * HEADS + head) * (size_t)N_TOK * HD;
#pragma unroll
    for (int j = 0; j < 4; ++j) {
        int n = n0 + tx * 4 + j;
        float4 wv = make_float4(acc[0][j] + bias[0], acc[1][j] + bias[1],
                                acc[2][j] + bias[2], acc[3][j] + bias[3]);
        *(float4*)(outbase + (size_t)n * HD + ty * 4) = wv;
    }
}

// ---------------------------------------------------------------------------
// Kernel 3: flash-style attention, fp32. One block per (q-tile, b, head).
// q/k/v layout: [(s*B+b)*HEADS+h][n][d]. Output h layout: [b][c=head*64+d][n].
__global__ __launch_bounds__(256) void attn_kernel(const float* __restrict__ qkv,
                                                   float* __restrict__ hout) {
    const int bh = blockIdx.x & 7;            // b*HEADS + head
    const int q0 = (blockIdx.x >> 3) * TS;
    const size_t plane = (size_t)N_TOK * HD;
    const float* Q = qkv + (size_t)bh * plane;
    const float* K = qkv + (size_t)(B_DIM * HEADS + bh) * plane;
    const float* V = qkv + (size_t)(2 * B_DIM * HEADS + bh) * plane;

    __shared__ float Qs[TS][PS], Ks[TS][PS], Vs[TS][PS], Ps[TS][PS];

    const int tx = threadIdx.x & 15, ty = threadIdx.x >> 4;

#pragma unroll
    for (int r = 0; r < 4; ++r) {
        int idx = threadIdx.x + (r << 8);
        int row = idx >> 4, col = (idx & 15) << 2;
        *(float4*)&Qs[row][col] = *(const float4*)(Q + (size_t)(q0 + row) * HD + col);
    }

    float o_acc[4][4] = {};
    float m_i[4] = {-1e30f, -1e30f, -1e30f, -1e30f};
    float l_i[4] = {0.f, 0.f, 0.f, 0.f};

    __syncthreads();

    for (int kt = 0; kt < N_TOK / TS; ++kt) {
        const int k0 = kt * TS;
#pragma unroll
        for (int r = 0; r < 4; ++r) {
            int idx = threadIdx.x + (r << 8);
            int row = idx >> 4, col = (idx & 15) << 2;
            *(float4*)&Ks[row][col] = *(const float4*)(K + (size_t)(k0 + row) * HD + col);
            *(float4*)&Vs[row][col] = *(const float4*)(V + (size_t)(k0 + row) * HD + col);
        }
        __syncthreads();

        // S = (Q K^T) * scale ; thread owns q rows ty*4+i, k cols tx*4+j
        float s[4][4] = {};
#pragma unroll 4
        for (int kk = 0; kk < HD; kk += 4) {
            float4 a[4], bv[4];
#pragma unroll
            for (int i = 0; i < 4; ++i) a[i]  = *(const float4*)&Qs[ty * 4 + i][kk];
#pragma unroll
            for (int j = 0; j < 4; ++j) bv[j] = *(const float4*)&Ks[tx * 4 + j][kk];
            dot4x4(a, bv, s);
        }
#pragma unroll
        for (int i = 0; i < 4; ++i)
#pragma unroll
            for (int j = 0; j < 4; ++j) s[i][j] *= 0.125f;  // hd^-0.5

        // online softmax: rows of S are shared by the 16 threads with same ty
#pragma unroll
        for (int i = 0; i < 4; ++i) {
            float rmax = fmaxf(fmaxf(s[i][0], s[i][1]), fmaxf(s[i][2], s[i][3]));
#pragma unroll
            for (int off = 1; off < 16; off <<= 1) rmax = fmaxf(rmax, __shfl_xor(rmax, off));
            float mo = m_i[i];
            float mn = fmaxf(mo, rmax);
            float f  = __expf(mo - mn);
            float p0 = __expf(s[i][0] - mn);
            float p1 = __expf(s[i][1] - mn);
            float p2 = __expf(s[i][2] - mn);
            float p3 = __expf(s[i][3] - mn);
            Ps[ty * 4 + i][tx * 4 + 0] = p0;
            Ps[ty * 4 + i][tx * 4 + 1] = p1;
            Ps[ty * 4 + i][tx * 4 + 2] = p2;
            Ps[ty * 4 + i][tx * 4 + 3] = p3;
            float psum = p0 + p1 + p2 + p3;
#pragma unroll
            for (int off = 1; off < 16; off <<= 1) psum += __shfl_xor(psum, off);
            l_i[i] = l_i[i] * f + psum;
            m_i[i] = mn;
#pragma unroll
            for (int j = 0; j < 4; ++j) o_acc[i][j] *= f;
        }
        __syncthreads();

        // O += P @ V ; thread owns q rows ty*4+i, d cols tx*4+j
#pragma unroll 4
        for (int kk = 0; kk < TS; kk += 4) {
            float4 a[4], bv[4];
#pragma unroll
            for (int i = 0; i < 4; ++i) a[i]  = *(const float4*)&Ps[ty * 4 + i][kk];
#pragma unroll
            for (int r = 0; r < 4; ++r) bv[r] = *(const float4*)&Vs[kk + r][tx * 4];
            fma4x4(a, bv, o_acc);
        }
        __syncthreads();
    }

    // normalize and write h[b][head*64 + d][n]; i direction = consecutive n
    const int b = bh >> 2, head = bh & 3;
    float inv[4];
#pragma unroll
    for (int i = 0; i < 4; ++i) inv[i] = 1.f / l_i[i];
#pragma unroll
    for (int j = 0; j < 4; ++j) {
        int c = head * HD + tx * 4 + j;
        float4 wv = make_float4(o_acc[0][j] * inv[0], o_acc[1][j] * inv[1],
                                o_acc[2][j] * inv[2], o_acc[3][j] * inv[3]);
        *(float4*)(hout + ((size_t)b * C_DIM + c) * N_TOK + q0 + ty * 4) = wv;
    }
}

// ---------------------------------------------------------------------------
// Kernel 4: output projection + bias + residual.
__global__ __launch_bounds__(256) void proj_kernel(
    const float* __restrict__ h, const float* __restrict__ proj_w,
    const float* __restrict__ proj_b, const float* __restrict__ x,
    float* __restrict__ out) {
    __shared__ float As[TS][PS];  // [o][k]
    __shared__ float Bs[TS][PS];  // [k][n]
    const int n0 = blockIdx.x * TS;
    const int o0 = blockIdx.y * TS;
    const int b  = blockIdx.z;
    const int tx = threadIdx.x & 15, ty = threadIdx.x >> 4;
    float acc[4][4] = {};

    for (int k0 = 0; k0 < C_DIM; k0 += TS) {
#pragma unroll
        for (int r = 0; r < 4; ++r) {
            int idx = threadIdx.x + (r << 8);
            int row = idx >> 4, col = (idx & 15) << 2;
            *(float4*)&As[row][col] = *(const float4*)(proj_w + (size_t)(o0 + row) * C_DIM + k0 + col);
            *(float4*)&Bs[row][col] = *(const float4*)(h + ((size_t)b * C_DIM + k0 + row) * N_TOK + n0 + col);
        }
        __syncthreads();
#pragma unroll 4
        for (int kk = 0; kk < TS; kk += 4) {
            float4 a[4], bv[4];
#pragma unroll
            for (int i = 0; i < 4; ++i) a[i]  = *(const float4*)&As[ty * 4 + i][kk];
#pragma unroll
            for (int r = 0; r < 4; ++r) bv[r] = *(const float4*)&Bs[kk + r][tx * 4];
            fma4x4(a, bv, acc);
        }
        __syncthreads();
    }

#pragma unroll
    for (int i = 0; i < 4; ++i) {
        int o = o0 + ty * 4 + i;
        float bias = proj_b[o];
        size_t base = ((size_t)b * C_DIM + o) * N_TOK + n0 + tx * 4;
        float4 res = *(const float4*)(x + base);
        float4 wv = make_float4(acc[i][0] + bias + res.x, acc[i][1] + bias + res.y,
                                acc[i][2] + bias + res.z, acc[i][3] + bias + res.w);
        *(float4*)(out + base) = wv;
    }
}

// ---------------------------------------------------------------------------
extern "C" void kernel_launch(void* const* d_in, const int* in_sizes, int n_in,
                              void* d_out, int out_size, void* d_ws, size_t ws_size,
                              hipStream_t stream) {
    const float* x      = (const float*)d_in[0];
    const float* norm_w = (const float*)d_in[1];
    const float* norm_b = (const float*)d_in[2];
    const float* qkv_w  = (const float*)d_in[3];
    const float* qkv_b  = (const float*)d_in[4];
    const float* proj_w = (const float*)d_in[5];
    const float* proj_b = (const float*)d_in[6];
    float* out = (float*)d_out;

    // workspace layout (fp32): stats[32] | qkv[3*B*H*N*HD] | h[B*C*N]  (~33.5 MB)
    float* stats = (float*)d_ws;
    float* qkv   = stats + 32;
    float* hbuf  = qkv + (size_t)3 * B_DIM * HEADS * N_TOK * HD;

    gn_stats_kernel<<<B_DIM * GROUPS, 256, 0, stream>>>(x, stats);
    qkv_gemm_kernel<<<dim3(N_TOK / TS, 3 * C_DIM / TS, B_DIM), 256, 0, stream>>>(
        x, stats, norm_w, norm_b, qkv_w, qkv_b, qkv);
    attn_kernel<<<(N_TOK / TS) * B_DIM * HEADS, 256, 0, stream>>>(qkv, hbuf);
    proj_kernel<<<dim3(N_TOK / TS, C_DIM / TS, B_DIM), 256, 0, stream>>>(
        hbuf, proj_w, proj_b, x, out);
}

// Round 2
// 247.405 us; speedup vs baseline: 4.5537x; 4.5537x over previous
//
#include <hip/hip_runtime.h>
#include <math.h>

#define B_DIM 2
#define C_DIM 256
#define N_TOK 4096      // 16*16*16
#define HEADS 4
#define HD 64
#define GROUPS 8
#define CPG (C_DIM / GROUPS)   // 32
#define EPS 1e-5f
#define TS 64           // GEMM tile size
#define PS 68           // padded fp32 LDS row stride
#define KB 64           // attention key-tile
#define PSB 72          // padded bf16 LDS row stride (144 B, 16B-aligned rows)

typedef __bf16 bf16x8 __attribute__((ext_vector_type(8)));
typedef float  f32x4  __attribute__((ext_vector_type(4)));
typedef unsigned short u16x4v __attribute__((ext_vector_type(4)));
typedef unsigned short u16x8v __attribute__((ext_vector_type(8)));

__device__ __forceinline__ unsigned short f2bf(float f) {
    return __builtin_bit_cast(unsigned short, (__bf16)f);
}

// ---------------------------------------------------------------------------
// fp32 4x4 register-tile FMA micro-kernels (used by qkv/proj GEMMs)
__device__ __forceinline__ void fma4x4(const float4 a[4], const float4 b[4], float acc[4][4]) {
#pragma unroll
    for (int i = 0; i < 4; ++i) {
        acc[i][0] += a[i].x * b[0].x + a[i].y * b[1].x + a[i].z * b[2].x + a[i].w * b[3].x;
        acc[i][1] += a[i].x * b[0].y + a[i].y * b[1].y + a[i].z * b[2].y + a[i].w * b[3].y;
        acc[i][2] += a[i].x * b[0].z + a[i].y * b[1].z + a[i].z * b[2].z + a[i].w * b[3].z;
        acc[i][3] += a[i].x * b[0].w + a[i].y * b[1].w + a[i].z * b[2].w + a[i].w * b[3].w;
    }
}

// ---------------------------------------------------------------------------
// Kernel 1: GroupNorm statistics.
__global__ __launch_bounds__(256) void gn_stats_kernel(const float* __restrict__ x,
                                                       float* __restrict__ stats) {
    const int bg = blockIdx.x;
    const float4* p = (const float4*)(x + (size_t)bg * CPG * N_TOK);
    const int n4 = CPG * N_TOK / 4;
    float s = 0.f, ss = 0.f;
    for (int i = threadIdx.x; i < n4; i += 256) {
        float4 v = p[i];
        s  += v.x + v.y + v.z + v.w;
        ss += v.x * v.x + v.y * v.y + v.z * v.z + v.w * v.w;
    }
#pragma unroll
    for (int off = 32; off > 0; off >>= 1) {
        s  += __shfl_down(s, off);
        ss += __shfl_down(ss, off);
    }
    __shared__ float ls[4], lss[4];
    const int lane = threadIdx.x & 63, wid = threadIdx.x >> 6;
    if (lane == 0) { ls[wid] = s; lss[wid] = ss; }
    __syncthreads();
    if (threadIdx.x == 0) {
        float S  = ls[0] + ls[1] + ls[2] + ls[3];
        float SS = lss[0] + lss[1] + lss[2] + lss[3];
        const float inv = 1.f / (float)(CPG * N_TOK);
        float mean = S * inv;
        float var  = SS * inv - mean * mean;
        stats[bg * 2 + 0] = mean;
        stats[bg * 2 + 1] = rsqrtf(var + EPS);
    }
}

// ---------------------------------------------------------------------------
// Kernel 2: fused GroupNorm-apply + QKV GEMM (fp32 compute, bf16 output).
// q,k layout: [(s*B+b)*HEADS+h][n][d]  (d contiguous)
// v   layout: [b*HEADS+h][d][n]        (n contiguous — pre-transposed for PV)
__global__ __launch_bounds__(256) void qkv_gemm_kernel(
    const float* __restrict__ x, const float* __restrict__ stats,
    const float* __restrict__ norm_w, const float* __restrict__ norm_b,
    const float* __restrict__ qkv_w, const float* __restrict__ qkv_b,
    unsigned short* __restrict__ qkvb) {
    __shared__ float As[TS][PS];
    __shared__ float Bs[TS][PS];
    const int n0 = blockIdx.x * TS;
    const int o0 = blockIdx.y * TS;
    const int b  = blockIdx.z;
    const int tx = threadIdx.x & 15, ty = threadIdx.x >> 4;
    float acc[4][4] = {};

    for (int k0 = 0; k0 < C_DIM; k0 += TS) {
#pragma unroll
        for (int r = 0; r < 4; ++r) {
            int idx = threadIdx.x + (r << 8);
            int row = idx >> 4, col = (idx & 15) << 2;
            *(float4*)&As[row][col] = *(const float4*)(qkv_w + (size_t)(o0 + row) * C_DIM + k0 + col);
        }
#pragma unroll
        for (int r = 0; r < 4; ++r) {
            int idx = threadIdx.x + (r << 8);
            int row = idx >> 4, col = (idx & 15) << 2;
            int c = k0 + row;
            int g = c >> 5;
            float mean = stats[(b * GROUPS + g) * 2 + 0];
            float rstd = stats[(b * GROUPS + g) * 2 + 1];
            float w  = norm_w[c] * rstd;
            float bb = norm_b[c] - mean * w;
            float4 v = *(const float4*)(x + ((size_t)b * C_DIM + c) * N_TOK + n0 + col);
            float4 o;
            o.x = v.x * w + bb; o.y = v.y * w + bb; o.z = v.z * w + bb; o.w = v.w * w + bb;
            *(float4*)&Bs[row][col] = o;
        }
        __syncthreads();
#pragma unroll 4
        for (int kk = 0; kk < TS; kk += 4) {
            float4 a[4], bv[4];
#pragma unroll
            for (int i = 0; i < 4; ++i) a[i]  = *(const float4*)&As[ty * 4 + i][kk];
#pragma unroll
            for (int r = 0; r < 4; ++r) bv[r] = *(const float4*)&Bs[kk + r][tx * 4];
            fma4x4(a, bv, acc);
        }
        __syncthreads();
    }

    const int sidx = o0 >> 8;           // 0=q, 1=k, 2=v
    const int head = (o0 >> 6) & 3;
    float bias[4];
#pragma unroll
    for (int i = 0; i < 4; ++i) bias[i] = qkv_b[o0 + ty * 4 + i];

    if (sidx < 2) {
        unsigned short* base = qkvb + ((size_t)(sidx * B_DIM + b) * HEADS + head) * (size_t)N_TOK * HD;
#pragma unroll
        for (int j = 0; j < 4; ++j) {
            int n = n0 + tx * 4 + j;
            u16x4v w;
#pragma unroll
            for (int i = 0; i < 4; ++i) w[i] = f2bf(acc[i][j] + bias[i]);
            *(u16x4v*)(base + (size_t)n * HD + ty * 4) = w;
        }
    } else {
        unsigned short* base = qkvb + (size_t)2 * B_DIM * HEADS * N_TOK * HD
                             + ((size_t)b * HEADS + head) * (size_t)HD * N_TOK;
#pragma unroll
        for (int i = 0; i < 4; ++i) {
            int d = ty * 4 + i;
            u16x4v w;
#pragma unroll
            for (int j = 0; j < 4; ++j) w[j] = f2bf(acc[i][j] + bias[i]);
            *(u16x4v*)(base + (size_t)d * N_TOK + n0 + tx * 4) = w;
        }
    }
}

// ---------------------------------------------------------------------------
// Kernel 3: bf16 MFMA flash attention.
// Block = 64 q rows (4 waves x 16 q), iterates 64-key tiles.
// Q,K: [bh][n][d] bf16 ; V: [bh][d][n] bf16 (pre-transposed).
// Output h: [b][c=head*64+d][n] f32.
__global__ __launch_bounds__(256) void attn_kernel(const unsigned short* __restrict__ qkvb,
                                                   float* __restrict__ hout) {
    const int bh = blockIdx.x & 7;            // b*HEADS + head
    const int q0 = (blockIdx.x >> 3) * 64;
    const size_t plane = (size_t)N_TOK * HD;
    const unsigned short* Qg  = qkvb + (size_t)bh * plane;
    const unsigned short* Kg  = qkvb + (size_t)(B_DIM * HEADS + bh) * plane;
    const unsigned short* Vtg = qkvb + (size_t)2 * B_DIM * HEADS * plane + (size_t)bh * plane; // [d][n]

    __shared__ unsigned short Ks[KB][PSB];       // [key][d]
    __shared__ unsigned short Vt[HD][PSB];       // [d][key]
    __shared__ unsigned short Pl[4][16][PSB];    // per-wave P [q][key]

    const int tid  = threadIdx.x;
    const int lane = tid & 63;
    const int wid  = tid >> 6;
    const int lo   = lane & 15;
    const int hi   = lane >> 4;

    // Q fragments in registers: rows q0 + wid*16 + lo, d-chunks c*32 + hi*8
    bf16x8 qf[2];
#pragma unroll
    for (int c = 0; c < 2; ++c)
        qf[c] = *(const bf16x8*)(Qg + (size_t)(q0 + wid * 16 + lo) * HD + c * 32 + hi * 8);

    f32x4 acc_o[4] = {};   // [d-block]  -> O[q = hi*4+i][d = db*16+lo]
    float m_i[4] = {-1e30f, -1e30f, -1e30f, -1e30f};
    float l_i[4] = {0.f, 0.f, 0.f, 0.f};

    for (int kt = 0; kt < N_TOK / KB; ++kt) {
        __syncthreads();   // previous iteration's LDS reads complete
        const int k0 = kt * KB;
#pragma unroll
        for (int r = 0; r < 2; ++r) {
            int idx = tid + (r << 8);
            int row = idx >> 3, c8 = (idx & 7) << 3;
            *(u16x8v*)&Ks[row][c8] = *(const u16x8v*)(Kg + (size_t)(k0 + row) * HD + c8);
            *(u16x8v*)&Vt[row][c8] = *(const u16x8v*)(Vtg + (size_t)row * N_TOK + k0 + c8);
        }
        __syncthreads();

        // S = Q K^T : A = Q[16x32 chunk], B = K^T (keys nb*16+lo as N, d as K)
        f32x4 s4[4] = {};
#pragma unroll
        for (int nb = 0; nb < 4; ++nb)
#pragma unroll
            for (int c = 0; c < 2; ++c)
                s4[nb] = __builtin_amdgcn_mfma_f32_16x16x32_bf16(
                    qf[c], *(const bf16x8*)&Ks[nb * 16 + lo][c * 32 + hi * 8], s4[nb], 0, 0, 0);

        // online softmax per q-row i (row q = hi*4+i shared by 16 lanes w/ same hi)
        unsigned short* Pw = &Pl[wid][0][0];
        float fsc[4];
#pragma unroll
        for (int i = 0; i < 4; ++i) {
            float s0 = s4[0][i] * 0.125f, s1 = s4[1][i] * 0.125f;
            float s2 = s4[2][i] * 0.125f, s3 = s4[3][i] * 0.125f;
            float rm = fmaxf(fmaxf(s0, s1), fmaxf(s2, s3));
#pragma unroll
            for (int off = 1; off < 16; off <<= 1) rm = fmaxf(rm, __shfl_xor(rm, off));
            float mo = m_i[i];
            float mn = fmaxf(mo, rm);
            float fi = __expf(mo - mn);
            float p0 = __expf(s0 - mn), p1 = __expf(s1 - mn);
            float p2 = __expf(s2 - mn), p3 = __expf(s3 - mn);
            int row = hi * 4 + i;
            Pw[row * PSB +  0 + lo] = f2bf(p0);
            Pw[row * PSB + 16 + lo] = f2bf(p1);
            Pw[row * PSB + 32 + lo] = f2bf(p2);
            Pw[row * PSB + 48 + lo] = f2bf(p3);
            float ps = p0 + p1 + p2 + p3;
#pragma unroll
            for (int off = 1; off < 16; off <<= 1) ps += __shfl_xor(ps, off);
            l_i[i] = l_i[i] * fi + ps;
            m_i[i] = mn;
            fsc[i] = fi;
        }
#pragma unroll
        for (int db = 0; db < 4; ++db)
#pragma unroll
            for (int i = 0; i < 4; ++i) acc_o[db][i] *= fsc[i];

        // O += P V : A = P[q][k] (wave-local), B = V[k][d] read from Vt[d][k]
        const unsigned short* Pr = Pw;
        bf16x8 pf[2];
#pragma unroll
        for (int c = 0; c < 2; ++c)
            pf[c] = *(const bf16x8*)&Pr[lo * PSB + c * 32 + hi * 8];
#pragma unroll
        for (int db = 0; db < 4; ++db)
#pragma unroll
            for (int c = 0; c < 2; ++c)
                acc_o[db] = __builtin_amdgcn_mfma_f32_16x16x32_bf16(
                    pf[c], *(const bf16x8*)&Vt[db * 16 + lo][c * 32 + hi * 8], acc_o[db], 0, 0, 0);
    }

    // epilogue: O[q][d]/l -> hout[b][head*64+d][n=q]; reg i = consecutive q = contiguous n
    const int b = bh >> 2, head = bh & 3;
    float inv[4];
#pragma unroll
    for (int i = 0; i < 4; ++i) inv[i] = 1.f / l_i[i];
#pragma unroll
    for (int db = 0; db < 4; ++db) {
        float4 w = make_float4(acc_o[db][0] * inv[0], acc_o[db][1] * inv[1],
                               acc_o[db][2] * inv[2], acc_o[db][3] * inv[3]);
        *(float4*)(hout + ((size_t)b * C_DIM + head * 64 + db * 16 + lo) * N_TOK
                        + q0 + wid * 16 + hi * 4) = w;
    }
}

// ---------------------------------------------------------------------------
// Kernel 4: output projection + bias + residual (fp32).
__global__ __launch_bounds__(256) void proj_kernel(
    const float* __restrict__ h, const float* __restrict__ proj_w,
    const float* __restrict__ proj_b, const float* __restrict__ x,
    float* __restrict__ out) {
    __shared__ float As[TS][PS];
    __shared__ float Bs[TS][PS];
    const int n0 = blockIdx.x * TS;
    const int o0 = blockIdx.y * TS;
    const int b  = blockIdx.z;
    const int tx = threadIdx.x & 15, ty = threadIdx.x >> 4;
    float acc[4][4] = {};

    for (int k0 = 0; k0 < C_DIM; k0 += TS) {
#pragma unroll
        for (int r = 0; r < 4; ++r) {
            int idx = threadIdx.x + (r << 8);
            int row = idx >> 4, col = (idx & 15) << 2;
            *(float4*)&As[row][col] = *(const float4*)(proj_w + (size_t)(o0 + row) * C_DIM + k0 + col);
            *(float4*)&Bs[row][col] = *(const float4*)(h + ((size_t)b * C_DIM + k0 + row) * N_TOK + n0 + col);
        }
        __syncthreads();
#pragma unroll 4
        for (int kk = 0; kk < TS; kk += 4) {
            float4 a[4], bv[4];
#pragma unroll
            for (int i = 0; i < 4; ++i) a[i]  = *(const float4*)&As[ty * 4 + i][kk];
#pragma unroll
            for (int r = 0; r < 4; ++r) bv[r] = *(const float4*)&Bs[kk + r][tx * 4];
            fma4x4(a, bv, acc);
        }
        __syncthreads();
    }

#pragma unroll
    for (int i = 0; i < 4; ++i) {
        int o = o0 + ty * 4 + i;
        float bias = proj_b[o];
        size_t base = ((size_t)b * C_DIM + o) * N_TOK + n0 + tx * 4;
        float4 res = *(const float4*)(x + base);
        float4 wv = make_float4(acc[i][0] + bias + res.x, acc[i][1] + bias + res.y,
                                acc[i][2] + bias + res.z, acc[i][3] + bias + res.w);
        *(float4*)(out + base) = wv;
    }
}

// ---------------------------------------------------------------------------
extern "C" void kernel_launch(void* const* d_in, const int* in_sizes, int n_in,
                              void* d_out, int out_size, void* d_ws, size_t ws_size,
                              hipStream_t stream) {
    const float* x      = (const float*)d_in[0];
    const float* norm_w = (const float*)d_in[1];
    const float* norm_b = (const float*)d_in[2];
    const float* qkv_w  = (const float*)d_in[3];
    const float* qkv_b  = (const float*)d_in[4];
    const float* proj_w = (const float*)d_in[5];
    const float* proj_b = (const float*)d_in[6];
    float* out = (float*)d_out;

    // ws: stats f32[32] | qkv bf16 [3*B*H*N*HD] (~12.6MB) | h f32 [B*C*N] (8.4MB)
    float* stats = (float*)d_ws;
    unsigned short* qkvb = (unsigned short*)(stats + 32);
    float* hbuf = (float*)(qkvb + (size_t)3 * B_DIM * HEADS * N_TOK * HD);

    gn_stats_kernel<<<B_DIM * GROUPS, 256, 0, stream>>>(x, stats);
    qkv_gemm_kernel<<<dim3(N_TOK / TS, 3 * C_DIM / TS, B_DIM), 256, 0, stream>>>(
        x, stats, norm_w, norm_b, qkv_w, qkv_b, qkvb);
    attn_kernel<<<(N_TOK / KB) * B_DIM * HEADS, 256, 0, stream>>>(qkvb, hbuf);
    proj_kernel<<<dim3(N_TOK / TS, C_DIM / TS, B_DIM), 256, 0, stream>>>(
        hbuf, proj_w, proj_b, x, out);
}

// Round 3
// 160.867 us; speedup vs baseline: 7.0034x; 1.5379x over previous
//
#include <hip/hip_runtime.h>
#include <math.h>

#define B_DIM 2
#define C_DIM 256
#define N_TOK 4096      // 16*16*16
#define HEADS 4
#define HD 64
#define GROUPS 8
#define CPG (C_DIM / GROUPS)   // 32
#define EPS 1e-5f
#define PSB 72          // padded bf16 LDS row stride (144 B, 16B-aligned rows)
#define QK_SCALE 0.180336880f  // 0.125 * log2(e), folded into Q

typedef __bf16 bf16x8 __attribute__((ext_vector_type(8)));
typedef float  f32x4  __attribute__((ext_vector_type(4)));
typedef unsigned short u16x4v __attribute__((ext_vector_type(4)));
typedef unsigned short u16x8v __attribute__((ext_vector_type(8)));

__device__ __forceinline__ unsigned short f2bf(float f) {
    return __builtin_bit_cast(unsigned short, (__bf16)f);
}

// K-staging row permutation: bits [b5 b4 b3 b2 b1 b0] -> [b5 b3 b2 b4 b1 b0].
// Makes the S^T output registers exactly the PV B-fragment (see derivation).
__device__ __forceinline__ int kperm(int r) {
    return (r & 0x23) | ((r & 0x0C) << 1) | ((r & 0x10) >> 2);
}

// ---------------------------------------------------------------------------
// Kernel 1: GroupNorm statistics.
__global__ __launch_bounds__(256) void gn_stats_kernel(const float* __restrict__ x,
                                                       float* __restrict__ stats) {
    const int bg = blockIdx.x;
    const float4* p = (const float4*)(x + (size_t)bg * CPG * N_TOK);
    const int n4 = CPG * N_TOK / 4;
    float s = 0.f, ss = 0.f;
    for (int i = threadIdx.x; i < n4; i += 256) {
        float4 v = p[i];
        s  += v.x + v.y + v.z + v.w;
        ss += v.x * v.x + v.y * v.y + v.z * v.z + v.w * v.w;
    }
#pragma unroll
    for (int off = 32; off > 0; off >>= 1) {
        s  += __shfl_down(s, off);
        ss += __shfl_down(ss, off);
    }
    __shared__ float ls[4], lss[4];
    const int lane = threadIdx.x & 63, wid = threadIdx.x >> 6;
    if (lane == 0) { ls[wid] = s; lss[wid] = ss; }
    __syncthreads();
    if (threadIdx.x == 0) {
        float S  = ls[0] + ls[1] + ls[2] + ls[3];
        float SS = lss[0] + lss[1] + lss[2] + lss[3];
        const float inv = 1.f / (float)(CPG * N_TOK);
        float mean = S * inv;
        float var  = SS * inv - mean * mean;
        stats[bg * 2 + 0] = mean;
        stats[bg * 2 + 1] = rsqrtf(var + EPS);
    }
}

// ---------------------------------------------------------------------------
// Kernel 2: fused GroupNorm-apply + QKV GEMM, bf16 MFMA.
// q,k out: [(s*B+b)*HEADS+h][n][d] bf16 (q pre-scaled by QK_SCALE)
// v   out: [b*HEADS+h][d][n] bf16
__global__ __launch_bounds__(256) void qkv_gemm_kernel(
    const float* __restrict__ x, const float* __restrict__ stats,
    const float* __restrict__ norm_w, const float* __restrict__ norm_b,
    const float* __restrict__ qkv_w, const float* __restrict__ qkv_b,
    unsigned short* __restrict__ qkvb) {
    __shared__ unsigned short Ws[64][PSB];  // [o][c] bf16
    __shared__ unsigned short Xt[64][PSB];  // [n][c] bf16 (transposed xn)
    const int n0 = blockIdx.x * 64;
    const int o0 = blockIdx.y * 64;
    const int b  = blockIdx.z;
    const int tid = threadIdx.x;
    const int lane = tid & 63, w = tid >> 6;
    const int lo = lane & 15, hi = lane >> 4;
    f32x4 acc[4] = {};

    for (int k0 = 0; k0 < C_DIM; k0 += 64) {
#pragma unroll
        for (int r = 0; r < 4; ++r) {
            int idx = tid + (r << 8);
            int row = idx >> 4, col4 = (idx & 15) << 2;
            float4 wv = *(const float4*)(qkv_w + (size_t)(o0 + row) * C_DIM + k0 + col4);
            u16x4v o;
            o[0] = f2bf(wv.x); o[1] = f2bf(wv.y); o[2] = f2bf(wv.z); o[3] = f2bf(wv.w);
            *(u16x4v*)&Ws[row][col4] = o;
        }
#pragma unroll
        for (int r = 0; r < 4; ++r) {
            int idx = tid + (r << 8);
            int crow = idx >> 4, col4 = (idx & 15) << 2;
            int c = k0 + crow;
            int g = c >> 5;
            float mean = stats[(b * GROUPS + g) * 2 + 0];
            float rstd = stats[(b * GROUPS + g) * 2 + 1];
            float ww = norm_w[c] * rstd;
            float bb = norm_b[c] - mean * ww;
            float4 v = *(const float4*)(x + ((size_t)b * C_DIM + c) * N_TOK + n0 + col4);
            Xt[col4 + 0][crow] = f2bf(v.x * ww + bb);
            Xt[col4 + 1][crow] = f2bf(v.y * ww + bb);
            Xt[col4 + 2][crow] = f2bf(v.z * ww + bb);
            Xt[col4 + 3][crow] = f2bf(v.w * ww + bb);
        }
        __syncthreads();
#pragma unroll
        for (int ck = 0; ck < 2; ++ck) {
            bf16x8 aw = *(const bf16x8*)&Ws[w * 16 + lo][ck * 32 + hi * 8];
#pragma unroll
            for (int nb = 0; nb < 4; ++nb)
                acc[nb] = __builtin_amdgcn_mfma_f32_16x16x32_bf16(
                    aw, *(const bf16x8*)&Xt[nb * 16 + lo][ck * 32 + hi * 8], acc[nb], 0, 0, 0);
        }
        __syncthreads();
    }

    // epilogue: o = o0 + w*16 + hi*4 + i (i=acc reg), n = n0 + nb*16 + lo
    const int sidx = o0 >> 8;           // 0=q, 1=k, 2=v
    const int head = (o0 >> 6) & 3;
    const int od = w * 16 + hi * 4;     // d within head (+i)
    float bias[4];
#pragma unroll
    for (int i = 0; i < 4; ++i) bias[i] = qkv_b[o0 + od + i];
    const size_t plane = (size_t)N_TOK * HD;

    if (sidx < 2) {
        const float sc = (sidx == 0) ? QK_SCALE : 1.0f;
        unsigned short* base = qkvb + ((size_t)(sidx * B_DIM + b) * HEADS + head) * plane;
#pragma unroll
        for (int nb = 0; nb < 4; ++nb) {
            int n = n0 + nb * 16 + lo;
            u16x4v o;
#pragma unroll
            for (int i = 0; i < 4; ++i) o[i] = f2bf((acc[nb][i] + bias[i]) * sc);
            *(u16x4v*)(base + (size_t)n * HD + od) = o;
        }
    } else {
        unsigned short* base = qkvb + (size_t)2 * B_DIM * HEADS * plane
                             + ((size_t)b * HEADS + head) * plane;
#pragma unroll
        for (int nb = 0; nb < 4; ++nb)
#pragma unroll
            for (int i = 0; i < 4; ++i)
                base[(size_t)(od + i) * N_TOK + n0 + nb * 16 + lo] = f2bf(acc[nb][i] + bias[i]);
    }
}

// ---------------------------------------------------------------------------
// Kernel 3: bf16 MFMA flash attention, swapped-operand (S^T) form.
// P stays in registers (permuted-K staging). Double-buffered K/V staging.
// Output hT: [b][n][c] bf16.
__global__ __launch_bounds__(256) void attn_kernel(const unsigned short* __restrict__ qkvb,
                                                   unsigned short* __restrict__ hT) {
    const int bh = blockIdx.x & 7;            // b*HEADS + head
    const int q0 = (blockIdx.x >> 3) * 64;
    const size_t plane = (size_t)N_TOK * HD;
    const unsigned short* Qg  = qkvb + (size_t)bh * plane;
    const unsigned short* Kg  = qkvb + (size_t)(B_DIM * HEADS + bh) * plane;
    const unsigned short* Vtg = qkvb + (size_t)2 * B_DIM * HEADS * plane + (size_t)bh * plane;

    __shared__ unsigned short Ks[2][64][PSB];  // [buf][perm key row][d]
    __shared__ unsigned short Vt[2][64][PSB];  // [buf][d][key]

    const int tid  = threadIdx.x;
    const int lane = tid & 63;
    const int wid  = tid >> 6;
    const int lo   = lane & 15;
    const int hi   = lane >> 4;

    // Q fragment (B-operand of S^T mfma): q = q0+wid*16+lo, d-chunks c*32+hi*8
    bf16x8 qf[2];
#pragma unroll
    for (int c = 0; c < 2; ++c)
        qf[c] = *(const bf16x8*)(Qg + (size_t)(q0 + wid * 16 + lo) * HD + c * 32 + hi * 8);

    // staging addressing: idx = tid + r*256; row = idx>>3, blk = idx&7
    const int srow = tid >> 3, sblk = tid & 7;

    f32x4 acc[4] = {};   // acc[db][i] = O^T[d = db*16+hi*4+i][q = q0+wid*16+lo]
    float m = -1e30f, l = 0.f;

    u16x8v kreg[2], vreg[2];
    // prologue: stage tile 0
#pragma unroll
    for (int r = 0; r < 2; ++r) {
        int row = srow + r * 32;
        kreg[r] = *(const u16x8v*)(Kg + (size_t)kperm(row) * HD + sblk * 8);
        vreg[r] = *(const u16x8v*)(Vtg + (size_t)row * N_TOK + sblk * 8);
    }
#pragma unroll
    for (int r = 0; r < 2; ++r) {
        int row = srow + r * 32;
        *(u16x8v*)&Ks[0][row][sblk * 8] = kreg[r];
        *(u16x8v*)&Vt[0][row][sblk * 8] = vreg[r];
    }
    __syncthreads();

    for (int kt = 0; kt < N_TOK / 64; ++kt) {
        const int cur = kt & 1;
        if (kt + 1 < N_TOK / 64) {
            const int k1 = (kt + 1) * 64;
#pragma unroll
            for (int r = 0; r < 2; ++r) {
                int row = srow + r * 32;
                kreg[r] = *(const u16x8v*)(Kg + (size_t)(k1 + kperm(row)) * HD + sblk * 8);
                vreg[r] = *(const u16x8v*)(Vtg + (size_t)row * N_TOK + k1 + sblk * 8);
            }
        }

        // S^T = K Q^T : A = K rows (perm), B = Q^T (qf). s4[kb][i] = S^T[kb*16+hi*4+i][lo]
        f32x4 s4[4] = {};
#pragma unroll
        for (int kb = 0; kb < 4; ++kb)
#pragma unroll
            for (int c = 0; c < 2; ++c)
                s4[kb] = __builtin_amdgcn_mfma_f32_16x16x32_bf16(
                    *(const bf16x8*)&Ks[cur][kb * 16 + lo][c * 32 + hi * 8], qf[c], s4[kb], 0, 0, 0);

        // softmax (log2 domain, scale pre-folded into Q). All 16 values = query lo.
        float rm = s4[0][0];
#pragma unroll
        for (int kb = 0; kb < 4; ++kb)
#pragma unroll
            for (int i = 0; i < 4; ++i) rm = fmaxf(rm, s4[kb][i]);
        rm = fmaxf(rm, __shfl_xor(rm, 16));
        rm = fmaxf(rm, __shfl_xor(rm, 32));
        const float mn = fmaxf(m, rm);
        const float fi = exp2f(m - mn);
        float p[4][4];
        float ps = 0.f;
#pragma unroll
        for (int kb = 0; kb < 4; ++kb)
#pragma unroll
            for (int i = 0; i < 4; ++i) {
                p[kb][i] = exp2f(s4[kb][i] - mn);
                ps += p[kb][i];
            }
        m = mn;
        l = l * fi + ps;   // lane-partial l (over this lane's 16 keys); reduced at end
#pragma unroll
        for (int db = 0; db < 4; ++db)
#pragma unroll
            for (int i = 0; i < 4; ++i) acc[db][i] *= fi;

        // pack P into PV B-fragment: pf[c][j] = p[2c + (j>>2)][j&3]
        bf16x8 pf[2];
#pragma unroll
        for (int c = 0; c < 2; ++c)
#pragma unroll
            for (int j = 0; j < 8; ++j) pf[c][j] = (__bf16)p[2 * c + (j >> 2)][j & 3];

        // O^T += V^T P^T : A = V^T (from Vt), B = pf
#pragma unroll
        for (int db = 0; db < 4; ++db)
#pragma unroll
            for (int c = 0; c < 2; ++c)
                acc[db] = __builtin_amdgcn_mfma_f32_16x16x32_bf16(
                    *(const bf16x8*)&Vt[cur][db * 16 + lo][c * 32 + hi * 8], pf[c], acc[db], 0, 0, 0);

        __syncthreads();
        if (kt + 1 < N_TOK / 64) {
            const int nxt = cur ^ 1;
#pragma unroll
            for (int r = 0; r < 2; ++r) {
                int row = srow + r * 32;
                *(u16x8v*)&Ks[nxt][row][sblk * 8] = kreg[r];
                *(u16x8v*)&Vt[nxt][row][sblk * 8] = vreg[r];
            }
            __syncthreads();
        }
    }

    // epilogue: reduce l across the 4 hi-lanes sharing query lo, write hT[b][n][c] bf16
    float l1 = l + __shfl_xor(l, 16);
    float lt = l1 + __shfl_xor(l1, 32);
    const float inv = 1.f / lt;
    const int b = bh >> 2, head = bh & 3;
    const int n = q0 + wid * 16 + lo;
    unsigned short* base = hT + ((size_t)b * N_TOK + n) * C_DIM + head * HD;
#pragma unroll
    for (int db = 0; db < 4; ++db) {
        u16x4v o;
#pragma unroll
        for (int i = 0; i < 4; ++i) o[i] = f2bf(acc[db][i] * inv);
        *(u16x4v*)(base + db * 16 + hi * 4) = o;
    }
}

// ---------------------------------------------------------------------------
// Kernel 4: output projection + bias + residual, bf16 MFMA.
// h input: hT [b][n][c] bf16 (no transpose staging needed).
__global__ __launch_bounds__(256) void proj_kernel(
    const unsigned short* __restrict__ hT, const float* __restrict__ proj_w,
    const float* __restrict__ proj_b, const float* __restrict__ x,
    float* __restrict__ out) {
    __shared__ unsigned short Ws[64][PSB];  // [o][c]
    __shared__ unsigned short Hs[64][PSB];  // [n][c]
    const int n0 = blockIdx.x * 64;
    const int o0 = blockIdx.y * 64;
    const int b  = blockIdx.z;
    const int tid = threadIdx.x;
    const int lane = tid & 63, w = tid >> 6;
    const int lo = lane & 15, hi = lane >> 4;
    f32x4 acc[4] = {};

    for (int k0 = 0; k0 < C_DIM; k0 += 64) {
#pragma unroll
        for (int r = 0; r < 4; ++r) {
            int idx = tid + (r << 8);
            int row = idx >> 4, col4 = (idx & 15) << 2;
            float4 wv = *(const float4*)(proj_w + (size_t)(o0 + row) * C_DIM + k0 + col4);
            u16x4v o;
            o[0] = f2bf(wv.x); o[1] = f2bf(wv.y); o[2] = f2bf(wv.z); o[3] = f2bf(wv.w);
            *(u16x4v*)&Ws[row][col4] = o;
        }
#pragma unroll
        for (int r = 0; r < 2; ++r) {
            int idx = tid + (r << 8);
            int row = idx >> 3, blk = idx & 7;
            *(u16x8v*)&Hs[row][blk * 8] =
                *(const u16x8v*)(hT + ((size_t)b * N_TOK + n0 + row) * C_DIM + k0 + blk * 8);
        }
        __syncthreads();
#pragma unroll
        for (int ck = 0; ck < 2; ++ck) {
            bf16x8 aw = *(const bf16x8*)&Ws[w * 16 + lo][ck * 32 + hi * 8];
#pragma unroll
            for (int nb = 0; nb < 4; ++nb)
                acc[nb] = __builtin_amdgcn_mfma_f32_16x16x32_bf16(
                    aw, *(const bf16x8*)&Hs[nb * 16 + lo][ck * 32 + hi * 8], acc[nb], 0, 0, 0);
        }
        __syncthreads();
    }

#pragma unroll
    for (int nb = 0; nb < 4; ++nb) {
#pragma unroll
        for (int i = 0; i < 4; ++i) {
            int o = o0 + w * 16 + hi * 4 + i;
            size_t addr = ((size_t)b * C_DIM + o) * N_TOK + n0 + nb * 16 + lo;
            out[addr] = acc[nb][i] + proj_b[o] + x[addr];
        }
    }
}

// ---------------------------------------------------------------------------
extern "C" void kernel_launch(void* const* d_in, const int* in_sizes, int n_in,
                              void* d_out, int out_size, void* d_ws, size_t ws_size,
                              hipStream_t stream) {
    const float* x      = (const float*)d_in[0];
    const float* norm_w = (const float*)d_in[1];
    const float* norm_b = (const float*)d_in[2];
    const float* qkv_w  = (const float*)d_in[3];
    const float* qkv_b  = (const float*)d_in[4];
    const float* proj_w = (const float*)d_in[5];
    const float* proj_b = (const float*)d_in[6];
    float* out = (float*)d_out;

    // ws: stats f32[32] | qkv bf16 [3*B*H*N*HD] (12.6MB) | hT bf16 [B*N*C] (4.2MB)
    float* stats = (float*)d_ws;
    unsigned short* qkvb = (unsigned short*)(stats + 32);
    unsigned short* hT = qkvb + (size_t)3 * B_DIM * HEADS * N_TOK * HD;

    gn_stats_kernel<<<B_DIM * GROUPS, 256, 0, stream>>>(x, stats);
    qkv_gemm_kernel<<<dim3(N_TOK / 64, 3 * C_DIM / 64, B_DIM), 256, 0, stream>>>(
        x, stats, norm_w, norm_b, qkv_w, qkv_b, qkvb);
    attn_kernel<<<(N_TOK / 64) * B_DIM * HEADS, 256, 0, stream>>>(qkvb, hT);
    proj_kernel<<<dim3(N_TOK / 64, C_DIM / 64, B_DIM), 256, 0, stream>>>(
        hT, proj_w, proj_b, x, out);
}

// Round 4
// 154.855 us; speedup vs baseline: 7.2753x; 1.0388x over previous
//
#include <hip/hip_runtime.h>
#include <math.h>

#define B_DIM 2
#define C_DIM 256
#define N_TOK 4096      // 16*16*16
#define HEADS 4
#define HD 64
#define GROUPS 8
#define CPG (C_DIM / GROUPS)   // 32
#define EPS 1e-5f
#define PSB 72          // padded bf16 LDS row stride (144 B, 16B-aligned rows)
#define QK_SCALE 0.180336880f  // 0.125 * log2(e), folded into Q
#define KSPLIT 2
#define NKT (N_TOK / 64)       // 64 key tiles total

typedef __bf16 bf16x8 __attribute__((ext_vector_type(8)));
typedef float  f32x4  __attribute__((ext_vector_type(4)));
typedef unsigned short u16x4v __attribute__((ext_vector_type(4)));
typedef unsigned short u16x8v __attribute__((ext_vector_type(8)));

__device__ __forceinline__ unsigned short f2bf(float f) {
    return __builtin_bit_cast(unsigned short, (__bf16)f);
}
__device__ __forceinline__ float bf2f(unsigned short u) {
    return (float)__builtin_bit_cast(__bf16, u);
}

// K-staging row permutation: bits [b5 b4 b3 b2 b1 b0] -> [b5 b3 b2 b4 b1 b0].
// Makes the S^T output registers exactly the PV B-fragment.
__device__ __forceinline__ int kperm(int r) {
    return (r & 0x23) | ((r & 0x0C) << 1) | ((r & 0x10) >> 2);
}

// ---------------------------------------------------------------------------
// Kernel 1: GroupNorm statistics.
__global__ __launch_bounds__(256) void gn_stats_kernel(const float* __restrict__ x,
                                                       float* __restrict__ stats) {
    const int bg = blockIdx.x;
    const float4* p = (const float4*)(x + (size_t)bg * CPG * N_TOK);
    const int n4 = CPG * N_TOK / 4;
    float s = 0.f, ss = 0.f;
    for (int i = threadIdx.x; i < n4; i += 256) {
        float4 v = p[i];
        s  += v.x + v.y + v.z + v.w;
        ss += v.x * v.x + v.y * v.y + v.z * v.z + v.w * v.w;
    }
#pragma unroll
    for (int off = 32; off > 0; off >>= 1) {
        s  += __shfl_down(s, off);
        ss += __shfl_down(ss, off);
    }
    __shared__ float ls[4], lss[4];
    const int lane = threadIdx.x & 63, wid = threadIdx.x >> 6;
    if (lane == 0) { ls[wid] = s; lss[wid] = ss; }
    __syncthreads();
    if (threadIdx.x == 0) {
        float S  = ls[0] + ls[1] + ls[2] + ls[3];
        float SS = lss[0] + lss[1] + lss[2] + lss[3];
        const float inv = 1.f / (float)(CPG * N_TOK);
        float mean = S * inv;
        float var  = SS * inv - mean * mean;
        stats[bg * 2 + 0] = mean;
        stats[bg * 2 + 1] = rsqrtf(var + EPS);
    }
}

// ---------------------------------------------------------------------------
// Kernel 2: fused GroupNorm-apply + QKV GEMM, bf16 MFMA.
// q,k out: [(s*B+b)*HEADS+h][n][d] bf16 (q pre-scaled by QK_SCALE)
// v   out: [b*HEADS+h][d][n] bf16
__global__ __launch_bounds__(256) void qkv_gemm_kernel(
    const float* __restrict__ x, const float* __restrict__ stats,
    const float* __restrict__ norm_w, const float* __restrict__ norm_b,
    const float* __restrict__ qkv_w, const float* __restrict__ qkv_b,
    unsigned short* __restrict__ qkvb) {
    __shared__ unsigned short Ws[64][PSB];  // [o][c] bf16
    __shared__ unsigned short Xt[64][PSB];  // [n][c] bf16 (transposed xn)
    const int n0 = blockIdx.x * 64;
    const int o0 = blockIdx.y * 64;
    const int b  = blockIdx.z;
    const int tid = threadIdx.x;
    const int lane = tid & 63, w = tid >> 6;
    const int lo = lane & 15, hi = lane >> 4;
    f32x4 acc[4] = {};

    for (int k0 = 0; k0 < C_DIM; k0 += 64) {
#pragma unroll
        for (int r = 0; r < 4; ++r) {
            int idx = tid + (r << 8);
            int row = idx >> 4, col4 = (idx & 15) << 2;
            float4 wv = *(const float4*)(qkv_w + (size_t)(o0 + row) * C_DIM + k0 + col4);
            u16x4v o;
            o[0] = f2bf(wv.x); o[1] = f2bf(wv.y); o[2] = f2bf(wv.z); o[3] = f2bf(wv.w);
            *(u16x4v*)&Ws[row][col4] = o;
        }
#pragma unroll
        for (int r = 0; r < 4; ++r) {
            int idx = tid + (r << 8);
            int crow = idx >> 4, col4 = (idx & 15) << 2;
            int c = k0 + crow;
            int g = c >> 5;
            float mean = stats[(b * GROUPS + g) * 2 + 0];
            float rstd = stats[(b * GROUPS + g) * 2 + 1];
            float ww = norm_w[c] * rstd;
            float bb = norm_b[c] - mean * ww;
            float4 v = *(const float4*)(x + ((size_t)b * C_DIM + c) * N_TOK + n0 + col4);
            Xt[col4 + 0][crow] = f2bf(v.x * ww + bb);
            Xt[col4 + 1][crow] = f2bf(v.y * ww + bb);
            Xt[col4 + 2][crow] = f2bf(v.z * ww + bb);
            Xt[col4 + 3][crow] = f2bf(v.w * ww + bb);
        }
        __syncthreads();
#pragma unroll
        for (int ck = 0; ck < 2; ++ck) {
            bf16x8 aw = *(const bf16x8*)&Ws[w * 16 + lo][ck * 32 + hi * 8];
#pragma unroll
            for (int nb = 0; nb < 4; ++nb)
                acc[nb] = __builtin_amdgcn_mfma_f32_16x16x32_bf16(
                    aw, *(const bf16x8*)&Xt[nb * 16 + lo][ck * 32 + hi * 8], acc[nb], 0, 0, 0);
        }
        __syncthreads();
    }

    const int sidx = o0 >> 8;           // 0=q, 1=k, 2=v
    const int head = (o0 >> 6) & 3;
    const int od = w * 16 + hi * 4;     // d within head (+i)
    float bias[4];
#pragma unroll
    for (int i = 0; i < 4; ++i) bias[i] = qkv_b[o0 + od + i];
    const size_t plane = (size_t)N_TOK * HD;

    if (sidx < 2) {
        const float sc = (sidx == 0) ? QK_SCALE : 1.0f;
        unsigned short* base = qkvb + ((size_t)(sidx * B_DIM + b) * HEADS + head) * plane;
#pragma unroll
        for (int nb = 0; nb < 4; ++nb) {
            int n = n0 + nb * 16 + lo;
            u16x4v o;
#pragma unroll
            for (int i = 0; i < 4; ++i) o[i] = f2bf((acc[nb][i] + bias[i]) * sc);
            *(u16x4v*)(base + (size_t)n * HD + od) = o;
        }
    } else {
        unsigned short* base = qkvb + (size_t)2 * B_DIM * HEADS * plane
                             + ((size_t)b * HEADS + head) * plane;
#pragma unroll
        for (int nb = 0; nb < 4; ++nb)
#pragma unroll
            for (int i = 0; i < 4; ++i)
                base[(size_t)(od + i) * N_TOK + n0 + nb * 16 + lo] = f2bf(acc[nb][i] + bias[i]);
    }
}

// ---------------------------------------------------------------------------
// Kernel 3: bf16 MFMA flash attention, swapped-operand (S^T), K-split x2.
// blockIdx.x = qt*16 + bh*2 + ks  (low 4 bits = (bh,ks) -> XCD L2 locality).
// Writes normalized bf16 partial O + per-query log-sum-exp r.
__global__ __launch_bounds__(256) void attn_kernel(const unsigned short* __restrict__ qkvb,
                                                   unsigned short* __restrict__ obuf,
                                                   float* __restrict__ rbuf) {
    const int bhks = blockIdx.x & 15;
    const int bh = bhks >> 1;                 // b*HEADS + head
    const int ks = bhks & 1;                  // key-split half
    const int q0 = (blockIdx.x >> 4) * 64;
    const size_t plane = (size_t)N_TOK * HD;
    const unsigned short* Qg  = qkvb + (size_t)bh * plane;
    const unsigned short* Kg  = qkvb + (size_t)(B_DIM * HEADS + bh) * plane;
    const unsigned short* Vtg = qkvb + (size_t)2 * B_DIM * HEADS * plane + (size_t)bh * plane;

    __shared__ unsigned short Ks[2][64][PSB];  // [buf][perm key row][d]
    __shared__ unsigned short Vt[2][64][PSB];  // [buf][d][key]

    const int tid  = threadIdx.x;
    const int lane = tid & 63;
    const int wid  = tid >> 6;
    const int lo   = lane & 15;
    const int hi   = lane >> 4;

    // Q fragment (B-operand of S^T mfma): q = q0+wid*16+lo, d-chunks c*32+hi*8
    bf16x8 qf[2];
#pragma unroll
    for (int c = 0; c < 2; ++c)
        qf[c] = *(const bf16x8*)(Qg + (size_t)(q0 + wid * 16 + lo) * HD + c * 32 + hi * 8);

    const int srow = tid >> 3, sblk = tid & 7;
    const int kt0 = ks * (NKT / KSPLIT), ktE = kt0 + NKT / KSPLIT;

    f32x4 acc[4] = {};   // acc[db][i] = O^T[d = db*16+hi*4+i][q = q0+wid*16+lo]
    float m = -1e30f, l = 0.f;

    u16x8v kreg[2], vreg[2];
#pragma unroll
    for (int r = 0; r < 2; ++r) {
        int row = srow + r * 32;
        kreg[r] = *(const u16x8v*)(Kg + (size_t)(kt0 * 64 + kperm(row)) * HD + sblk * 8);
        vreg[r] = *(const u16x8v*)(Vtg + (size_t)row * N_TOK + kt0 * 64 + sblk * 8);
    }
#pragma unroll
    for (int r = 0; r < 2; ++r) {
        int row = srow + r * 32;
        *(u16x8v*)&Ks[0][row][sblk * 8] = kreg[r];
        *(u16x8v*)&Vt[0][row][sblk * 8] = vreg[r];
    }
    __syncthreads();

    for (int kt = kt0; kt < ktE; ++kt) {
        const int cur = kt & 1;
        if (kt + 1 < ktE) {
            const int k1 = (kt + 1) * 64;
#pragma unroll
            for (int r = 0; r < 2; ++r) {
                int row = srow + r * 32;
                kreg[r] = *(const u16x8v*)(Kg + (size_t)(k1 + kperm(row)) * HD + sblk * 8);
                vreg[r] = *(const u16x8v*)(Vtg + (size_t)row * N_TOK + k1 + sblk * 8);
            }
        }

        // S^T = K Q^T. s4[kb][i] = S^T[key = kb*16+hi*4+i][query lo]
        f32x4 s4[4] = {};
#pragma unroll
        for (int kb = 0; kb < 4; ++kb)
#pragma unroll
            for (int c = 0; c < 2; ++c)
                s4[kb] = __builtin_amdgcn_mfma_f32_16x16x32_bf16(
                    *(const bf16x8*)&Ks[cur][kb * 16 + lo][c * 32 + hi * 8], qf[c], s4[kb], 0, 0, 0);

        // tile max for query lo (reduce 16 regs, then across hi groups)
        float r0 = fmaxf(fmaxf(s4[0][0], s4[0][1]), fmaxf(s4[0][2], s4[0][3]));
        float r1 = fmaxf(fmaxf(s4[1][0], s4[1][1]), fmaxf(s4[1][2], s4[1][3]));
        float r2 = fmaxf(fmaxf(s4[2][0], s4[2][1]), fmaxf(s4[2][2], s4[2][3]));
        float r3 = fmaxf(fmaxf(s4[3][0], s4[3][1]), fmaxf(s4[3][2], s4[3][3]));
        float rm = fmaxf(fmaxf(r0, r1), fmaxf(r2, r3));
        rm = fmaxf(rm, __shfl_xor(rm, 16));
        rm = fmaxf(rm, __shfl_xor(rm, 32));

        // defer-max (T13): only rescale when the running max grew by > 8 (log2)
        if (__any(rm > m + 8.0f)) {
            const float mn = fmaxf(m, rm);
            const float fi = exp2f(m - mn);
            m = mn;
            l *= fi;
#pragma unroll
            for (int db = 0; db < 4; ++db)
#pragma unroll
                for (int i = 0; i < 4; ++i) acc[db][i] *= fi;
        }

        float p[4][4];
        float ps = 0.f;
#pragma unroll
        for (int kb = 0; kb < 4; ++kb)
#pragma unroll
            for (int i = 0; i < 4; ++i) {
                p[kb][i] = exp2f(s4[kb][i] - m);
                ps += p[kb][i];
            }
        l += ps;

        // pack P into PV B-fragment: pf[c][j] = p[2c + (j>>2)][j&3]
        bf16x8 pf[2];
#pragma unroll
        for (int c = 0; c < 2; ++c)
#pragma unroll
            for (int j = 0; j < 8; ++j) pf[c][j] = (__bf16)p[2 * c + (j >> 2)][j & 3];

        // O^T += V^T P^T
#pragma unroll
        for (int db = 0; db < 4; ++db)
#pragma unroll
            for (int c = 0; c < 2; ++c)
                acc[db] = __builtin_amdgcn_mfma_f32_16x16x32_bf16(
                    *(const bf16x8*)&Vt[cur][db * 16 + lo][c * 32 + hi * 8], pf[c], acc[db], 0, 0, 0);

        __syncthreads();
        if (kt + 1 < ktE) {
            const int nxt = cur ^ 1;
#pragma unroll
            for (int r = 0; r < 2; ++r) {
                int row = srow + r * 32;
                *(u16x8v*)&Ks[nxt][row][sblk * 8] = kreg[r];
                *(u16x8v*)&Vt[nxt][row][sblk * 8] = vreg[r];
            }
            __syncthreads();
        }
    }

    // epilogue: normalized bf16 partial O + log-sum-exp r
    float l1 = l + __shfl_xor(l, 16);
    float lt = l1 + __shfl_xor(l1, 32);
    const float inv = 1.f / lt;
    const int n = q0 + wid * 16 + lo;
    unsigned short* ob = obuf + ((size_t)(ks * 8 + bh) * N_TOK + n) * HD;
#pragma unroll
    for (int db = 0; db < 4; ++db) {
        u16x4v o;
#pragma unroll
        for (int i = 0; i < 4; ++i) o[i] = f2bf(acc[db][i] * inv);
        *(u16x4v*)(ob + db * 16 + hi * 4) = o;
    }
    if (hi == 0)
        rbuf[(size_t)(ks * 8 + bh) * N_TOK + n] = m + log2f(lt);
}

// ---------------------------------------------------------------------------
// Kernel 3b: combine the two K-split halves -> hT [b][n][c] bf16.
__global__ __launch_bounds__(256) void attn_combine_kernel(
    const unsigned short* __restrict__ obuf, const float* __restrict__ rbuf,
    unsigned short* __restrict__ hT) {
    const int idx = blockIdx.x * 256 + threadIdx.x;  // bh*N_TOK + n
    const int bh = idx >> 12, n = idx & (N_TOK - 1);
    const float ra = rbuf[(size_t)bh * N_TOK + n];
    const float rb = rbuf[(size_t)(8 + bh) * N_TOK + n];
    const float M = fmaxf(ra, rb);
    float wa = exp2f(ra - M), wb = exp2f(rb - M);
    const float inv = 1.f / (wa + wb);
    wa *= inv; wb *= inv;
    const unsigned short* oa = obuf + ((size_t)bh * N_TOK + n) * HD;
    const unsigned short* ob = obuf + ((size_t)(8 + bh) * N_TOK + n) * HD;
    const int b = bh >> 2, head = bh & 3;
    unsigned short* dst = hT + ((size_t)b * N_TOK + n) * C_DIM + head * HD;
#pragma unroll
    for (int d = 0; d < HD; d += 8) {
        u16x8v va = *(const u16x8v*)(oa + d);
        u16x8v vb = *(const u16x8v*)(ob + d);
        u16x8v o;
#pragma unroll
        for (int j = 0; j < 8; ++j) o[j] = f2bf(bf2f(va[j]) * wa + bf2f(vb[j]) * wb);
        *(u16x8v*)(dst + d) = o;
    }
}

// ---------------------------------------------------------------------------
// Kernel 4: output projection + bias + residual, bf16 MFMA.
__global__ __launch_bounds__(256) void proj_kernel(
    const unsigned short* __restrict__ hT, const float* __restrict__ proj_w,
    const float* __restrict__ proj_b, const float* __restrict__ x,
    float* __restrict__ out) {
    __shared__ unsigned short Ws[64][PSB];  // [o][c]
    __shared__ unsigned short Hs[64][PSB];  // [n][c]
    const int n0 = blockIdx.x * 64;
    const int o0 = blockIdx.y * 64;
    const int b  = blockIdx.z;
    const int tid = threadIdx.x;
    const int lane = tid & 63, w = tid >> 6;
    const int lo = lane & 15, hi = lane >> 4;
    f32x4 acc[4] = {};

    for (int k0 = 0; k0 < C_DIM; k0 += 64) {
#pragma unroll
        for (int r = 0; r < 4; ++r) {
            int idx = tid + (r << 8);
            int row = idx >> 4, col4 = (idx & 15) << 2;
            float4 wv = *(const float4*)(proj_w + (size_t)(o0 + row) * C_DIM + k0 + col4);
            u16x4v o;
            o[0] = f2bf(wv.x); o[1] = f2bf(wv.y); o[2] = f2bf(wv.z); o[3] = f2bf(wv.w);
            *(u16x4v*)&Ws[row][col4] = o;
        }
#pragma unroll
        for (int r = 0; r < 2; ++r) {
            int idx = tid + (r << 8);
            int row = idx >> 3, blk = idx & 7;
            *(u16x8v*)&Hs[row][blk * 8] =
                *(const u16x8v*)(hT + ((size_t)b * N_TOK + n0 + row) * C_DIM + k0 + blk * 8);
        }
        __syncthreads();
#pragma unroll
        for (int ck = 0; ck < 2; ++ck) {
            bf16x8 aw = *(const bf16x8*)&Ws[w * 16 + lo][ck * 32 + hi * 8];
#pragma unroll
            for (int nb = 0; nb < 4; ++nb)
                acc[nb] = __builtin_amdgcn_mfma_f32_16x16x32_bf16(
                    aw, *(const bf16x8*)&Hs[nb * 16 + lo][ck * 32 + hi * 8], acc[nb], 0, 0, 0);
        }
        __syncthreads();
    }

#pragma unroll
    for (int nb = 0; nb < 4; ++nb) {
#pragma unroll
        for (int i = 0; i < 4; ++i) {
            int o = o0 + w * 16 + hi * 4 + i;
            size_t addr = ((size_t)b * C_DIM + o) * N_TOK + n0 + nb * 16 + lo;
            out[addr] = acc[nb][i] + proj_b[o] + x[addr];
        }
    }
}

// ---------------------------------------------------------------------------
extern "C" void kernel_launch(void* const* d_in, const int* in_sizes, int n_in,
                              void* d_out, int out_size, void* d_ws, size_t ws_size,
                              hipStream_t stream) {
    const float* x      = (const float*)d_in[0];
    const float* norm_w = (const float*)d_in[1];
    const float* norm_b = (const float*)d_in[2];
    const float* qkv_w  = (const float*)d_in[3];
    const float* qkv_b  = (const float*)d_in[4];
    const float* proj_w = (const float*)d_in[5];
    const float* proj_b = (const float*)d_in[6];
    float* out = (float*)d_out;

    // ws: stats f32[32] | qkvb bf16 (12.6MB) | hT bf16 (4.2MB)
    //   | obuf bf16 [2][8][N][HD] (8.4MB) | rbuf f32 [2][8][N] (256KB)  ~= 25.5MB
    float* stats = (float*)d_ws;
    unsigned short* qkvb = (unsigned short*)(stats + 32);
    unsigned short* hT = qkvb + (size_t)3 * B_DIM * HEADS * N_TOK * HD;
    unsigned short* obuf = hT + (size_t)B_DIM * N_TOK * C_DIM;
    float* rbuf = (float*)(obuf + (size_t)KSPLIT * B_DIM * HEADS * N_TOK * HD);

    gn_stats_kernel<<<B_DIM * GROUPS, 256, 0, stream>>>(x, stats);
    qkv_gemm_kernel<<<dim3(N_TOK / 64, 3 * C_DIM / 64, B_DIM), 256, 0, stream>>>(
        x, stats, norm_w, norm_b, qkv_w, qkv_b, qkvb);
    attn_kernel<<<(N_TOK / 64) * B_DIM * HEADS * KSPLIT, 256, 0, stream>>>(qkvb, obuf, rbuf);
    attn_combine_kernel<<<B_DIM * HEADS * N_TOK / 256, 256, 0, stream>>>(obuf, rbuf, hT);
    proj_kernel<<<dim3(N_TOK / 64, C_DIM / 64, B_DIM), 256, 0, stream>>>(
        hT, proj_w, proj_b, x, out);
}

// Round 5
// 117.596 us; speedup vs baseline: 9.5803x; 1.3168x over previous
//
#include <hip/hip_runtime.h>
#include <math.h>

#define B_DIM 2
#define C_DIM 256
#define N_TOK 4096      // 16*16*16
#define HEADS 4
#define HD 64
#define GROUPS 8
#define CPG (C_DIM / GROUPS)   // 32
#define EPS 1e-5f
#define PSB 72          // padded bf16 LDS row stride (144 B, 16B-aligned rows)
#define QK_SCALE 0.180336880f  // 0.125 * log2(e), folded into Q
#define KSPLIT 4
#define NKT (N_TOK / 64)       // 64 key tiles total
#define GN_CH 64               // partial-reduction chunks per group

typedef __bf16 bf16x8 __attribute__((ext_vector_type(8)));
typedef float  f32x4  __attribute__((ext_vector_type(4)));
typedef unsigned short u16x4v __attribute__((ext_vector_type(4)));
typedef unsigned short u16x8v __attribute__((ext_vector_type(8)));

__device__ __forceinline__ unsigned short f2bf(float f) {
    return __builtin_bit_cast(unsigned short, (__bf16)f);
}
__device__ __forceinline__ float bf2f(unsigned short u) {
    return (float)__builtin_bit_cast(__bf16, u);
}

// K-staging row permutation: bits [b5 b4 b3 b2 b1 b0] -> [b5 b3 b2 b4 b1 b0].
// Makes the S^T output registers exactly the PV B-fragment.
__device__ __forceinline__ int kperm(int r) {
    return (r & 0x23) | ((r & 0x0C) << 1) | ((r & 0x10) >> 2);
}

// ---------------------------------------------------------------------------
// Kernel 1a: GroupNorm partial sums. 1024 blocks (16 groups x 64 chunks).
__global__ __launch_bounds__(256) void gn_part_kernel(const float* __restrict__ x,
                                                      float* __restrict__ partials) {
    const int bg = blockIdx.x >> 6, ch = blockIdx.x & 63;
    const float4* p = (const float4*)(x + (size_t)bg * CPG * N_TOK) + ch * 512;
    float s = 0.f, ss = 0.f;
#pragma unroll
    for (int r = 0; r < 2; ++r) {
        float4 v = p[threadIdx.x + (r << 8)];
        s  += v.x + v.y + v.z + v.w;
        ss += v.x * v.x + v.y * v.y + v.z * v.z + v.w * v.w;
    }
#pragma unroll
    for (int off = 32; off > 0; off >>= 1) {
        s  += __shfl_down(s, off);
        ss += __shfl_down(ss, off);
    }
    __shared__ float ls[4], lss[4];
    const int lane = threadIdx.x & 63, wid = threadIdx.x >> 6;
    if (lane == 0) { ls[wid] = s; lss[wid] = ss; }
    __syncthreads();
    if (threadIdx.x == 0) {
        partials[blockIdx.x * 2 + 0] = ls[0] + ls[1] + ls[2] + ls[3];
        partials[blockIdx.x * 2 + 1] = lss[0] + lss[1] + lss[2] + lss[3];
    }
}

// Kernel 1b: finalize mean/rstd per (b,g). 16 blocks x 64 threads.
__global__ __launch_bounds__(64) void gn_final_kernel(const float* __restrict__ partials,
                                                      float* __restrict__ stats) {
    const int bg = blockIdx.x, t = threadIdx.x;
    float s  = partials[(bg * 64 + t) * 2 + 0];
    float ss = partials[(bg * 64 + t) * 2 + 1];
#pragma unroll
    for (int off = 32; off > 0; off >>= 1) {
        s  += __shfl_down(s, off);
        ss += __shfl_down(ss, off);
    }
    if (t == 0) {
        const float inv = 1.f / (float)(CPG * N_TOK);
        float mean = s * inv;
        float var  = ss * inv - mean * mean;
        stats[bg * 2 + 0] = mean;
        stats[bg * 2 + 1] = rsqrtf(var + EPS);
    }
}

// ---------------------------------------------------------------------------
// Kernel 2: fused GroupNorm-apply + QKV GEMM, bf16 MFMA.
// q,k out: [(s*B+b)*HEADS+h][n][d] bf16 (q pre-scaled by QK_SCALE)
// v   out: [b*HEADS+h][d][n] bf16
__global__ __launch_bounds__(256) void qkv_gemm_kernel(
    const float* __restrict__ x, const float* __restrict__ stats,
    const float* __restrict__ norm_w, const float* __restrict__ norm_b,
    const float* __restrict__ qkv_w, const float* __restrict__ qkv_b,
    unsigned short* __restrict__ qkvb) {
    __shared__ unsigned short Ws[64][PSB];  // [o][c] bf16
    __shared__ unsigned short Xt[64][PSB];  // [n][c] bf16 (transposed xn)
    const int n0 = blockIdx.x * 64;
    const int o0 = blockIdx.y * 64;
    const int b  = blockIdx.z;
    const int tid = threadIdx.x;
    const int lane = tid & 63, w = tid >> 6;
    const int lo = lane & 15, hi = lane >> 4;
    f32x4 acc[4] = {};

    for (int k0 = 0; k0 < C_DIM; k0 += 64) {
#pragma unroll
        for (int r = 0; r < 4; ++r) {
            int idx = tid + (r << 8);
            int row = idx >> 4, col4 = (idx & 15) << 2;
            float4 wv = *(const float4*)(qkv_w + (size_t)(o0 + row) * C_DIM + k0 + col4);
            u16x4v o;
            o[0] = f2bf(wv.x); o[1] = f2bf(wv.y); o[2] = f2bf(wv.z); o[3] = f2bf(wv.w);
            *(u16x4v*)&Ws[row][col4] = o;
        }
#pragma unroll
        for (int r = 0; r < 4; ++r) {
            int idx = tid + (r << 8);
            int crow = idx >> 4, col4 = (idx & 15) << 2;
            int c = k0 + crow;
            int g = c >> 5;
            float mean = stats[(b * GROUPS + g) * 2 + 0];
            float rstd = stats[(b * GROUPS + g) * 2 + 1];
            float ww = norm_w[c] * rstd;
            float bb = norm_b[c] - mean * ww;
            float4 v = *(const float4*)(x + ((size_t)b * C_DIM + c) * N_TOK + n0 + col4);
            Xt[col4 + 0][crow] = f2bf(v.x * ww + bb);
            Xt[col4 + 1][crow] = f2bf(v.y * ww + bb);
            Xt[col4 + 2][crow] = f2bf(v.z * ww + bb);
            Xt[col4 + 3][crow] = f2bf(v.w * ww + bb);
        }
        __syncthreads();
#pragma unroll
        for (int ck = 0; ck < 2; ++ck) {
            bf16x8 aw = *(const bf16x8*)&Ws[w * 16 + lo][ck * 32 + hi * 8];
#pragma unroll
            for (int nb = 0; nb < 4; ++nb)
                acc[nb] = __builtin_amdgcn_mfma_f32_16x16x32_bf16(
                    aw, *(const bf16x8*)&Xt[nb * 16 + lo][ck * 32 + hi * 8], acc[nb], 0, 0, 0);
        }
        __syncthreads();
    }

    const int sidx = o0 >> 8;           // 0=q, 1=k, 2=v
    const int head = (o0 >> 6) & 3;
    const int od = w * 16 + hi * 4;     // d within head (+i)
    float bias[4];
#pragma unroll
    for (int i = 0; i < 4; ++i) bias[i] = qkv_b[o0 + od + i];
    const size_t plane = (size_t)N_TOK * HD;

    if (sidx < 2) {
        const float sc = (sidx == 0) ? QK_SCALE : 1.0f;
        unsigned short* base = qkvb + ((size_t)(sidx * B_DIM + b) * HEADS + head) * plane;
#pragma unroll
        for (int nb = 0; nb < 4; ++nb) {
            int n = n0 + nb * 16 + lo;
            u16x4v o;
#pragma unroll
            for (int i = 0; i < 4; ++i) o[i] = f2bf((acc[nb][i] + bias[i]) * sc);
            *(u16x4v*)(base + (size_t)n * HD + od) = o;
        }
    } else {
        unsigned short* base = qkvb + (size_t)2 * B_DIM * HEADS * plane
                             + ((size_t)b * HEADS + head) * plane;
#pragma unroll
        for (int nb = 0; nb < 4; ++nb)
#pragma unroll
            for (int i = 0; i < 4; ++i)
                base[(size_t)(od + i) * N_TOK + n0 + nb * 16 + lo] = f2bf(acc[nb][i] + bias[i]);
    }
}

// ---------------------------------------------------------------------------
// Kernel 3: bf16 MFMA flash attention, swapped-operand (S^T), K-split x4.
// blockIdx.x: bits[2:0]=bh (XCD L2 locality), bits[4:3]=ks, rest=q-tile.
// Single-buffered LDS (18.4KB) + async-stage split; 8 blocks/CU possible.
__global__ __launch_bounds__(256) void attn_kernel(const unsigned short* __restrict__ qkvb,
                                                   unsigned short* __restrict__ obuf,
                                                   float* __restrict__ rbuf) {
    const int bh = blockIdx.x & 7;            // b*HEADS + head
    const int ks = (blockIdx.x >> 3) & 3;     // key-split quarter
    const int q0 = (blockIdx.x >> 5) * 64;
    const size_t plane = (size_t)N_TOK * HD;
    const unsigned short* Qg  = qkvb + (size_t)bh * plane;
    const unsigned short* Kg  = qkvb + (size_t)(B_DIM * HEADS + bh) * plane;
    const unsigned short* Vtg = qkvb + (size_t)2 * B_DIM * HEADS * plane + (size_t)bh * plane;

    __shared__ unsigned short Ks[64][PSB];  // [perm key row][d]
    __shared__ unsigned short Vt[64][PSB];  // [d][key]

    const int tid  = threadIdx.x;
    const int lane = tid & 63;
    const int wid  = tid >> 6;
    const int lo   = lane & 15;
    const int hi   = lane >> 4;

    // Q fragment (B-operand of S^T mfma): q = q0+wid*16+lo, d-chunks c*32+hi*8
    bf16x8 qf[2];
#pragma unroll
    for (int c = 0; c < 2; ++c)
        qf[c] = *(const bf16x8*)(Qg + (size_t)(q0 + wid * 16 + lo) * HD + c * 32 + hi * 8);

    const int srow = tid >> 3, sblk = tid & 7;
    const int kt0 = ks * (NKT / KSPLIT), ktE = kt0 + NKT / KSPLIT;

    f32x4 acc[4] = {};   // acc[db][i] = O^T[d = db*16+hi*4+i][q = q0+wid*16+lo]
    float m = -1e30f, l = 0.f;

    u16x8v kreg[2], vreg[2];
#pragma unroll
    for (int r = 0; r < 2; ++r) {
        int row = srow + r * 32;
        kreg[r] = *(const u16x8v*)(Kg + (size_t)(kt0 * 64 + kperm(row)) * HD + sblk * 8);
        vreg[r] = *(const u16x8v*)(Vtg + (size_t)row * N_TOK + kt0 * 64 + sblk * 8);
    }
#pragma unroll
    for (int r = 0; r < 2; ++r) {
        int row = srow + r * 32;
        *(u16x8v*)&Ks[row][sblk * 8] = kreg[r];
        *(u16x8v*)&Vt[row][sblk * 8] = vreg[r];
    }
    __syncthreads();

    for (int kt = kt0; kt < ktE; ++kt) {
        // issue next tile's global loads (in flight across the compute phase)
        if (kt + 1 < ktE) {
            const int k1 = (kt + 1) * 64;
#pragma unroll
            for (int r = 0; r < 2; ++r) {
                int row = srow + r * 32;
                kreg[r] = *(const u16x8v*)(Kg + (size_t)(k1 + kperm(row)) * HD + sblk * 8);
                vreg[r] = *(const u16x8v*)(Vtg + (size_t)row * N_TOK + k1 + sblk * 8);
            }
        }

        // S^T = K Q^T. s4[kb][i] = S^T[key = kb*16+hi*4+i][query lo]
        f32x4 s4[4] = {};
        __builtin_amdgcn_s_setprio(1);
#pragma unroll
        for (int kb = 0; kb < 4; ++kb)
#pragma unroll
            for (int c = 0; c < 2; ++c)
                s4[kb] = __builtin_amdgcn_mfma_f32_16x16x32_bf16(
                    *(const bf16x8*)&Ks[kb * 16 + lo][c * 32 + hi * 8], qf[c], s4[kb], 0, 0, 0);
        __builtin_amdgcn_s_setprio(0);

        // tile max for query lo (reduce 16 regs, then across hi groups)
        float r0 = fmaxf(fmaxf(s4[0][0], s4[0][1]), fmaxf(s4[0][2], s4[0][3]));
        float r1 = fmaxf(fmaxf(s4[1][0], s4[1][1]), fmaxf(s4[1][2], s4[1][3]));
        float r2 = fmaxf(fmaxf(s4[2][0], s4[2][1]), fmaxf(s4[2][2], s4[2][3]));
        float r3 = fmaxf(fmaxf(s4[3][0], s4[3][1]), fmaxf(s4[3][2], s4[3][3]));
        float rm = fmaxf(fmaxf(r0, r1), fmaxf(r2, r3));
        rm = fmaxf(rm, __shfl_xor(rm, 16));
        rm = fmaxf(rm, __shfl_xor(rm, 32));

        // defer-max (T13): only rescale when the running max grew by > 8 (log2)
        if (__any(rm > m + 8.0f)) {
            const float mn = fmaxf(m, rm);
            const float fi = exp2f(m - mn);
            m = mn;
            l *= fi;
#pragma unroll
            for (int db = 0; db < 4; ++db)
#pragma unroll
                for (int i = 0; i < 4; ++i) acc[db][i] *= fi;
        }

        float p[4][4];
        float ps = 0.f;
#pragma unroll
        for (int kb = 0; kb < 4; ++kb)
#pragma unroll
            for (int i = 0; i < 4; ++i) {
                p[kb][i] = exp2f(s4[kb][i] - m);
                ps += p[kb][i];
            }
        l += ps;

        // pack P into PV B-fragment: pf[c][j] = p[2c + (j>>2)][j&3]
        bf16x8 pf[2];
#pragma unroll
        for (int c = 0; c < 2; ++c)
#pragma unroll
            for (int j = 0; j < 8; ++j) pf[c][j] = (__bf16)p[2 * c + (j >> 2)][j & 3];

        // O^T += V^T P^T
        __builtin_amdgcn_s_setprio(1);
#pragma unroll
        for (int db = 0; db < 4; ++db)
#pragma unroll
            for (int c = 0; c < 2; ++c)
                acc[db] = __builtin_amdgcn_mfma_f32_16x16x32_bf16(
                    *(const bf16x8*)&Vt[db * 16 + lo][c * 32 + hi * 8], pf[c], acc[db], 0, 0, 0);
        __builtin_amdgcn_s_setprio(0);

        __syncthreads();   // all waves done reading Ks/Vt
        if (kt + 1 < ktE) {
#pragma unroll
            for (int r = 0; r < 2; ++r) {
                int row = srow + r * 32;
                *(u16x8v*)&Ks[row][sblk * 8] = kreg[r];
                *(u16x8v*)&Vt[row][sblk * 8] = vreg[r];
            }
            __syncthreads();
        }
    }

    // epilogue: normalized bf16 partial O + log-sum-exp r
    float l1 = l + __shfl_xor(l, 16);
    float lt = l1 + __shfl_xor(l1, 32);
    const float inv = 1.f / lt;
    const int n = q0 + wid * 16 + lo;
    unsigned short* ob = obuf + ((size_t)(ks * 8 + bh) * N_TOK + n) * HD;
#pragma unroll
    for (int db = 0; db < 4; ++db) {
        u16x4v o;
#pragma unroll
        for (int i = 0; i < 4; ++i) o[i] = f2bf(acc[db][i] * inv);
        *(u16x4v*)(ob + db * 16 + hi * 4) = o;
    }
    if (hi == 0)
        rbuf[(size_t)(ks * 8 + bh) * N_TOK + n] = m + log2f(lt);
}

// ---------------------------------------------------------------------------
// Kernel 3b: combine the 4 K-split quarters -> hT [b][n][c] bf16.
// thread -> (bh, n, 16-d block); 4 consecutive threads cover one n (coalesced).
__global__ __launch_bounds__(256) void attn_combine_kernel(
    const unsigned short* __restrict__ obuf, const float* __restrict__ rbuf,
    unsigned short* __restrict__ hT) {
    const int idx = blockIdx.x * 256 + threadIdx.x;
    const int dq  = (idx & 3) * 16;
    const int bhn = idx >> 2;                  // bh*N_TOK + n
    const int n   = bhn & (N_TOK - 1);
    const int bh  = bhn >> 12;
    float r[KSPLIT], M = -1e30f;
#pragma unroll
    for (int k = 0; k < KSPLIT; ++k) {
        r[k] = rbuf[(size_t)(k * 8 + bh) * N_TOK + n];
        M = fmaxf(M, r[k]);
    }
    float w[KSPLIT], tot = 0.f;
#pragma unroll
    for (int k = 0; k < KSPLIT; ++k) { w[k] = exp2f(r[k] - M); tot += w[k]; }
    const float inv = 1.f / tot;
    const int b = bh >> 2, head = bh & 3;
    unsigned short* dst = hT + ((size_t)b * N_TOK + n) * C_DIM + head * HD + dq;
#pragma unroll
    for (int c = 0; c < 2; ++c) {
        float a[8] = {};
#pragma unroll
        for (int k = 0; k < KSPLIT; ++k) {
            u16x8v v = *(const u16x8v*)(obuf + ((size_t)(k * 8 + bh) * N_TOK + n) * HD + dq + c * 8);
#pragma unroll
            for (int j = 0; j < 8; ++j) a[j] += w[k] * bf2f(v[j]);
        }
        u16x8v o;
#pragma unroll
        for (int j = 0; j < 8; ++j) o[j] = f2bf(a[j] * inv);
        *(u16x8v*)(dst + c * 8) = o;
    }
}

// ---------------------------------------------------------------------------
// Kernel 4: output projection + bias + residual, bf16 MFMA.
__global__ __launch_bounds__(256) void proj_kernel(
    const unsigned short* __restrict__ hT, const float* __restrict__ proj_w,
    const float* __restrict__ proj_b, const float* __restrict__ x,
    float* __restrict__ out) {
    __shared__ unsigned short Ws[64][PSB];  // [o][c]
    __shared__ unsigned short Hs[64][PSB];  // [n][c]
    const int n0 = blockIdx.x * 64;
    const int o0 = blockIdx.y * 64;
    const int b  = blockIdx.z;
    const int tid = threadIdx.x;
    const int lane = tid & 63, w = tid >> 6;
    const int lo = lane & 15, hi = lane >> 4;
    f32x4 acc[4] = {};

    for (int k0 = 0; k0 < C_DIM; k0 += 64) {
#pragma unroll
        for (int r = 0; r < 4; ++r) {
            int idx = tid + (r << 8);
            int row = idx >> 4, col4 = (idx & 15) << 2;
            float4 wv = *(const float4*)(proj_w + (size_t)(o0 + row) * C_DIM + k0 + col4);
            u16x4v o;
            o[0] = f2bf(wv.x); o[1] = f2bf(wv.y); o[2] = f2bf(wv.z); o[3] = f2bf(wv.w);
            *(u16x4v*)&Ws[row][col4] = o;
        }
#pragma unroll
        for (int r = 0; r < 2; ++r) {
            int idx = tid + (r << 8);
            int row = idx >> 3, blk = idx & 7;
            *(u16x8v*)&Hs[row][blk * 8] =
                *(const u16x8v*)(hT + ((size_t)b * N_TOK + n0 + row) * C_DIM + k0 + blk * 8);
        }
        __syncthreads();
#pragma unroll
        for (int ck = 0; ck < 2; ++ck) {
            bf16x8 aw = *(const bf16x8*)&Ws[w * 16 + lo][ck * 32 + hi * 8];
#pragma unroll
            for (int nb = 0; nb < 4; ++nb)
                acc[nb] = __builtin_amdgcn_mfma_f32_16x16x32_bf16(
                    aw, *(const bf16x8*)&Hs[nb * 16 + lo][ck * 32 + hi * 8], acc[nb], 0, 0, 0);
        }
        __syncthreads();
    }

#pragma unroll
    for (int nb = 0; nb < 4; ++nb) {
#pragma unroll
        for (int i = 0; i < 4; ++i) {
            int o = o0 + w * 16 + hi * 4 + i;
            size_t addr = ((size_t)b * C_DIM + o) * N_TOK + n0 + nb * 16 + lo;
            out[addr] = acc[nb][i] + proj_b[o] + x[addr];
        }
    }
}

// ---------------------------------------------------------------------------
extern "C" void kernel_launch(void* const* d_in, const int* in_sizes, int n_in,
                              void* d_out, int out_size, void* d_ws, size_t ws_size,
                              hipStream_t stream) {
    const float* x      = (const float*)d_in[0];
    const float* norm_w = (const float*)d_in[1];
    const float* norm_b = (const float*)d_in[2];
    const float* qkv_w  = (const float*)d_in[3];
    const float* qkv_b  = (const float*)d_in[4];
    const float* proj_w = (const float*)d_in[5];
    const float* proj_b = (const float*)d_in[6];
    float* out = (float*)d_out;

    // ws: stats f32[32] | partials f32[2048] | qkvb bf16 (12.6MB)
    //   | obuf bf16 [4][8][N][HD] (16.8MB) | rbuf f32 [4][8][N] (512KB) ~= 29.9MB
    // hT (4.2MB) aliases the dead q-plane inside qkvb (attn completes before combine).
    float* stats = (float*)d_ws;
    float* partials = stats + 32;
    unsigned short* qkvb = (unsigned short*)(partials + 2048);
    unsigned short* hT = qkvb;  // q-plane reuse
    unsigned short* obuf = qkvb + (size_t)3 * B_DIM * HEADS * N_TOK * HD;
    float* rbuf = (float*)(obuf + (size_t)KSPLIT * B_DIM * HEADS * N_TOK * HD);

    gn_part_kernel<<<B_DIM * GROUPS * 64, 256, 0, stream>>>(x, partials);
    gn_final_kernel<<<B_DIM * GROUPS, 64, 0, stream>>>(partials, stats);
    qkv_gemm_kernel<<<dim3(N_TOK / 64, 3 * C_DIM / 64, B_DIM), 256, 0, stream>>>(
        x, stats, norm_w, norm_b, qkv_w, qkv_b, qkvb);
    attn_kernel<<<(N_TOK / 64) * B_DIM * HEADS * KSPLIT, 256, 0, stream>>>(qkvb, obuf, rbuf);
    attn_combine_kernel<<<B_DIM * HEADS * N_TOK * 4 / 256, 256, 0, stream>>>(obuf, rbuf, hT);
    proj_kernel<<<dim3(N_TOK / 64, C_DIM / 64, B_DIM), 256, 0, stream>>>(
        hT, proj_w, proj_b, x, out);
}

// Round 6
// 109.237 us; speedup vs baseline: 10.3134x; 1.0765x over previous
//
#include <hip/hip_runtime.h>
#include <math.h>

#define B_DIM 2
#define C_DIM 256
#define N_TOK 4096      // 16*16*16
#define HEADS 4
#define HD 64
#define GROUPS 8
#define CPG (C_DIM / GROUPS)   // 32
#define EPS 1e-5f
#define PSB 72          // padded bf16 LDS row stride (144 B, 16B-aligned rows)
#define QK_SCALE 0.180336880f  // 0.125 * log2(e), folded into Q
#define KSPLIT 4
#define NKT (N_TOK / 64)       // 64 key tiles total

typedef __bf16 bf16x8 __attribute__((ext_vector_type(8)));
typedef float  f32x4  __attribute__((ext_vector_type(4)));
typedef unsigned short u16x4v __attribute__((ext_vector_type(4)));
typedef unsigned short u16x8v __attribute__((ext_vector_type(8)));

__device__ __forceinline__ unsigned short f2bf(float f) {
    return __builtin_bit_cast(unsigned short, (__bf16)f);
}
__device__ __forceinline__ float bf2f(unsigned short u) {
    return (float)__builtin_bit_cast(__bf16, u);
}
// raw v_exp_f32 (2^x); inputs are bounded (x <= ~8) so no OCML fixup needed
__device__ __forceinline__ float exp2_fast(float x) { return __builtin_amdgcn_exp2f(x); }

// K-staging row permutation: bits [b5 b4 b3 b2 b1 b0] -> [b5 b3 b2 b4 b1 b0].
// Makes the S^T output registers exactly the PV B-fragment.
__device__ __forceinline__ int kperm(int r) {
    return (r & 0x23) | ((r & 0x0C) << 1) | ((r & 0x10) >> 2);
}

// ---------------------------------------------------------------------------
// Kernel 1a: GroupNorm partial sums. 1024 blocks (16 groups x 64 chunks).
__global__ __launch_bounds__(256) void gn_part_kernel(const float* __restrict__ x,
                                                      float* __restrict__ partials) {
    const int bg = blockIdx.x >> 6, ch = blockIdx.x & 63;
    const float4* p = (const float4*)(x + (size_t)bg * CPG * N_TOK) + ch * 512;
    float s = 0.f, ss = 0.f;
#pragma unroll
    for (int r = 0; r < 2; ++r) {
        float4 v = p[threadIdx.x + (r << 8)];
        s  += v.x + v.y + v.z + v.w;
        ss += v.x * v.x + v.y * v.y + v.z * v.z + v.w * v.w;
    }
#pragma unroll
    for (int off = 32; off > 0; off >>= 1) {
        s  += __shfl_down(s, off);
        ss += __shfl_down(ss, off);
    }
    __shared__ float ls[4], lss[4];
    const int lane = threadIdx.x & 63, wid = threadIdx.x >> 6;
    if (lane == 0) { ls[wid] = s; lss[wid] = ss; }
    __syncthreads();
    if (threadIdx.x == 0) {
        partials[blockIdx.x * 2 + 0] = ls[0] + ls[1] + ls[2] + ls[3];
        partials[blockIdx.x * 2 + 1] = lss[0] + lss[1] + lss[2] + lss[3];
    }
}

// Kernel 1b: finalize mean/rstd per (b,g). 16 blocks x 64 threads.
__global__ __launch_bounds__(64) void gn_final_kernel(const float* __restrict__ partials,
                                                      float* __restrict__ stats) {
    const int bg = blockIdx.x, t = threadIdx.x;
    float s  = partials[(bg * 64 + t) * 2 + 0];
    float ss = partials[(bg * 64 + t) * 2 + 1];
#pragma unroll
    for (int off = 32; off > 0; off >>= 1) {
        s  += __shfl_down(s, off);
        ss += __shfl_down(ss, off);
    }
    if (t == 0) {
        const float inv = 1.f / (float)(CPG * N_TOK);
        float mean = s * inv;
        float var  = ss * inv - mean * mean;
        stats[bg * 2 + 0] = mean;
        stats[bg * 2 + 1] = rsqrtf(var + EPS);
    }
}

// ---------------------------------------------------------------------------
// Kernel 2: fused GroupNorm-apply + QKV GEMM, bf16 MFMA.
// q,k out: [(s*B+b)*HEADS+h][n][d] bf16 (q pre-scaled by QK_SCALE)
// v   out: [b*HEADS+h][d][n] bf16
__global__ __launch_bounds__(256) void qkv_gemm_kernel(
    const float* __restrict__ x, const float* __restrict__ stats,
    const float* __restrict__ norm_w, const float* __restrict__ norm_b,
    const float* __restrict__ qkv_w, const float* __restrict__ qkv_b,
    unsigned short* __restrict__ qkvb) {
    __shared__ unsigned short Ws[64][PSB];  // [o][c] bf16
    __shared__ unsigned short Xt[64][PSB];  // [n][c] bf16 (transposed xn)
    const int n0 = blockIdx.x * 64;
    const int o0 = blockIdx.y * 64;
    const int b  = blockIdx.z;
    const int tid = threadIdx.x;
    const int lane = tid & 63, w = tid >> 6;
    const int lo = lane & 15, hi = lane >> 4;
    f32x4 acc[4] = {};

    for (int k0 = 0; k0 < C_DIM; k0 += 64) {
#pragma unroll
        for (int r = 0; r < 4; ++r) {
            int idx = tid + (r << 8);
            int row = idx >> 4, col4 = (idx & 15) << 2;
            float4 wv = *(const float4*)(qkv_w + (size_t)(o0 + row) * C_DIM + k0 + col4);
            u16x4v o;
            o[0] = f2bf(wv.x); o[1] = f2bf(wv.y); o[2] = f2bf(wv.z); o[3] = f2bf(wv.w);
            *(u16x4v*)&Ws[row][col4] = o;
        }
#pragma unroll
        for (int r = 0; r < 4; ++r) {
            int idx = tid + (r << 8);
            int crow = idx >> 4, col4 = (idx & 15) << 2;
            int c = k0 + crow;
            int g = c >> 5;
            float mean = stats[(b * GROUPS + g) * 2 + 0];
            float rstd = stats[(b * GROUPS + g) * 2 + 1];
            float ww = norm_w[c] * rstd;
            float bb = norm_b[c] - mean * ww;
            float4 v = *(const float4*)(x + ((size_t)b * C_DIM + c) * N_TOK + n0 + col4);
            Xt[col4 + 0][crow] = f2bf(v.x * ww + bb);
            Xt[col4 + 1][crow] = f2bf(v.y * ww + bb);
            Xt[col4 + 2][crow] = f2bf(v.z * ww + bb);
            Xt[col4 + 3][crow] = f2bf(v.w * ww + bb);
        }
        __syncthreads();
#pragma unroll
        for (int ck = 0; ck < 2; ++ck) {
            bf16x8 aw = *(const bf16x8*)&Ws[w * 16 + lo][ck * 32 + hi * 8];
#pragma unroll
            for (int nb = 0; nb < 4; ++nb)
                acc[nb] = __builtin_amdgcn_mfma_f32_16x16x32_bf16(
                    aw, *(const bf16x8*)&Xt[nb * 16 + lo][ck * 32 + hi * 8], acc[nb], 0, 0, 0);
        }
        __syncthreads();
    }

    const int sidx = o0 >> 8;           // 0=q, 1=k, 2=v
    const int head = (o0 >> 6) & 3;
    const int od = w * 16 + hi * 4;     // d within head (+i)
    float bias[4];
#pragma unroll
    for (int i = 0; i < 4; ++i) bias[i] = qkv_b[o0 + od + i];
    const size_t plane = (size_t)N_TOK * HD;

    if (sidx < 2) {
        const float sc = (sidx == 0) ? QK_SCALE : 1.0f;
        unsigned short* base = qkvb + ((size_t)(sidx * B_DIM + b) * HEADS + head) * plane;
#pragma unroll
        for (int nb = 0; nb < 4; ++nb) {
            int n = n0 + nb * 16 + lo;
            u16x4v o;
#pragma unroll
            for (int i = 0; i < 4; ++i) o[i] = f2bf((acc[nb][i] + bias[i]) * sc);
            *(u16x4v*)(base + (size_t)n * HD + od) = o;
        }
    } else {
        unsigned short* base = qkvb + (size_t)2 * B_DIM * HEADS * plane
                             + ((size_t)b * HEADS + head) * plane;
#pragma unroll
        for (int nb = 0; nb < 4; ++nb)
#pragma unroll
            for (int i = 0; i < 4; ++i)
                base[(size_t)(od + i) * N_TOK + n0 + nb * 16 + lo] = f2bf(acc[nb][i] + bias[i]);
    }
}

// ---------------------------------------------------------------------------
// Kernel 3: bf16 MFMA flash attention, swapped-operand (S^T), K-split x4.
// blockIdx.x: bits[2:0]=bh (XCD L2 locality), bits[4:3]=ks, rest=q-tile.
__global__ __launch_bounds__(256) void attn_kernel(const unsigned short* __restrict__ qkvb,
                                                   unsigned short* __restrict__ obuf,
                                                   float* __restrict__ rbuf) {
    const int bh = blockIdx.x & 7;            // b*HEADS + head
    const int ks = (blockIdx.x >> 3) & 3;     // key-split quarter
    const int q0 = (blockIdx.x >> 5) * 64;
    const size_t plane = (size_t)N_TOK * HD;
    const unsigned short* Qg  = qkvb + (size_t)bh * plane;
    const unsigned short* Kg  = qkvb + (size_t)(B_DIM * HEADS + bh) * plane;
    const unsigned short* Vtg = qkvb + (size_t)2 * B_DIM * HEADS * plane + (size_t)bh * plane;

    __shared__ unsigned short Ks[64][PSB];  // [perm key row][d]
    __shared__ unsigned short Vt[64][PSB];  // [d][key]

    const int tid  = threadIdx.x;
    const int lane = tid & 63;
    const int wid  = tid >> 6;
    const int lo   = lane & 15;
    const int hi   = lane >> 4;

    // Q fragment (B-operand of S^T mfma): q = q0+wid*16+lo, d-chunks c*32+hi*8
    bf16x8 qf[2];
#pragma unroll
    for (int c = 0; c < 2; ++c)
        qf[c] = *(const bf16x8*)(Qg + (size_t)(q0 + wid * 16 + lo) * HD + c * 32 + hi * 8);

    const int srow = tid >> 3, sblk = tid & 7;
    const int kt0 = ks * (NKT / KSPLIT), ktE = kt0 + NKT / KSPLIT;

    f32x4 acc[4] = {};   // acc[db][i] = O^T[d = db*16+hi*4+i][q = q0+wid*16+lo]
    float m = -1e30f, l = 0.f;

    u16x8v kreg[2], vreg[2];
#pragma unroll
    for (int r = 0; r < 2; ++r) {
        int row = srow + r * 32;
        kreg[r] = *(const u16x8v*)(Kg + (size_t)(kt0 * 64 + kperm(row)) * HD + sblk * 8);
        vreg[r] = *(const u16x8v*)(Vtg + (size_t)row * N_TOK + kt0 * 64 + sblk * 8);
    }
#pragma unroll
    for (int r = 0; r < 2; ++r) {
        int row = srow + r * 32;
        *(u16x8v*)&Ks[row][sblk * 8] = kreg[r];
        *(u16x8v*)&Vt[row][sblk * 8] = vreg[r];
    }
    __syncthreads();

    for (int kt = kt0; kt < ktE; ++kt) {
        // issue next tile's global loads (in flight across the compute phase)
        if (kt + 1 < ktE) {
            const int k1 = (kt + 1) * 64;
#pragma unroll
            for (int r = 0; r < 2; ++r) {
                int row = srow + r * 32;
                kreg[r] = *(const u16x8v*)(Kg + (size_t)(k1 + kperm(row)) * HD + sblk * 8);
                vreg[r] = *(const u16x8v*)(Vtg + (size_t)row * N_TOK + k1 + sblk * 8);
            }
        }

        // S^T = K Q^T. s4[kb][i] = S^T[key = kb*16+hi*4+i][query lo]
        f32x4 s4[4] = {};
        __builtin_amdgcn_s_setprio(1);
#pragma unroll
        for (int kb = 0; kb < 4; ++kb)
#pragma unroll
            for (int c = 0; c < 2; ++c)
                s4[kb] = __builtin_amdgcn_mfma_f32_16x16x32_bf16(
                    *(const bf16x8*)&Ks[kb * 16 + lo][c * 32 + hi * 8], qf[c], s4[kb], 0, 0, 0);
        __builtin_amdgcn_s_setprio(0);

        // tile max for query lo; nested fmaxf triples fuse to v_max3_f32
        float r0 = fmaxf(fmaxf(fmaxf(s4[0][0], s4[0][1]), s4[0][2]), s4[0][3]);
        float r1 = fmaxf(fmaxf(fmaxf(s4[1][0], s4[1][1]), s4[1][2]), s4[1][3]);
        float r2 = fmaxf(fmaxf(fmaxf(s4[2][0], s4[2][1]), s4[2][2]), s4[2][3]);
        float r3 = fmaxf(fmaxf(fmaxf(s4[3][0], s4[3][1]), s4[3][2]), s4[3][3]);
        float rm = fmaxf(fmaxf(fmaxf(r0, r1), r2), r3);
        rm = fmaxf(rm, __shfl_xor(rm, 16));
        rm = fmaxf(rm, __shfl_xor(rm, 32));

        // defer-max (T13): only rescale when the running max grew by > 8 (log2)
        if (__any(rm > m + 8.0f)) {
            const float mn = fmaxf(m, rm);
            const float fi = exp2_fast(m - mn);
            m = mn;
            l *= fi;
#pragma unroll
            for (int db = 0; db < 4; ++db)
#pragma unroll
                for (int i = 0; i < 4; ++i) acc[db][i] *= fi;
        }

        float p[4][4];
        float ps = 0.f;
#pragma unroll
        for (int kb = 0; kb < 4; ++kb)
#pragma unroll
            for (int i = 0; i < 4; ++i) {
                p[kb][i] = exp2_fast(s4[kb][i] - m);
                ps += p[kb][i];
            }
        l += ps;

        // pack P into PV B-fragment: pf[c][j] = p[2c + (j>>2)][j&3]
        bf16x8 pf[2];
#pragma unroll
        for (int c = 0; c < 2; ++c)
#pragma unroll
            for (int j = 0; j < 8; ++j) pf[c][j] = (__bf16)p[2 * c + (j >> 2)][j & 3];

        // O^T += V^T P^T
        __builtin_amdgcn_s_setprio(1);
#pragma unroll
        for (int db = 0; db < 4; ++db)
#pragma unroll
            for (int c = 0; c < 2; ++c)
                acc[db] = __builtin_amdgcn_mfma_f32_16x16x32_bf16(
                    *(const bf16x8*)&Vt[db * 16 + lo][c * 32 + hi * 8], pf[c], acc[db], 0, 0, 0);
        __builtin_amdgcn_s_setprio(0);

        __syncthreads();   // all waves done reading Ks/Vt
        if (kt + 1 < ktE) {
#pragma unroll
            for (int r = 0; r < 2; ++r) {
                int row = srow + r * 32;
                *(u16x8v*)&Ks[row][sblk * 8] = kreg[r];
                *(u16x8v*)&Vt[row][sblk * 8] = vreg[r];
            }
            __syncthreads();
        }
    }

    // epilogue: normalized bf16 partial O + log-sum-exp r
    float l1 = l + __shfl_xor(l, 16);
    float lt = l1 + __shfl_xor(l1, 32);
    const float inv = 1.f / lt;
    const int n = q0 + wid * 16 + lo;
    unsigned short* ob = obuf + ((size_t)(ks * 8 + bh) * N_TOK + n) * HD;
#pragma unroll
    for (int db = 0; db < 4; ++db) {
        u16x4v o;
#pragma unroll
        for (int i = 0; i < 4; ++i) o[i] = f2bf(acc[db][i] * inv);
        *(u16x4v*)(ob + db * 16 + hi * 4) = o;
    }
    if (hi == 0)
        rbuf[(size_t)(ks * 8 + bh) * N_TOK + n] = m + __builtin_amdgcn_logf(lt);
}

// ---------------------------------------------------------------------------
// Kernel 4: output projection + bias + residual, bf16 MFMA.
// K-split combine fused into the h staging (reads obuf/rbuf directly).
__global__ __launch_bounds__(256) void proj_kernel(
    const unsigned short* __restrict__ obuf, const float* __restrict__ rbuf,
    const float* __restrict__ proj_w, const float* __restrict__ proj_b,
    const float* __restrict__ x, float* __restrict__ out) {
    __shared__ unsigned short Ws[64][PSB];  // [o][c]
    __shared__ unsigned short Hs[64][PSB];  // [n][c-within-head]
    const int n0 = blockIdx.x * 64;
    const int o0 = blockIdx.y * 64;
    const int b  = blockIdx.z;
    const int tid = threadIdx.x;
    const int lane = tid & 63, w = tid >> 6;
    const int lo = lane & 15, hi = lane >> 4;
    f32x4 acc[4] = {};

    for (int k0 = 0; k0 < C_DIM; k0 += 64) {
#pragma unroll
        for (int r = 0; r < 4; ++r) {
            int idx = tid + (r << 8);
            int row = idx >> 4, col4 = (idx & 15) << 2;
            float4 wv = *(const float4*)(proj_w + (size_t)(o0 + row) * C_DIM + k0 + col4);
            u16x4v o;
            o[0] = f2bf(wv.x); o[1] = f2bf(wv.y); o[2] = f2bf(wv.z); o[3] = f2bf(wv.w);
            *(u16x4v*)&Ws[row][col4] = o;
        }
        // stage h[n][k0..k0+64): head = k0>>6; combine the 4 K-split partials
        {
            const int head = k0 >> 6;
            const int bh = b * HEADS + head;
#pragma unroll
            for (int r = 0; r < 2; ++r) {
                int idx = tid + (r << 8);
                int row = idx >> 3, blk = idx & 7;   // n-row in tile, 8-d chunk
                int n = n0 + row;
                float rr[KSPLIT], M = -1e30f;
#pragma unroll
                for (int k = 0; k < KSPLIT; ++k) {
                    rr[k] = rbuf[(size_t)(k * 8 + bh) * N_TOK + n];
                    M = fmaxf(M, rr[k]);
                }
                float wk[KSPLIT], tot = 0.f;
#pragma unroll
                for (int k = 0; k < KSPLIT; ++k) { wk[k] = exp2_fast(rr[k] - M); tot += wk[k]; }
                const float inv = 1.f / tot;
                float a[8] = {};
#pragma unroll
                for (int k = 0; k < KSPLIT; ++k) {
                    u16x8v v = *(const u16x8v*)(obuf
                        + ((size_t)(k * 8 + bh) * N_TOK + n) * HD + blk * 8);
#pragma unroll
                    for (int j = 0; j < 8; ++j) a[j] += wk[k] * bf2f(v[j]);
                }
                u16x8v o;
#pragma unroll
                for (int j = 0; j < 8; ++j) o[j] = f2bf(a[j] * inv);
                *(u16x8v*)&Hs[row][blk * 8] = o;
            }
        }
        __syncthreads();
#pragma unroll
        for (int ck = 0; ck < 2; ++ck) {
            bf16x8 aw = *(const bf16x8*)&Ws[w * 16 + lo][ck * 32 + hi * 8];
#pragma unroll
            for (int nb = 0; nb < 4; ++nb)
                acc[nb] = __builtin_amdgcn_mfma_f32_16x16x32_bf16(
                    aw, *(const bf16x8*)&Hs[nb * 16 + lo][ck * 32 + hi * 8], acc[nb], 0, 0, 0);
        }
        __syncthreads();
    }

#pragma unroll
    for (int nb = 0; nb < 4; ++nb) {
#pragma unroll
        for (int i = 0; i < 4; ++i) {
            int o = o0 + w * 16 + hi * 4 + i;
            size_t addr = ((size_t)b * C_DIM + o) * N_TOK + n0 + nb * 16 + lo;
            out[addr] = acc[nb][i] + proj_b[o] + x[addr];
        }
    }
}

// ---------------------------------------------------------------------------
extern "C" void kernel_launch(void* const* d_in, const int* in_sizes, int n_in,
                              void* d_out, int out_size, void* d_ws, size_t ws_size,
                              hipStream_t stream) {
    const float* x      = (const float*)d_in[0];
    const float* norm_w = (const float*)d_in[1];
    const float* norm_b = (const float*)d_in[2];
    const float* qkv_w  = (const float*)d_in[3];
    const float* qkv_b  = (const float*)d_in[4];
    const float* proj_w = (const float*)d_in[5];
    const float* proj_b = (const float*)d_in[6];
    float* out = (float*)d_out;

    // ws: stats f32[32] | partials f32[2048] | qkvb bf16 (12.6MB)
    //   | obuf bf16 [4][8][N][HD] (16.8MB) | rbuf f32 [4][8][N] (512KB) ~= 29.9MB
    float* stats = (float*)d_ws;
    float* partials = stats + 32;
    unsigned short* qkvb = (unsigned short*)(partials + 2048);
    unsigned short* obuf = qkvb + (size_t)3 * B_DIM * HEADS * N_TOK * HD;
    float* rbuf = (float*)(obuf + (size_t)KSPLIT * B_DIM * HEADS * N_TOK * HD);

    gn_part_kernel<<<B_DIM * GROUPS * 64, 256, 0, stream>>>(x, partials);
    gn_final_kernel<<<B_DIM * GROUPS, 64, 0, stream>>>(partials, stats);
    qkv_gemm_kernel<<<dim3(N_TOK / 64, 3 * C_DIM / 64, B_DIM), 256, 0, stream>>>(
        x, stats, norm_w, norm_b, qkv_w, qkv_b, qkvb);
    attn_kernel<<<(N_TOK / 64) * B_DIM * HEADS * KSPLIT, 256, 0, stream>>>(qkvb, obuf, rbuf);
    proj_kernel<<<dim3(N_TOK / 64, C_DIM / 64, B_DIM), 256, 0, stream>>>(
        obuf, rbuf, proj_w, proj_b, x, out);
}

// Round 7
// 105.229 us; speedup vs baseline: 10.7063x; 1.0381x over previous
//
#include <hip/hip_runtime.h>
#include <math.h>

#define B_DIM 2
#define C_DIM 256
#define N_TOK 4096      // 16*16*16
#define HEADS 4
#define HD 64
#define GROUPS 8
#define CPG (C_DIM / GROUPS)   // 32
#define EPS 1e-5f
#define PSB 72          // padded bf16 LDS row stride (GEMM kernels)
#define QK_SCALE 0.180336880f  // 0.125 * log2(e), folded into Q
#define KSPLIT 4
#define NKT (N_TOK / 64)       // 64 key tiles total

typedef __bf16 bf16x8 __attribute__((ext_vector_type(8)));
typedef float  f32x4  __attribute__((ext_vector_type(4)));
typedef unsigned short u16x4v __attribute__((ext_vector_type(4)));
typedef unsigned short u16x8v __attribute__((ext_vector_type(8)));

__device__ __forceinline__ unsigned short f2bf(float f) {
    return __builtin_bit_cast(unsigned short, (__bf16)f);
}
__device__ __forceinline__ float bf2f(unsigned short u) {
    return (float)__builtin_bit_cast(__bf16, u);
}
// raw v_exp_f32 (2^x); inputs bounded so no OCML fixup needed
__device__ __forceinline__ float exp2_fast(float x) { return __builtin_amdgcn_exp2f(x); }

// async global->LDS, 16B per lane, wave-uniform LDS base (linear dest)
__device__ __forceinline__ void gload16(const unsigned short* g, unsigned short* l) {
    __builtin_amdgcn_global_load_lds(
        (const __attribute__((address_space(1))) unsigned int*)g,
        (__attribute__((address_space(3))) unsigned int*)l, 16, 0, 0);
}

// K-staging row permutation: [b5 b4 b3 b2 b1 b0] -> [b5 b3 b2 b4 b1 b0].
// Makes the S^T output registers exactly the PV B-fragment.
__device__ __forceinline__ int kperm(int r) {
    return (r & 0x23) | ((r & 0x0C) << 1) | ((r & 0x10) >> 2);
}

// ---------------------------------------------------------------------------
// Kernel 1: GroupNorm partial sums. 1024 blocks (16 groups x 64 chunks).
__global__ __launch_bounds__(256) void gn_part_kernel(const float* __restrict__ x,
                                                      float* __restrict__ partials) {
    const int bg = blockIdx.x >> 6, ch = blockIdx.x & 63;
    const float4* p = (const float4*)(x + (size_t)bg * CPG * N_TOK) + ch * 512;
    float s = 0.f, ss = 0.f;
#pragma unroll
    for (int r = 0; r < 2; ++r) {
        float4 v = p[threadIdx.x + (r << 8)];
        s  += v.x + v.y + v.z + v.w;
        ss += v.x * v.x + v.y * v.y + v.z * v.z + v.w * v.w;
    }
#pragma unroll
    for (int off = 32; off > 0; off >>= 1) {
        s  += __shfl_down(s, off);
        ss += __shfl_down(ss, off);
    }
    __shared__ float ls[4], lss[4];
    const int lane = threadIdx.x & 63, wid = threadIdx.x >> 6;
    if (lane == 0) { ls[wid] = s; lss[wid] = ss; }
    __syncthreads();
    if (threadIdx.x == 0) {
        partials[blockIdx.x * 2 + 0] = ls[0] + ls[1] + ls[2] + ls[3];
        partials[blockIdx.x * 2 + 1] = lss[0] + lss[1] + lss[2] + lss[3];
    }
}

// ---------------------------------------------------------------------------
// Kernel 2: fused GroupNorm finalize + apply + QKV GEMM, bf16 MFMA.
// q,k out: [(s*B+b)*HEADS+h][n][d] bf16 (q pre-scaled by QK_SCALE)
// v   out: [b*HEADS+h][d][n] bf16
__global__ __launch_bounds__(256) void qkv_gemm_kernel(
    const float* __restrict__ x, const float* __restrict__ partials,
    const float* __restrict__ norm_w, const float* __restrict__ norm_b,
    const float* __restrict__ qkv_w, const float* __restrict__ qkv_b,
    unsigned short* __restrict__ qkvb) {
    __shared__ unsigned short Ws[64][PSB];  // [o][c] bf16
    __shared__ unsigned short Xt[64][PSB];  // [n][c] bf16 (transposed xn)
    __shared__ float stat_s[GROUPS][2];
    const int n0 = blockIdx.x * 64;
    const int o0 = blockIdx.y * 64;
    const int b  = blockIdx.z;
    const int tid = threadIdx.x;
    const int lane = tid & 63, w = tid >> 6;
    const int lo = lane & 15, hi = lane >> 4;

    // finalize GroupNorm stats from partials (each block, redundantly; cheap)
    {
        const int g = tid >> 5, sub = tid & 31;
        const float* pp = partials + (((size_t)b * GROUPS + g) * 64 + sub * 2) * 2;
        float4 v = *(const float4*)pp;
        float s = v.x + v.z, ss = v.y + v.w;
#pragma unroll
        for (int off = 16; off > 0; off >>= 1) {
            s  += __shfl_down(s, off, 32);
            ss += __shfl_down(ss, off, 32);
        }
        if (sub == 0) {
            const float inv = 1.f / (float)(CPG * N_TOK);
            float mean = s * inv;
            float var  = ss * inv - mean * mean;
            stat_s[g][0] = mean;
            stat_s[g][1] = rsqrtf(var + EPS);
        }
        __syncthreads();
    }

    f32x4 acc[4] = {};
    for (int k0 = 0; k0 < C_DIM; k0 += 64) {
#pragma unroll
        for (int r = 0; r < 4; ++r) {
            int idx = tid + (r << 8);
            int row = idx >> 4, col4 = (idx & 15) << 2;
            float4 wv = *(const float4*)(qkv_w + (size_t)(o0 + row) * C_DIM + k0 + col4);
            u16x4v o;
            o[0] = f2bf(wv.x); o[1] = f2bf(wv.y); o[2] = f2bf(wv.z); o[3] = f2bf(wv.w);
            *(u16x4v*)&Ws[row][col4] = o;
        }
#pragma unroll
        for (int r = 0; r < 4; ++r) {
            int idx = tid + (r << 8);
            int crow = idx >> 4, col4 = (idx & 15) << 2;
            int c = k0 + crow;
            int g = c >> 5;
            float ww = norm_w[c] * stat_s[g][1];
            float bb = norm_b[c] - stat_s[g][0] * ww;
            float4 v = *(const float4*)(x + ((size_t)b * C_DIM + c) * N_TOK + n0 + col4);
            Xt[col4 + 0][crow] = f2bf(v.x * ww + bb);
            Xt[col4 + 1][crow] = f2bf(v.y * ww + bb);
            Xt[col4 + 2][crow] = f2bf(v.z * ww + bb);
            Xt[col4 + 3][crow] = f2bf(v.w * ww + bb);
        }
        __syncthreads();
#pragma unroll
        for (int ck = 0; ck < 2; ++ck) {
            bf16x8 aw = *(const bf16x8*)&Ws[w * 16 + lo][ck * 32 + hi * 8];
#pragma unroll
            for (int nb = 0; nb < 4; ++nb)
                acc[nb] = __builtin_amdgcn_mfma_f32_16x16x32_bf16(
                    aw, *(const bf16x8*)&Xt[nb * 16 + lo][ck * 32 + hi * 8], acc[nb], 0, 0, 0);
        }
        __syncthreads();
    }

    const int sidx = o0 >> 8;           // 0=q, 1=k, 2=v
    const int head = (o0 >> 6) & 3;
    const int od = w * 16 + hi * 4;     // d within head (+i)
    float bias[4];
#pragma unroll
    for (int i = 0; i < 4; ++i) bias[i] = qkv_b[o0 + od + i];
    const size_t plane = (size_t)N_TOK * HD;

    if (sidx < 2) {
        const float sc = (sidx == 0) ? QK_SCALE : 1.0f;
        unsigned short* base = qkvb + ((size_t)(sidx * B_DIM + b) * HEADS + head) * plane;
#pragma unroll
        for (int nb = 0; nb < 4; ++nb) {
            int n = n0 + nb * 16 + lo;
            u16x4v o;
#pragma unroll
            for (int i = 0; i < 4; ++i) o[i] = f2bf((acc[nb][i] + bias[i]) * sc);
            *(u16x4v*)(base + (size_t)n * HD + od) = o;
        }
    } else {
        unsigned short* base = qkvb + (size_t)2 * B_DIM * HEADS * plane
                             + ((size_t)b * HEADS + head) * plane;
#pragma unroll
        for (int nb = 0; nb < 4; ++nb)
#pragma unroll
            for (int i = 0; i < 4; ++i)
                base[(size_t)(od + i) * N_TOK + n0 + nb * 16 + lo] = f2bf(acc[nb][i] + bias[i]);
    }
}

// ---------------------------------------------------------------------------
// Kernel 3: bf16 MFMA flash attention, swapped-operand (S^T), K-split x4.
// global_load_lds double-buffered staging (linear LDS dest, pre-swizzled
// global source: kperm row + col16^row&7 XOR), ONE barrier per tile.
__global__ __launch_bounds__(256) void attn_kernel(const unsigned short* __restrict__ qkvb,
                                                   unsigned short* __restrict__ obuf,
                                                   float* __restrict__ rbuf) {
    const int bh = blockIdx.x & 7;            // b*HEADS + head
    const int ks = (blockIdx.x >> 3) & 3;     // key-split quarter
    const int q0 = (blockIdx.x >> 5) * 64;
    const size_t plane = (size_t)N_TOK * HD;
    const unsigned short* Qg  = qkvb + (size_t)bh * plane;
    const unsigned short* Kg  = qkvb + (size_t)(B_DIM * HEADS + bh) * plane;
    const unsigned short* Vtg = qkvb + (size_t)2 * B_DIM * HEADS * plane + (size_t)bh * plane;

    __shared__ unsigned short Ks[2][64][64];  // [buf][perm key row][d] (col-swizzled)
    __shared__ unsigned short Vt[2][64][64];  // [buf][d][key]          (col-swizzled)

    const int tid  = threadIdx.x;
    const int lane = tid & 63;
    const int wid  = tid >> 6;
    const int lo   = lane & 15;
    const int hi   = lane >> 4;

    // Q fragment (B-operand of S^T mfma): q = q0+wid*16+lo, d-chunks c*32+hi*8
    bf16x8 qf[2];
#pragma unroll
    for (int c = 0; c < 2; ++c)
        qf[c] = *(const bf16x8*)(Qg + (size_t)(q0 + wid * 16 + lo) * HD + c * 32 + hi * 8);

    // staging geometry: wave wid covers rows [wid*16, wid*16+16) via 2 DMA instrs.
    // lane writes LDS (row = r0 + lane/8, col16 = lane&7); source pre-swizzled.
    int krow[2], kcol[2], vrow[2], vcol[2];
#pragma unroll
    for (int i = 0; i < 2; ++i) {
        int row = wid * 16 + i * 8 + (lane >> 3);
        int c16 = (lane & 7) ^ (row & 7);
        krow[i] = kperm(row);
        kcol[i] = c16 * 8;
        vrow[i] = row;
        vcol[i] = c16 * 8;
    }
    // swizzled read column (elements) per d-chunk c: ((c*4+hi)^(lo&7))*8
    int rcol[2];
#pragma unroll
    for (int c = 0; c < 2; ++c) rcol[c] = (((c * 4 + hi) ^ (lo & 7)) << 3);

#define STAGE_KV(bufi, kbase)                                                          \
    do {                                                                               \
        _Pragma("unroll")                                                              \
        for (int i_ = 0; i_ < 2; ++i_) {                                               \
            gload16(Kg + (size_t)((kbase) + krow[i_]) * HD + kcol[i_],                 \
                    &Ks[bufi][wid * 16 + i_ * 8][0]);                                  \
            gload16(Vtg + (size_t)vrow[i_] * N_TOK + (kbase) + vcol[i_],               \
                    &Vt[bufi][wid * 16 + i_ * 8][0]);                                  \
        }                                                                              \
    } while (0)

    const int kt0 = ks * (NKT / KSPLIT), ktE = kt0 + NKT / KSPLIT;

    f32x4 acc[4] = {};   // acc[db][i] = O^T[d = db*16+hi*4+i][q = q0+wid*16+lo]
    float m = -1e30f, l = 0.f;

    STAGE_KV(0, kt0 * 64);
    __syncthreads();   // drains the DMA (vmcnt 0) + barrier

    for (int kt = kt0; kt < ktE; ++kt) {
        const int cur = kt & 1;
        if (kt + 1 < ktE) STAGE_KV(cur ^ 1, (kt + 1) * 64);

        // S^T = K Q^T. s4[kb][i] = S^T[lds key row = kb*16+hi*4+i][query lo]
        f32x4 s4[4] = {};
        __builtin_amdgcn_s_setprio(1);
#pragma unroll
        for (int kb = 0; kb < 4; ++kb)
#pragma unroll
            for (int c = 0; c < 2; ++c)
                s4[kb] = __builtin_amdgcn_mfma_f32_16x16x32_bf16(
                    *(const bf16x8*)&Ks[cur][kb * 16 + lo][rcol[c]], qf[c], s4[kb], 0, 0, 0);
        __builtin_amdgcn_s_setprio(0);

        // lane-local tile max (16 values); nested fmaxf fuses to v_max3
        float r0 = fmaxf(fmaxf(fmaxf(s4[0][0], s4[0][1]), s4[0][2]), s4[0][3]);
        float r1 = fmaxf(fmaxf(fmaxf(s4[1][0], s4[1][1]), s4[1][2]), s4[1][3]);
        float r2 = fmaxf(fmaxf(fmaxf(s4[2][0], s4[2][1]), s4[2][2]), s4[2][3]);
        float r3 = fmaxf(fmaxf(fmaxf(s4[3][0], s4[3][1]), s4[3][2]), s4[3][3]);
        float rm = fmaxf(fmaxf(fmaxf(r0, r1), r2), r3);

        // defer-max (T13) with LOCAL max check: cross-lane reduce only when needed.
        // Common path keeps old m (P bounded by 2^8) and skips both shfls.
        if (__any(rm > m + 8.0f)) {
            float rmx = rm;
            rmx = fmaxf(rmx, __shfl_xor(rmx, 16));
            rmx = fmaxf(rmx, __shfl_xor(rmx, 32));
            const float mn = fmaxf(m, rmx);
            const float fi = exp2_fast(m - mn);
            m = mn;
            l *= fi;
#pragma unroll
            for (int db = 0; db < 4; ++db)
#pragma unroll
                for (int i = 0; i < 4; ++i) acc[db][i] *= fi;
        }

        float p[4][4];
        float ps = 0.f;
#pragma unroll
        for (int kb = 0; kb < 4; ++kb)
#pragma unroll
            for (int i = 0; i < 4; ++i) {
                p[kb][i] = exp2_fast(s4[kb][i] - m);
                ps += p[kb][i];
            }
        l += ps;

        // pack P into PV B-fragment: pf[c][j] = p[2c + (j>>2)][j&3]
        bf16x8 pf[2];
#pragma unroll
        for (int c = 0; c < 2; ++c)
#pragma unroll
            for (int j = 0; j < 8; ++j) pf[c][j] = (__bf16)p[2 * c + (j >> 2)][j & 3];

        // O^T += V^T P^T
        __builtin_amdgcn_s_setprio(1);
#pragma unroll
        for (int db = 0; db < 4; ++db)
#pragma unroll
            for (int c = 0; c < 2; ++c)
                acc[db] = __builtin_amdgcn_mfma_f32_16x16x32_bf16(
                    *(const bf16x8*)&Vt[cur][db * 16 + lo][rcol[c]], pf[c], acc[db], 0, 0, 0);
        __builtin_amdgcn_s_setprio(0);

        // one barrier per tile: drains this wave's DMA (implicit vmcnt 0)
        // and guarantees all waves finished reading buf[cur].
        __syncthreads();
    }
#undef STAGE_KV

    // epilogue: normalized bf16 partial O + log-sum-exp r
    float l1 = l + __shfl_xor(l, 16);
    float lt = l1 + __shfl_xor(l1, 32);
    const float inv = 1.f / lt;
    const int n = q0 + wid * 16 + lo;
    unsigned short* ob = obuf + ((size_t)(ks * 8 + bh) * N_TOK + n) * HD;
#pragma unroll
    for (int db = 0; db < 4; ++db) {
        u16x4v o;
#pragma unroll
        for (int i = 0; i < 4; ++i) o[i] = f2bf(acc[db][i] * inv);
        *(u16x4v*)(ob + db * 16 + hi * 4) = o;
    }
    if (hi == 0)
        rbuf[(size_t)(ks * 8 + bh) * N_TOK + n] = m + __builtin_amdgcn_logf(lt);
}

// ---------------------------------------------------------------------------
// Kernel 4: output projection + bias + residual, bf16 MFMA.
// K-split combine fused into the h staging (reads obuf/rbuf directly).
__global__ __launch_bounds__(256) void proj_kernel(
    const unsigned short* __restrict__ obuf, const float* __restrict__ rbuf,
    const float* __restrict__ proj_w, const float* __restrict__ proj_b,
    const float* __restrict__ x, float* __restrict__ out) {
    __shared__ unsigned short Ws[64][PSB];  // [o][c]
    __shared__ unsigned short Hs[64][PSB];  // [n][c-within-head]
    const int n0 = blockIdx.x * 64;
    const int o0 = blockIdx.y * 64;
    const int b  = blockIdx.z;
    const int tid = threadIdx.x;
    const int lane = tid & 63, w = tid >> 6;
    const int lo = lane & 15, hi = lane >> 4;
    f32x4 acc[4] = {};

    for (int k0 = 0; k0 < C_DIM; k0 += 64) {
#pragma unroll
        for (int r = 0; r < 4; ++r) {
            int idx = tid + (r << 8);
            int row = idx >> 4, col4 = (idx & 15) << 2;
            float4 wv = *(const float4*)(proj_w + (size_t)(o0 + row) * C_DIM + k0 + col4);
            u16x4v o;
            o[0] = f2bf(wv.x); o[1] = f2bf(wv.y); o[2] = f2bf(wv.z); o[3] = f2bf(wv.w);
            *(u16x4v*)&Ws[row][col4] = o;
        }
        // stage h[n][k0..k0+64): head = k0>>6; combine the 4 K-split partials
        {
            const int head = k0 >> 6;
            const int bh = b * HEADS + head;
#pragma unroll
            for (int r = 0; r < 2; ++r) {
                int idx = tid + (r << 8);
                int row = idx >> 3, blk = idx & 7;   // n-row in tile, 8-d chunk
                int n = n0 + row;
                float rr[KSPLIT], M = -1e30f;
#pragma unroll
                for (int k = 0; k < KSPLIT; ++k) {
                    rr[k] = rbuf[(size_t)(k * 8 + bh) * N_TOK + n];
                    M = fmaxf(M, rr[k]);
                }
                float wk[KSPLIT], tot = 0.f;
#pragma unroll
                for (int k = 0; k < KSPLIT; ++k) { wk[k] = exp2_fast(rr[k] - M); tot += wk[k]; }
                const float inv = 1.f / tot;
                float a[8] = {};
#pragma unroll
                for (int k = 0; k < KSPLIT; ++k) {
                    u16x8v v = *(const u16x8v*)(obuf
                        + ((size_t)(k * 8 + bh) * N_TOK + n) * HD + blk * 8);
#pragma unroll
                    for (int j = 0; j < 8; ++j) a[j] += wk[k] * bf2f(v[j]);
                }
                u16x8v o;
#pragma unroll
                for (int j = 0; j < 8; ++j) o[j] = f2bf(a[j] * inv);
                *(u16x8v*)&Hs[row][blk * 8] = o;
            }
        }
        __syncthreads();
#pragma unroll
        for (int ck = 0; ck < 2; ++ck) {
            bf16x8 aw = *(const bf16x8*)&Ws[w * 16 + lo][ck * 32 + hi * 8];
#pragma unroll
            for (int nb = 0; nb < 4; ++nb)
                acc[nb] = __builtin_amdgcn_mfma_f32_16x16x32_bf16(
                    aw, *(const bf16x8*)&Hs[nb * 16 + lo][ck * 32 + hi * 8], acc[nb], 0, 0, 0);
        }
        __syncthreads();
    }

#pragma unroll
    for (int nb = 0; nb < 4; ++nb) {
#pragma unroll
        for (int i = 0; i < 4; ++i) {
            int o = o0 + w * 16 + hi * 4 + i;
            size_t addr = ((size_t)b * C_DIM + o) * N_TOK + n0 + nb * 16 + lo;
            out[addr] = acc[nb][i] + proj_b[o] + x[addr];
        }
    }
}

// ---------------------------------------------------------------------------
extern "C" void kernel_launch(void* const* d_in, const int* in_sizes, int n_in,
                              void* d_out, int out_size, void* d_ws, size_t ws_size,
                              hipStream_t stream) {
    const float* x      = (const float*)d_in[0];
    const float* norm_w = (const float*)d_in[1];
    const float* norm_b = (const float*)d_in[2];
    const float* qkv_w  = (const float*)d_in[3];
    const float* qkv_b  = (const float*)d_in[4];
    const float* proj_w = (const float*)d_in[5];
    const float* proj_b = (const float*)d_in[6];
    float* out = (float*)d_out;

    // ws: partials f32[2048] | qkvb bf16 (12.6MB)
    //   | obuf bf16 [4][8][N][HD] (16.8MB) | rbuf f32 [4][8][N] (512KB) ~= 29.9MB
    float* partials = (float*)d_ws;
    unsigned short* qkvb = (unsigned short*)(partials + 2048);
    unsigned short* obuf = qkvb + (size_t)3 * B_DIM * HEADS * N_TOK * HD;
    float* rbuf = (float*)(obuf + (size_t)KSPLIT * B_DIM * HEADS * N_TOK * HD);

    gn_part_kernel<<<B_DIM * GROUPS * 64, 256, 0, stream>>>(x, partials);
    qkv_gemm_kernel<<<dim3(N_TOK / 64, 3 * C_DIM / 64, B_DIM), 256, 0, stream>>>(
        x, partials, norm_w, norm_b, qkv_w, qkv_b, qkvb);
    attn_kernel<<<(N_TOK / 64) * B_DIM * HEADS * KSPLIT, 256, 0, stream>>>(qkvb, obuf, rbuf);
    proj_kernel<<<dim3(N_TOK / 64, C_DIM / 64, B_DIM), 256, 0, stream>>>(
        obuf, rbuf, proj_w, proj_b, x, out);
}

// Round 8
// 103.319 us; speedup vs baseline: 10.9042x; 1.0185x over previous
//
#include <hip/hip_runtime.h>
#include <math.h>

#define B_DIM 2
#define C_DIM 256
#define N_TOK 4096      // 16*16*16
#define HEADS 4
#define HD 64
#define GROUPS 8
#define CPG (C_DIM / GROUPS)   // 32
#define EPS 1e-5f
#define PSB 72          // padded bf16 LDS row stride (GEMM kernels)
#define QK_SCALE 0.180336880f  // 0.125 * log2(e), folded into Q
#define KSPLIT 4
#define NKT (N_TOK / 64)       // 64 key tiles total
#define QBLK 128               // queries per attention block (2 frags/wave)

typedef __bf16 bf16x8 __attribute__((ext_vector_type(8)));
typedef float  f32x4  __attribute__((ext_vector_type(4)));
typedef unsigned short u16x4v __attribute__((ext_vector_type(4)));
typedef unsigned short u16x8v __attribute__((ext_vector_type(8)));

__device__ __forceinline__ unsigned short f2bf(float f) {
    return __builtin_bit_cast(unsigned short, (__bf16)f);
}
__device__ __forceinline__ float bf2f(unsigned short u) {
    return (float)__builtin_bit_cast(__bf16, u);
}
// raw v_exp_f32 (2^x); inputs bounded so no OCML fixup needed
__device__ __forceinline__ float exp2_fast(float x) { return __builtin_amdgcn_exp2f(x); }

// async global->LDS, 16B per lane, wave-uniform LDS base (linear dest)
__device__ __forceinline__ void gload16(const unsigned short* g, unsigned short* l) {
    __builtin_amdgcn_global_load_lds(
        (const __attribute__((address_space(1))) unsigned int*)g,
        (__attribute__((address_space(3))) unsigned int*)l, 16, 0, 0);
}

// K-staging row permutation: [b5 b4 b3 b2 b1 b0] -> [b5 b3 b2 b4 b1 b0].
// Makes the S^T output registers exactly the PV B-fragment.
__device__ __forceinline__ int kperm(int r) {
    return (r & 0x23) | ((r & 0x0C) << 1) | ((r & 0x10) >> 2);
}

// ---------------------------------------------------------------------------
// Kernel 1: GroupNorm partial sums. 1024 blocks (16 groups x 64 chunks).
__global__ __launch_bounds__(256) void gn_part_kernel(const float* __restrict__ x,
                                                      float* __restrict__ partials) {
    const int bg = blockIdx.x >> 6, ch = blockIdx.x & 63;
    const float4* p = (const float4*)(x + (size_t)bg * CPG * N_TOK) + ch * 512;
    float s = 0.f, ss = 0.f;
#pragma unroll
    for (int r = 0; r < 2; ++r) {
        float4 v = p[threadIdx.x + (r << 8)];
        s  += v.x + v.y + v.z + v.w;
        ss += v.x * v.x + v.y * v.y + v.z * v.z + v.w * v.w;
    }
#pragma unroll
    for (int off = 32; off > 0; off >>= 1) {
        s  += __shfl_down(s, off);
        ss += __shfl_down(ss, off);
    }
    __shared__ float ls[4], lss[4];
    const int lane = threadIdx.x & 63, wid = threadIdx.x >> 6;
    if (lane == 0) { ls[wid] = s; lss[wid] = ss; }
    __syncthreads();
    if (threadIdx.x == 0) {
        partials[blockIdx.x * 2 + 0] = ls[0] + ls[1] + ls[2] + ls[3];
        partials[blockIdx.x * 2 + 1] = lss[0] + lss[1] + lss[2] + lss[3];
    }
}

// ---------------------------------------------------------------------------
// Kernel 2: fused GroupNorm finalize + apply + QKV GEMM, bf16 MFMA.
// q,k out: [(s*B+b)*HEADS+h][n][d] bf16 (q pre-scaled by QK_SCALE)
// v   out: [b*HEADS+h][d][n] bf16
__global__ __launch_bounds__(256) void qkv_gemm_kernel(
    const float* __restrict__ x, const float* __restrict__ partials,
    const float* __restrict__ norm_w, const float* __restrict__ norm_b,
    const float* __restrict__ qkv_w, const float* __restrict__ qkv_b,
    unsigned short* __restrict__ qkvb) {
    __shared__ unsigned short Ws[64][PSB];  // [o][c] bf16
    __shared__ unsigned short Xt[64][PSB];  // [n][c] bf16 (transposed xn)
    __shared__ float stat_s[GROUPS][2];
    const int n0 = blockIdx.x * 64;
    const int o0 = blockIdx.y * 64;
    const int b  = blockIdx.z;
    const int tid = threadIdx.x;
    const int lane = tid & 63, w = tid >> 6;
    const int lo = lane & 15, hi = lane >> 4;

    // finalize GroupNorm stats from partials (each block, redundantly; cheap)
    {
        const int g = tid >> 5, sub = tid & 31;
        const float* pp = partials + (((size_t)b * GROUPS + g) * 64 + sub * 2) * 2;
        float4 v = *(const float4*)pp;
        float s = v.x + v.z, ss = v.y + v.w;
#pragma unroll
        for (int off = 16; off > 0; off >>= 1) {
            s  += __shfl_down(s, off, 32);
            ss += __shfl_down(ss, off, 32);
        }
        if (sub == 0) {
            const float inv = 1.f / (float)(CPG * N_TOK);
            float mean = s * inv;
            float var  = ss * inv - mean * mean;
            stat_s[g][0] = mean;
            stat_s[g][1] = rsqrtf(var + EPS);
        }
        __syncthreads();
    }

    f32x4 acc[4] = {};
    for (int k0 = 0; k0 < C_DIM; k0 += 64) {
#pragma unroll
        for (int r = 0; r < 4; ++r) {
            int idx = tid + (r << 8);
            int row = idx >> 4, col4 = (idx & 15) << 2;
            float4 wv = *(const float4*)(qkv_w + (size_t)(o0 + row) * C_DIM + k0 + col4);
            u16x4v o;
            o[0] = f2bf(wv.x); o[1] = f2bf(wv.y); o[2] = f2bf(wv.z); o[3] = f2bf(wv.w);
            *(u16x4v*)&Ws[row][col4] = o;
        }
#pragma unroll
        for (int r = 0; r < 4; ++r) {
            int idx = tid + (r << 8);
            int crow = idx >> 4, col4 = (idx & 15) << 2;
            int c = k0 + crow;
            int g = c >> 5;
            float ww = norm_w[c] * stat_s[g][1];
            float bb = norm_b[c] - stat_s[g][0] * ww;
            float4 v = *(const float4*)(x + ((size_t)b * C_DIM + c) * N_TOK + n0 + col4);
            Xt[col4 + 0][crow] = f2bf(v.x * ww + bb);
            Xt[col4 + 1][crow] = f2bf(v.y * ww + bb);
            Xt[col4 + 2][crow] = f2bf(v.z * ww + bb);
            Xt[col4 + 3][crow] = f2bf(v.w * ww + bb);
        }
        __syncthreads();
#pragma unroll
        for (int ck = 0; ck < 2; ++ck) {
            bf16x8 aw = *(const bf16x8*)&Ws[w * 16 + lo][ck * 32 + hi * 8];
#pragma unroll
            for (int nb = 0; nb < 4; ++nb)
                acc[nb] = __builtin_amdgcn_mfma_f32_16x16x32_bf16(
                    aw, *(const bf16x8*)&Xt[nb * 16 + lo][ck * 32 + hi * 8], acc[nb], 0, 0, 0);
        }
        __syncthreads();
    }

    const int sidx = o0 >> 8;           // 0=q, 1=k, 2=v
    const int head = (o0 >> 6) & 3;
    const int od = w * 16 + hi * 4;     // d within head (+i)
    float bias[4];
#pragma unroll
    for (int i = 0; i < 4; ++i) bias[i] = qkv_b[o0 + od + i];
    const size_t plane = (size_t)N_TOK * HD;

    if (sidx < 2) {
        const float sc = (sidx == 0) ? QK_SCALE : 1.0f;
        unsigned short* base = qkvb + ((size_t)(sidx * B_DIM + b) * HEADS + head) * plane;
#pragma unroll
        for (int nb = 0; nb < 4; ++nb) {
            int n = n0 + nb * 16 + lo;
            u16x4v o;
#pragma unroll
            for (int i = 0; i < 4; ++i) o[i] = f2bf((acc[nb][i] + bias[i]) * sc);
            *(u16x4v*)(base + (size_t)n * HD + od) = o;
        }
    } else {
        unsigned short* base = qkvb + (size_t)2 * B_DIM * HEADS * plane
                             + ((size_t)b * HEADS + head) * plane;
#pragma unroll
        for (int nb = 0; nb < 4; ++nb)
#pragma unroll
            for (int i = 0; i < 4; ++i)
                base[(size_t)(od + i) * N_TOK + n0 + nb * 16 + lo] = f2bf(acc[nb][i] + bias[i]);
    }
}

// ---------------------------------------------------------------------------
// Kernel 3: bf16 MFMA flash attention, swapped-operand (S^T), K-split x4,
// QBLK=128 (two q-fragments per wave; K/V LDS fragments shared across frags).
// global_load_lds dbuf staging (linear dest, pre-swizzled source), 1 barrier/tile.
__global__ __launch_bounds__(256) void attn_kernel(const unsigned short* __restrict__ qkvb,
                                                   unsigned short* __restrict__ obuf,
                                                   float* __restrict__ rbuf) {
    const int bh = blockIdx.x & 7;            // b*HEADS + head
    const int ks = (blockIdx.x >> 3) & 3;     // key-split quarter
    const int q0 = (blockIdx.x >> 5) * QBLK;
    const size_t plane = (size_t)N_TOK * HD;
    const unsigned short* Qg  = qkvb + (size_t)bh * plane;
    const unsigned short* Kg  = qkvb + (size_t)(B_DIM * HEADS + bh) * plane;
    const unsigned short* Vtg = qkvb + (size_t)2 * B_DIM * HEADS * plane + (size_t)bh * plane;

    __shared__ unsigned short Ks[2][64][64];  // [buf][perm key row][d] (col-swizzled)
    __shared__ unsigned short Vt[2][64][64];  // [buf][d][key]          (col-swizzled)

    const int tid  = threadIdx.x;
    const int lane = tid & 63;
    const int wid  = tid >> 6;
    const int lo   = lane & 15;
    const int hi   = lane >> 4;

    // Q fragments: frag f covers q = q0 + wid*32 + f*16 + lo, d-chunks c*32+hi*8
    bf16x8 qf[2][2];
#pragma unroll
    for (int f = 0; f < 2; ++f)
#pragma unroll
        for (int c = 0; c < 2; ++c)
            qf[f][c] = *(const bf16x8*)(Qg + (size_t)(q0 + wid * 32 + f * 16 + lo) * HD
                                            + c * 32 + hi * 8);

    // staging geometry: wave wid covers rows [wid*16, wid*16+16) via 2 DMA instrs.
    int krow[2], kcol[2], vrow[2], vcol[2];
#pragma unroll
    for (int i = 0; i < 2; ++i) {
        int row = wid * 16 + i * 8 + (lane >> 3);
        int c16 = (lane & 7) ^ (row & 7);
        krow[i] = kperm(row);
        kcol[i] = c16 * 8;
        vrow[i] = row;
        vcol[i] = c16 * 8;
    }
    // swizzled read column (elements) per d-chunk c: ((c*4+hi)^(lo&7))*8
    int rcol[2];
#pragma unroll
    for (int c = 0; c < 2; ++c) rcol[c] = (((c * 4 + hi) ^ (lo & 7)) << 3);

#define STAGE_KV(bufi, kbase)                                                          \
    do {                                                                               \
        _Pragma("unroll")                                                              \
        for (int i_ = 0; i_ < 2; ++i_) {                                               \
            gload16(Kg + (size_t)((kbase) + krow[i_]) * HD + kcol[i_],                 \
                    &Ks[bufi][wid * 16 + i_ * 8][0]);                                  \
            gload16(Vtg + (size_t)vrow[i_] * N_TOK + (kbase) + vcol[i_],               \
                    &Vt[bufi][wid * 16 + i_ * 8][0]);                                  \
        }                                                                              \
    } while (0)

    const int kt0 = ks * (NKT / KSPLIT), ktE = kt0 + NKT / KSPLIT;

    f32x4 acc[2][4] = {};   // acc[f][db][i] = O^T[d=db*16+hi*4+i][q of frag f]
    float m[2] = {-1e30f, -1e30f}, l[2] = {0.f, 0.f};

    STAGE_KV(0, kt0 * 64);
    __syncthreads();   // drains the DMA (vmcnt 0) + barrier

    for (int kt = kt0; kt < ktE; ++kt) {
        const int cur = kt & 1;
        if (kt + 1 < ktE) STAGE_KV(cur ^ 1, (kt + 1) * 64);

        // S^T = K Q^T for BOTH q-frags; K fragment read once, used twice.
        f32x4 s4[2][4] = {};
        __builtin_amdgcn_s_setprio(1);
#pragma unroll
        for (int kb = 0; kb < 4; ++kb)
#pragma unroll
            for (int c = 0; c < 2; ++c) {
                bf16x8 kf = *(const bf16x8*)&Ks[cur][kb * 16 + lo][rcol[c]];
                s4[0][kb] = __builtin_amdgcn_mfma_f32_16x16x32_bf16(kf, qf[0][c], s4[0][kb], 0, 0, 0);
                s4[1][kb] = __builtin_amdgcn_mfma_f32_16x16x32_bf16(kf, qf[1][c], s4[1][kb], 0, 0, 0);
            }
        __builtin_amdgcn_s_setprio(0);

        // per-frag: softmax then PV (PV(f0) MFMAs overlap softmax(f1) VALU)
#pragma unroll
        for (int f = 0; f < 2; ++f) {
            float r0 = fmaxf(fmaxf(fmaxf(s4[f][0][0], s4[f][0][1]), s4[f][0][2]), s4[f][0][3]);
            float r1 = fmaxf(fmaxf(fmaxf(s4[f][1][0], s4[f][1][1]), s4[f][1][2]), s4[f][1][3]);
            float r2 = fmaxf(fmaxf(fmaxf(s4[f][2][0], s4[f][2][1]), s4[f][2][2]), s4[f][2][3]);
            float r3 = fmaxf(fmaxf(fmaxf(s4[f][3][0], s4[f][3][1]), s4[f][3][2]), s4[f][3][3]);
            float rm = fmaxf(fmaxf(fmaxf(r0, r1), r2), r3);

            // defer-max (T13) with LOCAL max check; cross-lane reduce only when needed
            if (__any(rm > m[f] + 8.0f)) {
                float rmx = rm;
                rmx = fmaxf(rmx, __shfl_xor(rmx, 16));
                rmx = fmaxf(rmx, __shfl_xor(rmx, 32));
                const float mn = fmaxf(m[f], rmx);
                const float fi = exp2_fast(m[f] - mn);
                m[f] = mn;
                l[f] *= fi;
#pragma unroll
                for (int db = 0; db < 4; ++db)
#pragma unroll
                    for (int i = 0; i < 4; ++i) acc[f][db][i] *= fi;
            }

            float p[4][4];
            float ps = 0.f;
#pragma unroll
            for (int kb = 0; kb < 4; ++kb)
#pragma unroll
                for (int i = 0; i < 4; ++i) {
                    p[kb][i] = exp2_fast(s4[f][kb][i] - m[f]);
                    ps += p[kb][i];
                }
            l[f] += ps;

            // pack P into PV B-fragment: pf[c][j] = p[2c + (j>>2)][j&3]
            bf16x8 pf[2];
#pragma unroll
            for (int c = 0; c < 2; ++c)
#pragma unroll
                for (int j = 0; j < 8; ++j) pf[c][j] = (__bf16)p[2 * c + (j >> 2)][j & 3];

            // O^T += V^T P^T
            __builtin_amdgcn_s_setprio(1);
#pragma unroll
            for (int db = 0; db < 4; ++db)
#pragma unroll
                for (int c = 0; c < 2; ++c) {
                    bf16x8 vf = *(const bf16x8*)&Vt[cur][db * 16 + lo][rcol[c]];
                    acc[f][db] = __builtin_amdgcn_mfma_f32_16x16x32_bf16(vf, pf[c], acc[f][db], 0, 0, 0);
                }
            __builtin_amdgcn_s_setprio(0);
        }

        // one barrier per tile: drains this wave's DMA (implicit vmcnt 0)
        // and guarantees all waves finished reading buf[cur].
        __syncthreads();
    }
#undef STAGE_KV

    // epilogue per frag: normalized bf16 partial O + log-sum-exp r
#pragma unroll
    for (int f = 0; f < 2; ++f) {
        float l1 = l[f] + __shfl_xor(l[f], 16);
        float lt = l1 + __shfl_xor(l1, 32);
        const float inv = 1.f / lt;
        const int n = q0 + wid * 32 + f * 16 + lo;
        unsigned short* ob = obuf + ((size_t)(ks * 8 + bh) * N_TOK + n) * HD;
#pragma unroll
        for (int db = 0; db < 4; ++db) {
            u16x4v o;
#pragma unroll
            for (int i = 0; i < 4; ++i) o[i] = f2bf(acc[f][db][i] * inv);
            *(u16x4v*)(ob + db * 16 + hi * 4) = o;
        }
        if (hi == 0)
            rbuf[(size_t)(ks * 8 + bh) * N_TOK + n] = m[f] + __builtin_amdgcn_logf(lt);
    }
}

// ---------------------------------------------------------------------------
// Kernel 4: output projection + bias + residual, bf16 MFMA.
// K-split combine fused into the h staging (reads obuf/rbuf directly).
__global__ __launch_bounds__(256) void proj_kernel(
    const unsigned short* __restrict__ obuf, const float* __restrict__ rbuf,
    const float* __restrict__ proj_w, const float* __restrict__ proj_b,
    const float* __restrict__ x, float* __restrict__ out) {
    __shared__ unsigned short Ws[64][PSB];  // [o][c]
    __shared__ unsigned short Hs[64][PSB];  // [n][c-within-head]
    const int n0 = blockIdx.x * 64;
    const int o0 = blockIdx.y * 64;
    const int b  = blockIdx.z;
    const int tid = threadIdx.x;
    const int lane = tid & 63, w = tid >> 6;
    const int lo = lane & 15, hi = lane >> 4;
    f32x4 acc[4] = {};

    for (int k0 = 0; k0 < C_DIM; k0 += 64) {
#pragma unroll
        for (int r = 0; r < 4; ++r) {
            int idx = tid + (r << 8);
            int row = idx >> 4, col4 = (idx & 15) << 2;
            float4 wv = *(const float4*)(proj_w + (size_t)(o0 + row) * C_DIM + k0 + col4);
            u16x4v o;
            o[0] = f2bf(wv.x); o[1] = f2bf(wv.y); o[2] = f2bf(wv.z); o[3] = f2bf(wv.w);
            *(u16x4v*)&Ws[row][col4] = o;
        }
        // stage h[n][k0..k0+64): head = k0>>6; combine the 4 K-split partials
        {
            const int head = k0 >> 6;
            const int bh = b * HEADS + head;
#pragma unroll
            for (int r = 0; r < 2; ++r) {
                int idx = tid + (r << 8);
                int row = idx >> 3, blk = idx & 7;   // n-row in tile, 8-d chunk
                int n = n0 + row;
                float rr[KSPLIT], M = -1e30f;
#pragma unroll
                for (int k = 0; k < KSPLIT; ++k) {
                    rr[k] = rbuf[(size_t)(k * 8 + bh) * N_TOK + n];
                    M = fmaxf(M, rr[k]);
                }
                float wk[KSPLIT], tot = 0.f;
#pragma unroll
                for (int k = 0; k < KSPLIT; ++k) { wk[k] = exp2_fast(rr[k] - M); tot += wk[k]; }
                const float inv = 1.f / tot;
                float a[8] = {};
#pragma unroll
                for (int k = 0; k < KSPLIT; ++k) {
                    u16x8v v = *(const u16x8v*)(obuf
                        + ((size_t)(k * 8 + bh) * N_TOK + n) * HD + blk * 8);
#pragma unroll
                    for (int j = 0; j < 8; ++j) a[j] += wk[k] * bf2f(v[j]);
                }
                u16x8v o;
#pragma unroll
                for (int j = 0; j < 8; ++j) o[j] = f2bf(a[j] * inv);
                *(u16x8v*)&Hs[row][blk * 8] = o;
            }
        }
        __syncthreads();
#pragma unroll
        for (int ck = 0; ck < 2; ++ck) {
            bf16x8 aw = *(const bf16x8*)&Ws[w * 16 + lo][ck * 32 + hi * 8];
#pragma unroll
            for (int nb = 0; nb < 4; ++nb)
                acc[nb] = __builtin_amdgcn_mfma_f32_16x16x32_bf16(
                    aw, *(const bf16x8*)&Hs[nb * 16 + lo][ck * 32 + hi * 8], acc[nb], 0, 0, 0);
        }
        __syncthreads();
    }

#pragma unroll
    for (int nb = 0; nb < 4; ++nb) {
#pragma unroll
        for (int i = 0; i < 4; ++i) {
            int o = o0 + w * 16 + hi * 4 + i;
            size_t addr = ((size_t)b * C_DIM + o) * N_TOK + n0 + nb * 16 + lo;
            out[addr] = acc[nb][i] + proj_b[o] + x[addr];
        }
    }
}

// ---------------------------------------------------------------------------
extern "C" void kernel_launch(void* const* d_in, const int* in_sizes, int n_in,
                              void* d_out, int out_size, void* d_ws, size_t ws_size,
                              hipStream_t stream) {
    const float* x      = (const float*)d_in[0];
    const float* norm_w = (const float*)d_in[1];
    const float* norm_b = (const float*)d_in[2];
    const float* qkv_w  = (const float*)d_in[3];
    const float* qkv_b  = (const float*)d_in[4];
    const float* proj_w = (const float*)d_in[5];
    const float* proj_b = (const float*)d_in[6];
    float* out = (float*)d_out;

    // ws: partials f32[2048] | qkvb bf16 (12.6MB)
    //   | obuf bf16 [4][8][N][HD] (16.8MB) | rbuf f32 [4][8][N] (512KB) ~= 29.9MB
    float* partials = (float*)d_ws;
    unsigned short* qkvb = (unsigned short*)(partials + 2048);
    unsigned short* obuf = qkvb + (size_t)3 * B_DIM * HEADS * N_TOK * HD;
    float* rbuf = (float*)(obuf + (size_t)KSPLIT * B_DIM * HEADS * N_TOK * HD);

    gn_part_kernel<<<B_DIM * GROUPS * 64, 256, 0, stream>>>(x, partials);
    qkv_gemm_kernel<<<dim3(N_TOK / 64, 3 * C_DIM / 64, B_DIM), 256, 0, stream>>>(
        x, partials, norm_w, norm_b, qkv_w, qkv_b, qkvb);
    attn_kernel<<<(N_TOK / QBLK) * B_DIM * HEADS * KSPLIT, 256, 0, stream>>>(qkvb, obuf, rbuf);
    proj_kernel<<<dim3(N_TOK / 64, C_DIM / 64, B_DIM), 256, 0, stream>>>(
        obuf, rbuf, proj_w, proj_b, x, out);
}

// Round 9
// 97.015 us; speedup vs baseline: 11.6127x; 1.0650x over previous
//
#include <hip/hip_runtime.h>
#include <math.h>

#define B_DIM 2
#define C_DIM 256
#define N_TOK 4096      // 16*16*16
#define HEADS 4
#define HD 64
#define GROUPS 8
#define CPG (C_DIM / GROUPS)   // 32
#define EPS 1e-5f
#define PSB 72          // padded bf16 LDS row stride (GEMM kernels)
#define QK_SCALE 0.180336880f  // 0.125 * log2(e), folded into Q
#define KSPLIT 4
#define NKT (N_TOK / 64)       // 64 key tiles total
#define QBLK 128               // queries per attention block (8 waves x 16 q)

typedef __bf16 bf16x8 __attribute__((ext_vector_type(8)));
typedef float  f32x4  __attribute__((ext_vector_type(4)));
typedef unsigned short u16x4v __attribute__((ext_vector_type(4)));
typedef unsigned short u16x8v __attribute__((ext_vector_type(8)));

__device__ __forceinline__ unsigned short f2bf(float f) {
    return __builtin_bit_cast(unsigned short, (__bf16)f);
}
__device__ __forceinline__ float bf2f(unsigned short u) {
    return (float)__builtin_bit_cast(__bf16, u);
}
// raw v_exp_f32 (2^x); inputs bounded so no OCML fixup needed
__device__ __forceinline__ float exp2_fast(float x) { return __builtin_amdgcn_exp2f(x); }

// async global->LDS, 16B per lane, wave-uniform LDS base (linear dest)
__device__ __forceinline__ void gload16(const unsigned short* g, unsigned short* l) {
    __builtin_amdgcn_global_load_lds(
        (const __attribute__((address_space(1))) unsigned int*)g,
        (__attribute__((address_space(3))) unsigned int*)l, 16, 0, 0);
}

// K-staging row permutation: [b5 b4 b3 b2 b1 b0] -> [b5 b3 b2 b4 b1 b0].
// Makes the S^T output registers exactly the PV B-fragment.
__device__ __forceinline__ int kperm(int r) {
    return (r & 0x23) | ((r & 0x0C) << 1) | ((r & 0x10) >> 2);
}

// ---------------------------------------------------------------------------
// Kernel 1: GroupNorm partial sums. 1024 blocks (16 groups x 64 chunks).
__global__ __launch_bounds__(256) void gn_part_kernel(const float* __restrict__ x,
                                                      float* __restrict__ partials) {
    const int bg = blockIdx.x >> 6, ch = blockIdx.x & 63;
    const float4* p = (const float4*)(x + (size_t)bg * CPG * N_TOK) + ch * 512;
    float s = 0.f, ss = 0.f;
#pragma unroll
    for (int r = 0; r < 2; ++r) {
        float4 v = p[threadIdx.x + (r << 8)];
        s  += v.x + v.y + v.z + v.w;
        ss += v.x * v.x + v.y * v.y + v.z * v.z + v.w * v.w;
    }
#pragma unroll
    for (int off = 32; off > 0; off >>= 1) {
        s  += __shfl_down(s, off);
        ss += __shfl_down(ss, off);
    }
    __shared__ float ls[4], lss[4];
    const int lane = threadIdx.x & 63, wid = threadIdx.x >> 6;
    if (lane == 0) { ls[wid] = s; lss[wid] = ss; }
    __syncthreads();
    if (threadIdx.x == 0) {
        partials[blockIdx.x * 2 + 0] = ls[0] + ls[1] + ls[2] + ls[3];
        partials[blockIdx.x * 2 + 1] = lss[0] + lss[1] + lss[2] + lss[3];
    }
}

// ---------------------------------------------------------------------------
// Kernel 2: fused GroupNorm finalize + apply + QKV GEMM, bf16 MFMA.
// q,k out: [(s*B+b)*HEADS+h][n][d] bf16 (q pre-scaled by QK_SCALE)
// v   out: [b*HEADS+h][d][n] bf16
__global__ __launch_bounds__(256) void qkv_gemm_kernel(
    const float* __restrict__ x, const float* __restrict__ partials,
    const float* __restrict__ norm_w, const float* __restrict__ norm_b,
    const float* __restrict__ qkv_w, const float* __restrict__ qkv_b,
    unsigned short* __restrict__ qkvb) {
    __shared__ unsigned short Ws[64][PSB];  // [o][c] bf16
    __shared__ unsigned short Xt[64][PSB];  // [n][c] bf16 (transposed xn)
    __shared__ float stat_s[GROUPS][2];
    const int n0 = blockIdx.x * 64;
    const int o0 = blockIdx.y * 64;
    const int b  = blockIdx.z;
    const int tid = threadIdx.x;
    const int lane = tid & 63, w = tid >> 6;
    const int lo = lane & 15, hi = lane >> 4;

    // finalize GroupNorm stats from partials (each block, redundantly; cheap)
    {
        const int g = tid >> 5, sub = tid & 31;
        const float* pp = partials + (((size_t)b * GROUPS + g) * 64 + sub * 2) * 2;
        float4 v = *(const float4*)pp;
        float s = v.x + v.z, ss = v.y + v.w;
#pragma unroll
        for (int off = 16; off > 0; off >>= 1) {
            s  += __shfl_down(s, off, 32);
            ss += __shfl_down(ss, off, 32);
        }
        if (sub == 0) {
            const float inv = 1.f / (float)(CPG * N_TOK);
            float mean = s * inv;
            float var  = ss * inv - mean * mean;
            stat_s[g][0] = mean;
            stat_s[g][1] = rsqrtf(var + EPS);
        }
        __syncthreads();
    }

    f32x4 acc[4] = {};
    for (int k0 = 0; k0 < C_DIM; k0 += 64) {
#pragma unroll
        for (int r = 0; r < 4; ++r) {
            int idx = tid + (r << 8);
            int row = idx >> 4, col4 = (idx & 15) << 2;
            float4 wv = *(const float4*)(qkv_w + (size_t)(o0 + row) * C_DIM + k0 + col4);
            u16x4v o;
            o[0] = f2bf(wv.x); o[1] = f2bf(wv.y); o[2] = f2bf(wv.z); o[3] = f2bf(wv.w);
            *(u16x4v*)&Ws[row][col4] = o;
        }
#pragma unroll
        for (int r = 0; r < 4; ++r) {
            int idx = tid + (r << 8);
            int crow = idx >> 4, col4 = (idx & 15) << 2;
            int c = k0 + crow;
            int g = c >> 5;
            float ww = norm_w[c] * stat_s[g][1];
            float bb = norm_b[c] - stat_s[g][0] * ww;
            float4 v = *(const float4*)(x + ((size_t)b * C_DIM + c) * N_TOK + n0 + col4);
            Xt[col4 + 0][crow] = f2bf(v.x * ww + bb);
            Xt[col4 + 1][crow] = f2bf(v.y * ww + bb);
            Xt[col4 + 2][crow] = f2bf(v.z * ww + bb);
            Xt[col4 + 3][crow] = f2bf(v.w * ww + bb);
        }
        __syncthreads();
#pragma unroll
        for (int ck = 0; ck < 2; ++ck) {
            bf16x8 aw = *(const bf16x8*)&Ws[w * 16 + lo][ck * 32 + hi * 8];
#pragma unroll
            for (int nb = 0; nb < 4; ++nb)
                acc[nb] = __builtin_amdgcn_mfma_f32_16x16x32_bf16(
                    aw, *(const bf16x8*)&Xt[nb * 16 + lo][ck * 32 + hi * 8], acc[nb], 0, 0, 0);
        }
        __syncthreads();
    }

    const int sidx = o0 >> 8;           // 0=q, 1=k, 2=v
    const int head = (o0 >> 6) & 3;
    const int od = w * 16 + hi * 4;     // d within head (+i)
    float bias[4];
#pragma unroll
    for (int i = 0; i < 4; ++i) bias[i] = qkv_b[o0 + od + i];
    const size_t plane = (size_t)N_TOK * HD;

    if (sidx < 2) {
        const float sc = (sidx == 0) ? QK_SCALE : 1.0f;
        unsigned short* base = qkvb + ((size_t)(sidx * B_DIM + b) * HEADS + head) * plane;
#pragma unroll
        for (int nb = 0; nb < 4; ++nb) {
            int n = n0 + nb * 16 + lo;
            u16x4v o;
#pragma unroll
            for (int i = 0; i < 4; ++i) o[i] = f2bf((acc[nb][i] + bias[i]) * sc);
            *(u16x4v*)(base + (size_t)n * HD + od) = o;
        }
    } else {
        unsigned short* base = qkvb + (size_t)2 * B_DIM * HEADS * plane
                             + ((size_t)b * HEADS + head) * plane;
#pragma unroll
        for (int nb = 0; nb < 4; ++nb)
#pragma unroll
            for (int i = 0; i < 4; ++i)
                base[(size_t)(od + i) * N_TOK + n0 + nb * 16 + lo] = f2bf(acc[nb][i] + bias[i]);
    }
}

// ---------------------------------------------------------------------------
// Kernel 3: bf16 MFMA flash attention, swapped-operand (S^T), K-split x4.
// 8 waves x 16 queries = QBLK 128; per-wave body identical to the verified
// round-7 structure. global_load_lds dbuf staging (linear dest, pre-swizzled
// source), 1 barrier/tile. 4 blocks/CU x 8 waves = 32 waves/CU.
__global__ __launch_bounds__(512, 8) void attn_kernel(const unsigned short* __restrict__ qkvb,
                                                      unsigned short* __restrict__ obuf,
                                                      float* __restrict__ rbuf) {
    const int bh = blockIdx.x & 7;            // b*HEADS + head
    const int ks = (blockIdx.x >> 3) & 3;     // key-split quarter
    const int q0 = (blockIdx.x >> 5) * QBLK;
    const size_t plane = (size_t)N_TOK * HD;
    const unsigned short* Qg  = qkvb + (size_t)bh * plane;
    const unsigned short* Kg  = qkvb + (size_t)(B_DIM * HEADS + bh) * plane;
    const unsigned short* Vtg = qkvb + (size_t)2 * B_DIM * HEADS * plane + (size_t)bh * plane;

    __shared__ unsigned short Ks[2][64][64];  // [buf][perm key row][d] (col-swizzled)
    __shared__ unsigned short Vt[2][64][64];  // [buf][d][key]          (col-swizzled)

    const int tid  = threadIdx.x;
    const int lane = tid & 63;
    const int wid  = tid >> 6;                // 0..7
    const int lo   = lane & 15;
    const int hi   = lane >> 4;

    // Q fragment (B-operand of S^T mfma): q = q0+wid*16+lo, d-chunks c*32+hi*8
    bf16x8 qf[2];
#pragma unroll
    for (int c = 0; c < 2; ++c)
        qf[c] = *(const bf16x8*)(Qg + (size_t)(q0 + wid * 16 + lo) * HD + c * 32 + hi * 8);

    // staging geometry: 512 threads cover the 64x64 tile in ONE K + ONE V DMA
    // per thread. thread -> row = tid>>3, 16B chunk = tid&7; source pre-swizzled.
    const int srow = tid >> 3, sblk = tid & 7;
    const int c16s = (sblk ^ (srow & 7)) * 8;
    const int krow = kperm(srow);
    // swizzled read column (elements) per d-chunk c: ((c*4+hi)^(lo&7))*8
    int rcol[2];
#pragma unroll
    for (int c = 0; c < 2; ++c) rcol[c] = (((c * 4 + hi) ^ (lo & 7)) << 3);

#define STAGE_KV(bufi, kbase)                                                          \
    do {                                                                               \
        gload16(Kg + (size_t)((kbase) + krow) * HD + c16s, &Ks[bufi][wid * 8][0]);     \
        gload16(Vtg + (size_t)srow * N_TOK + (kbase) + c16s, &Vt[bufi][wid * 8][0]);   \
    } while (0)

    const int kt0 = ks * (NKT / KSPLIT), ktE = kt0 + NKT / KSPLIT;

    f32x4 acc[4] = {};   // acc[db][i] = O^T[d = db*16+hi*4+i][q = q0+wid*16+lo]
    float m = -1e30f, l = 0.f;

    STAGE_KV(0, kt0 * 64);
    __syncthreads();   // drains the DMA (vmcnt 0) + barrier

    for (int kt = kt0; kt < ktE; ++kt) {
        const int cur = kt & 1;
        if (kt + 1 < ktE) STAGE_KV(cur ^ 1, (kt + 1) * 64);

        // S^T = K Q^T. s4[kb][i] = S^T[lds key row = kb*16+lo? -> key kb*16+hi*4+i][query lo]
        f32x4 s4[4] = {};
        __builtin_amdgcn_s_setprio(1);
#pragma unroll
        for (int kb = 0; kb < 4; ++kb)
#pragma unroll
            for (int c = 0; c < 2; ++c)
                s4[kb] = __builtin_amdgcn_mfma_f32_16x16x32_bf16(
                    *(const bf16x8*)&Ks[cur][kb * 16 + lo][rcol[c]], qf[c], s4[kb], 0, 0, 0);
        __builtin_amdgcn_s_setprio(0);

        // lane-local tile max (16 values); nested fmaxf fuses to v_max3
        float r0 = fmaxf(fmaxf(fmaxf(s4[0][0], s4[0][1]), s4[0][2]), s4[0][3]);
        float r1 = fmaxf(fmaxf(fmaxf(s4[1][0], s4[1][1]), s4[1][2]), s4[1][3]);
        float r2 = fmaxf(fmaxf(fmaxf(s4[2][0], s4[2][1]), s4[2][2]), s4[2][3]);
        float r3 = fmaxf(fmaxf(fmaxf(s4[3][0], s4[3][1]), s4[3][2]), s4[3][3]);
        float rm = fmaxf(fmaxf(fmaxf(r0, r1), r2), r3);

        // defer-max (T13) with LOCAL max check: cross-lane reduce only when needed.
        if (__any(rm > m + 8.0f)) {
            float rmx = rm;
            rmx = fmaxf(rmx, __shfl_xor(rmx, 16));
            rmx = fmaxf(rmx, __shfl_xor(rmx, 32));
            const float mn = fmaxf(m, rmx);
            const float fi = exp2_fast(m - mn);
            m = mn;
            l *= fi;
#pragma unroll
            for (int db = 0; db < 4; ++db)
#pragma unroll
                for (int i = 0; i < 4; ++i) acc[db][i] *= fi;
        }

        float p[4][4];
        float ps = 0.f;
#pragma unroll
        for (int kb = 0; kb < 4; ++kb)
#pragma unroll
            for (int i = 0; i < 4; ++i) {
                p[kb][i] = exp2_fast(s4[kb][i] - m);
                ps += p[kb][i];
            }
        l += ps;

        // pack P into PV B-fragment: pf[c][j] = p[2c + (j>>2)][j&3]
        bf16x8 pf[2];
#pragma unroll
        for (int c = 0; c < 2; ++c)
#pragma unroll
            for (int j = 0; j < 8; ++j) pf[c][j] = (__bf16)p[2 * c + (j >> 2)][j & 3];

        // O^T += V^T P^T
        __builtin_amdgcn_s_setprio(1);
#pragma unroll
        for (int db = 0; db < 4; ++db)
#pragma unroll
            for (int c = 0; c < 2; ++c)
                acc[db] = __builtin_amdgcn_mfma_f32_16x16x32_bf16(
                    *(const bf16x8*)&Vt[cur][db * 16 + lo][rcol[c]], pf[c], acc[db], 0, 0, 0);
        __builtin_amdgcn_s_setprio(0);

        // one barrier per tile: drains this wave's DMA (implicit vmcnt 0)
        // and guarantees all waves finished reading buf[cur].
        __syncthreads();
    }
#undef STAGE_KV

    // epilogue: normalized bf16 partial O + log-sum-exp r
    float l1 = l + __shfl_xor(l, 16);
    float lt = l1 + __shfl_xor(l1, 32);
    const float inv = 1.f / lt;
    const int n = q0 + wid * 16 + lo;
    unsigned short* ob = obuf + ((size_t)(ks * 8 + bh) * N_TOK + n) * HD;
#pragma unroll
    for (int db = 0; db < 4; ++db) {
        u16x4v o;
#pragma unroll
        for (int i = 0; i < 4; ++i) o[i] = f2bf(acc[db][i] * inv);
        *(u16x4v*)(ob + db * 16 + hi * 4) = o;
    }
    if (hi == 0)
        rbuf[(size_t)(ks * 8 + bh) * N_TOK + n] = m + __builtin_amdgcn_logf(lt);
}

// ---------------------------------------------------------------------------
// Kernel 4: output projection + bias + residual, bf16 MFMA.
// K-split combine fused into the h staging (reads obuf/rbuf directly).
__global__ __launch_bounds__(256) void proj_kernel(
    const unsigned short* __restrict__ obuf, const float* __restrict__ rbuf,
    const float* __restrict__ proj_w, const float* __restrict__ proj_b,
    const float* __restrict__ x, float* __restrict__ out) {
    __shared__ unsigned short Ws[64][PSB];  // [o][c]
    __shared__ unsigned short Hs[64][PSB];  // [n][c-within-head]
    const int n0 = blockIdx.x * 64;
    const int o0 = blockIdx.y * 64;
    const int b  = blockIdx.z;
    const int tid = threadIdx.x;
    const int lane = tid & 63, w = tid >> 6;
    const int lo = lane & 15, hi = lane >> 4;
    f32x4 acc[4] = {};

    for (int k0 = 0; k0 < C_DIM; k0 += 64) {
#pragma unroll
        for (int r = 0; r < 4; ++r) {
            int idx = tid + (r << 8);
            int row = idx >> 4, col4 = (idx & 15) << 2;
            float4 wv = *(const float4*)(proj_w + (size_t)(o0 + row) * C_DIM + k0 + col4);
            u16x4v o;
            o[0] = f2bf(wv.x); o[1] = f2bf(wv.y); o[2] = f2bf(wv.z); o[3] = f2bf(wv.w);
            *(u16x4v*)&Ws[row][col4] = o;
        }
        // stage h[n][k0..k0+64): head = k0>>6; combine the 4 K-split partials
        {
            const int head = k0 >> 6;
            const int bh = b * HEADS + head;
#pragma unroll
            for (int r = 0; r < 2; ++r) {
                int idx = tid + (r << 8);
                int row = idx >> 3, blk = idx & 7;   // n-row in tile, 8-d chunk
                int n = n0 + row;
                float rr[KSPLIT], M = -1e30f;
#pragma unroll
                for (int k = 0; k < KSPLIT; ++k) {
                    rr[k] = rbuf[(size_t)(k * 8 + bh) * N_TOK + n];
                    M = fmaxf(M, rr[k]);
                }
                float wk[KSPLIT], tot = 0.f;
#pragma unroll
                for (int k = 0; k < KSPLIT; ++k) { wk[k] = exp2_fast(rr[k] - M); tot += wk[k]; }
                const float inv = 1.f / tot;
                float a[8] = {};
#pragma unroll
                for (int k = 0; k < KSPLIT; ++k) {
                    u16x8v v = *(const u16x8v*)(obuf
                        + ((size_t)(k * 8 + bh) * N_TOK + n) * HD + blk * 8);
#pragma unroll
                    for (int j = 0; j < 8; ++j) a[j] += wk[k] * bf2f(v[j]);
                }
                u16x8v o;
#pragma unroll
                for (int j = 0; j < 8; ++j) o[j] = f2bf(a[j] * inv);
                *(u16x8v*)&Hs[row][blk * 8] = o;
            }
        }
        __syncthreads();
#pragma unroll
        for (int ck = 0; ck < 2; ++ck) {
            bf16x8 aw = *(const bf16x8*)&Ws[w * 16 + lo][ck * 32 + hi * 8];
#pragma unroll
            for (int nb = 0; nb < 4; ++nb)
                acc[nb] = __builtin_amdgcn_mfma_f32_16x16x32_bf16(
                    aw, *(const bf16x8*)&Hs[nb * 16 + lo][ck * 32 + hi * 8], acc[nb], 0, 0, 0);
        }
        __syncthreads();
    }

#pragma unroll
    for (int nb = 0; nb < 4; ++nb) {
#pragma unroll
        for (int i = 0; i < 4; ++i) {
            int o = o0 + w * 16 + hi * 4 + i;
            size_t addr = ((size_t)b * C_DIM + o) * N_TOK + n0 + nb * 16 + lo;
            out[addr] = acc[nb][i] + proj_b[o] + x[addr];
        }
    }
}

// ---------------------------------------------------------------------------
extern "C" void kernel_launch(void* const* d_in, const int* in_sizes, int n_in,
                              void* d_out, int out_size, void* d_ws, size_t ws_size,
                              hipStream_t stream) {
    const float* x      = (const float*)d_in[0];
    const float* norm_w = (const float*)d_in[1];
    const float* norm_b = (const float*)d_in[2];
    const float* qkv_w  = (const float*)d_in[3];
    const float* qkv_b  = (const float*)d_in[4];
    const float* proj_w = (const float*)d_in[5];
    const float* proj_b = (const float*)d_in[6];
    float* out = (float*)d_out;

    // ws: partials f32[2048] | qkvb bf16 (12.6MB)
    //   | obuf bf16 [4][8][N][HD] (16.8MB) | rbuf f32 [4][8][N] (512KB) ~= 29.9MB
    float* partials = (float*)d_ws;
    unsigned short* qkvb = (unsigned short*)(partials + 2048);
    unsigned short* obuf = qkvb + (size_t)3 * B_DIM * HEADS * N_TOK * HD;
    float* rbuf = (float*)(obuf + (size_t)KSPLIT * B_DIM * HEADS * N_TOK * HD);

    gn_part_kernel<<<B_DIM * GROUPS * 64, 256, 0, stream>>>(x, partials);
    qkv_gemm_kernel<<<dim3(N_TOK / 64, 3 * C_DIM / 64, B_DIM), 256, 0, stream>>>(
        x, partials, norm_w, norm_b, qkv_w, qkv_b, qkvb);
    attn_kernel<<<(N_TOK / QBLK) * B_DIM * HEADS * KSPLIT, 512, 0, stream>>>(qkvb, obuf, rbuf);
    proj_kernel<<<dim3(N_TOK / 64, C_DIM / 64, B_DIM), 256, 0, stream>>>(
        obuf, rbuf, proj_w, proj_b, x, out);
}

// Round 10
// 93.093 us; speedup vs baseline: 12.1020x; 1.0421x over previous
//
#include <hip/hip_runtime.h>
#include <math.h>

#define B_DIM 2
#define C_DIM 256
#define N_TOK 4096      // 16*16*16
#define HEADS 4
#define HD 64
#define GROUPS 8
#define CPG (C_DIM / GROUPS)   // 32
#define EPS 1e-5f
#define PSB 72          // padded bf16 LDS row stride (GEMM kernels)
#define QK_SCALE 0.180336880f  // 0.125 * log2(e), folded into Q
#define KSPLIT 4
#define NKT (N_TOK / 64)       // 64 key tiles total
#define QBLK 256               // queries per attention block (8 waves x 2 frags x 16 q)

typedef __bf16 bf16x8 __attribute__((ext_vector_type(8)));
typedef float  f32x4  __attribute__((ext_vector_type(4)));
typedef unsigned short u16x4v __attribute__((ext_vector_type(4)));
typedef unsigned short u16x8v __attribute__((ext_vector_type(8)));

__device__ __forceinline__ unsigned short f2bf(float f) {
    return __builtin_bit_cast(unsigned short, (__bf16)f);
}
__device__ __forceinline__ float bf2f(unsigned short u) {
    return (float)__builtin_bit_cast(__bf16, u);
}
// raw v_exp_f32 (2^x); inputs bounded so no OCML fixup needed
__device__ __forceinline__ float exp2_fast(float x) { return __builtin_amdgcn_exp2f(x); }

// async global->LDS, 16B per lane, wave-uniform LDS base (linear dest)
__device__ __forceinline__ void gload16(const unsigned short* g, unsigned short* l) {
    __builtin_amdgcn_global_load_lds(
        (const __attribute__((address_space(1))) unsigned int*)g,
        (__attribute__((address_space(3))) unsigned int*)l, 16, 0, 0);
}

// K-staging row permutation: [b5 b4 b3 b2 b1 b0] -> [b5 b3 b2 b4 b1 b0].
// Makes the S^T output registers exactly the PV B-fragment.
__device__ __forceinline__ int kperm(int r) {
    return (r & 0x23) | ((r & 0x0C) << 1) | ((r & 0x10) >> 2);
}

// ---------------------------------------------------------------------------
// Kernel 1: GroupNorm partial sums. 1024 blocks (16 groups x 64 chunks).
__global__ __launch_bounds__(256) void gn_part_kernel(const float* __restrict__ x,
                                                      float* __restrict__ partials) {
    const int bg = blockIdx.x >> 6, ch = blockIdx.x & 63;
    const float4* p = (const float4*)(x + (size_t)bg * CPG * N_TOK) + ch * 512;
    float s = 0.f, ss = 0.f;
#pragma unroll
    for (int r = 0; r < 2; ++r) {
        float4 v = p[threadIdx.x + (r << 8)];
        s  += v.x + v.y + v.z + v.w;
        ss += v.x * v.x + v.y * v.y + v.z * v.z + v.w * v.w;
    }
#pragma unroll
    for (int off = 32; off > 0; off >>= 1) {
        s  += __shfl_down(s, off);
        ss += __shfl_down(ss, off);
    }
    __shared__ float ls[4], lss[4];
    const int lane = threadIdx.x & 63, wid = threadIdx.x >> 6;
    if (lane == 0) { ls[wid] = s; lss[wid] = ss; }
    __syncthreads();
    if (threadIdx.x == 0) {
        partials[blockIdx.x * 2 + 0] = ls[0] + ls[1] + ls[2] + ls[3];
        partials[blockIdx.x * 2 + 1] = lss[0] + lss[1] + lss[2] + lss[3];
    }
}

// ---------------------------------------------------------------------------
// Kernel 2: fused GroupNorm finalize + apply + QKV GEMM, bf16 MFMA.
// q,k out: [(s*B+b)*HEADS+h][n][d] bf16 (q pre-scaled by QK_SCALE)
// v   out: [b*HEADS+h][d][n] bf16
__global__ __launch_bounds__(256) void qkv_gemm_kernel(
    const float* __restrict__ x, const float* __restrict__ partials,
    const float* __restrict__ norm_w, const float* __restrict__ norm_b,
    const float* __restrict__ qkv_w, const float* __restrict__ qkv_b,
    unsigned short* __restrict__ qkvb) {
    __shared__ unsigned short Ws[64][PSB];  // [o][c] bf16
    __shared__ unsigned short Xt[64][PSB];  // [n][c] bf16 (transposed xn)
    __shared__ float stat_s[GROUPS][2];
    const int n0 = blockIdx.x * 64;
    const int o0 = blockIdx.y * 64;
    const int b  = blockIdx.z;
    const int tid = threadIdx.x;
    const int lane = tid & 63, w = tid >> 6;
    const int lo = lane & 15, hi = lane >> 4;

    // finalize GroupNorm stats from partials (each block, redundantly; cheap)
    {
        const int g = tid >> 5, sub = tid & 31;
        const float* pp = partials + (((size_t)b * GROUPS + g) * 64 + sub * 2) * 2;
        float4 v = *(const float4*)pp;
        float s = v.x + v.z, ss = v.y + v.w;
#pragma unroll
        for (int off = 16; off > 0; off >>= 1) {
            s  += __shfl_down(s, off, 32);
            ss += __shfl_down(ss, off, 32);
        }
        if (sub == 0) {
            const float inv = 1.f / (float)(CPG * N_TOK);
            float mean = s * inv;
            float var  = ss * inv - mean * mean;
            stat_s[g][0] = mean;
            stat_s[g][1] = rsqrtf(var + EPS);
        }
        __syncthreads();
    }

    f32x4 acc[4] = {};
    for (int k0 = 0; k0 < C_DIM; k0 += 64) {
#pragma unroll
        for (int r = 0; r < 4; ++r) {
            int idx = tid + (r << 8);
            int row = idx >> 4, col4 = (idx & 15) << 2;
            float4 wv = *(const float4*)(qkv_w + (size_t)(o0 + row) * C_DIM + k0 + col4);
            u16x4v o;
            o[0] = f2bf(wv.x); o[1] = f2bf(wv.y); o[2] = f2bf(wv.z); o[3] = f2bf(wv.w);
            *(u16x4v*)&Ws[row][col4] = o;
        }
#pragma unroll
        for (int r = 0; r < 4; ++r) {
            int idx = tid + (r << 8);
            int crow = idx >> 4, col4 = (idx & 15) << 2;
            int c = k0 + crow;
            int g = c >> 5;
            float ww = norm_w[c] * stat_s[g][1];
            float bb = norm_b[c] - stat_s[g][0] * ww;
            float4 v = *(const float4*)(x + ((size_t)b * C_DIM + c) * N_TOK + n0 + col4);
            Xt[col4 + 0][crow] = f2bf(v.x * ww + bb);
            Xt[col4 + 1][crow] = f2bf(v.y * ww + bb);
            Xt[col4 + 2][crow] = f2bf(v.z * ww + bb);
            Xt[col4 + 3][crow] = f2bf(v.w * ww + bb);
        }
        __syncthreads();
#pragma unroll
        for (int ck = 0; ck < 2; ++ck) {
            bf16x8 aw = *(const bf16x8*)&Ws[w * 16 + lo][ck * 32 + hi * 8];
#pragma unroll
            for (int nb = 0; nb < 4; ++nb)
                acc[nb] = __builtin_amdgcn_mfma_f32_16x16x32_bf16(
                    aw, *(const bf16x8*)&Xt[nb * 16 + lo][ck * 32 + hi * 8], acc[nb], 0, 0, 0);
        }
        __syncthreads();
    }

    const int sidx = o0 >> 8;           // 0=q, 1=k, 2=v
    const int head = (o0 >> 6) & 3;
    const int od = w * 16 + hi * 4;     // d within head (+i)
    float bias[4];
#pragma unroll
    for (int i = 0; i < 4; ++i) bias[i] = qkv_b[o0 + od + i];
    const size_t plane = (size_t)N_TOK * HD;

    if (sidx < 2) {
        const float sc = (sidx == 0) ? QK_SCALE : 1.0f;
        unsigned short* base = qkvb + ((size_t)(sidx * B_DIM + b) * HEADS + head) * plane;
#pragma unroll
        for (int nb = 0; nb < 4; ++nb) {
            int n = n0 + nb * 16 + lo;
            u16x4v o;
#pragma unroll
            for (int i = 0; i < 4; ++i) o[i] = f2bf((acc[nb][i] + bias[i]) * sc);
            *(u16x4v*)(base + (size_t)n * HD + od) = o;
        }
    } else {
        unsigned short* base = qkvb + (size_t)2 * B_DIM * HEADS * plane
                             + ((size_t)b * HEADS + head) * plane;
#pragma unroll
        for (int nb = 0; nb < 4; ++nb)
#pragma unroll
            for (int i = 0; i < 4; ++i)
                base[(size_t)(od + i) * N_TOK + n0 + nb * 16 + lo] = f2bf(acc[nb][i] + bias[i]);
    }
}

// ---------------------------------------------------------------------------
// Kernel 3: bf16 MFMA flash attention, swapped-operand (S^T), K-split x4.
// 8 waves x 2 q-frags x 16 q = QBLK 256. K/V LDS fragments are read ONCE and
// feed both frags' MFMAs (halves LDS-read traffic vs 1-frag). global_load_lds
// dbuf staging (linear dest, pre-swizzled source), 1 barrier/tile.
__global__ __launch_bounds__(512, 4) void attn_kernel(const unsigned short* __restrict__ qkvb,
                                                      unsigned short* __restrict__ obuf,
                                                      float* __restrict__ rbuf) {
    const int bh = blockIdx.x & 7;            // b*HEADS + head
    const int ks = (blockIdx.x >> 3) & 3;     // key-split quarter
    const int q0 = (blockIdx.x >> 5) * QBLK;
    const size_t plane = (size_t)N_TOK * HD;
    const unsigned short* Qg  = qkvb + (size_t)bh * plane;
    const unsigned short* Kg  = qkvb + (size_t)(B_DIM * HEADS + bh) * plane;
    const unsigned short* Vtg = qkvb + (size_t)2 * B_DIM * HEADS * plane + (size_t)bh * plane;

    __shared__ unsigned short Ks[2][64][64];  // [buf][perm key row][d] (col-swizzled)
    __shared__ unsigned short Vt[2][64][64];  // [buf][d][key]          (col-swizzled)

    const int tid  = threadIdx.x;
    const int lane = tid & 63;
    const int wid  = tid >> 6;                // 0..7
    const int lo   = lane & 15;
    const int hi   = lane >> 4;

    // Q fragments: frag f covers q = q0 + wid*32 + f*16 + lo, d-chunks c*32+hi*8
    bf16x8 qf[2][2];
#pragma unroll
    for (int f = 0; f < 2; ++f)
#pragma unroll
        for (int c = 0; c < 2; ++c)
            qf[f][c] = *(const bf16x8*)(Qg + (size_t)(q0 + wid * 32 + f * 16 + lo) * HD
                                            + c * 32 + hi * 8);

    // staging geometry: 512 threads cover the 64x64 tile in ONE K + ONE V DMA
    // per thread. thread -> row = tid>>3, 16B chunk = tid&7; source pre-swizzled.
    const int srow = tid >> 3, sblk = tid & 7;
    const int c16s = (sblk ^ (srow & 7)) * 8;
    const int krow = kperm(srow);
    // swizzled read column (elements) per d-chunk c: ((c*4+hi)^(lo&7))*8
    int rcol[2];
#pragma unroll
    for (int c = 0; c < 2; ++c) rcol[c] = (((c * 4 + hi) ^ (lo & 7)) << 3);

#define STAGE_KV(bufi, kbase)                                                          \
    do {                                                                               \
        gload16(Kg + (size_t)((kbase) + krow) * HD + c16s, &Ks[bufi][wid * 8][0]);     \
        gload16(Vtg + (size_t)srow * N_TOK + (kbase) + c16s, &Vt[bufi][wid * 8][0]);   \
    } while (0)

    const int kt0 = ks * (NKT / KSPLIT), ktE = kt0 + NKT / KSPLIT;

    f32x4 acc[2][4] = {};   // acc[f][db][i] = O^T[d=db*16+hi*4+i][q of frag f]
    float m[2] = {-1e30f, -1e30f}, l[2] = {0.f, 0.f};

    STAGE_KV(0, kt0 * 64);
    __syncthreads();   // drains the DMA (vmcnt 0) + barrier

    for (int kt = kt0; kt < ktE; ++kt) {
        const int cur = kt & 1;
        if (kt + 1 < ktE) STAGE_KV(cur ^ 1, (kt + 1) * 64);

        // S^T = K Q^T for BOTH frags; each K fragment read once, used twice.
        f32x4 s4[2][4] = {};
        __builtin_amdgcn_s_setprio(1);
#pragma unroll
        for (int kb = 0; kb < 4; ++kb)
#pragma unroll
            for (int c = 0; c < 2; ++c) {
                bf16x8 kf = *(const bf16x8*)&Ks[cur][kb * 16 + lo][rcol[c]];
                s4[0][kb] = __builtin_amdgcn_mfma_f32_16x16x32_bf16(kf, qf[0][c], s4[0][kb], 0, 0, 0);
                s4[1][kb] = __builtin_amdgcn_mfma_f32_16x16x32_bf16(kf, qf[1][c], s4[1][kb], 0, 0, 0);
            }
        __builtin_amdgcn_s_setprio(0);

        // softmax per frag (lane-local; cross-lane only in rare rescale branch)
        bf16x8 pf[2][2];
#pragma unroll
        for (int f = 0; f < 2; ++f) {
            float r0 = fmaxf(fmaxf(fmaxf(s4[f][0][0], s4[f][0][1]), s4[f][0][2]), s4[f][0][3]);
            float r1 = fmaxf(fmaxf(fmaxf(s4[f][1][0], s4[f][1][1]), s4[f][1][2]), s4[f][1][3]);
            float r2 = fmaxf(fmaxf(fmaxf(s4[f][2][0], s4[f][2][1]), s4[f][2][2]), s4[f][2][3]);
            float r3 = fmaxf(fmaxf(fmaxf(s4[f][3][0], s4[f][3][1]), s4[f][3][2]), s4[f][3][3]);
            float rm = fmaxf(fmaxf(fmaxf(r0, r1), r2), r3);

            // defer-max (T13) with LOCAL max check
            if (__any(rm > m[f] + 8.0f)) {
                float rmx = rm;
                rmx = fmaxf(rmx, __shfl_xor(rmx, 16));
                rmx = fmaxf(rmx, __shfl_xor(rmx, 32));
                const float mn = fmaxf(m[f], rmx);
                const float fi = exp2_fast(m[f] - mn);
                m[f] = mn;
                l[f] *= fi;
#pragma unroll
                for (int db = 0; db < 4; ++db)
#pragma unroll
                    for (int i = 0; i < 4; ++i) acc[f][db][i] *= fi;
            }

            float p[4][4];
            float ps = 0.f;
#pragma unroll
            for (int kb = 0; kb < 4; ++kb)
#pragma unroll
                for (int i = 0; i < 4; ++i) {
                    p[kb][i] = exp2_fast(s4[f][kb][i] - m[f]);
                    ps += p[kb][i];
                }
            l[f] += ps;

            // pack P into PV B-fragment: pf[f][c][j] = p[2c + (j>>2)][j&3]
#pragma unroll
            for (int c = 0; c < 2; ++c)
#pragma unroll
                for (int j = 0; j < 8; ++j) pf[f][c][j] = (__bf16)p[2 * c + (j >> 2)][j & 3];
        }

        // O^T += V^T P^T for BOTH frags; each V fragment read once, used twice.
        __builtin_amdgcn_s_setprio(1);
#pragma unroll
        for (int db = 0; db < 4; ++db)
#pragma unroll
            for (int c = 0; c < 2; ++c) {
                bf16x8 vf = *(const bf16x8*)&Vt[cur][db * 16 + lo][rcol[c]];
                acc[0][db] = __builtin_amdgcn_mfma_f32_16x16x32_bf16(vf, pf[0][c], acc[0][db], 0, 0, 0);
                acc[1][db] = __builtin_amdgcn_mfma_f32_16x16x32_bf16(vf, pf[1][c], acc[1][db], 0, 0, 0);
            }
        __builtin_amdgcn_s_setprio(0);

        // one barrier per tile: drains this wave's DMA (implicit vmcnt 0)
        // and guarantees all waves finished reading buf[cur].
        __syncthreads();
    }
#undef STAGE_KV

    // epilogue per frag: normalized bf16 partial O + log-sum-exp r
#pragma unroll
    for (int f = 0; f < 2; ++f) {
        float l1 = l[f] + __shfl_xor(l[f], 16);
        float lt = l1 + __shfl_xor(l1, 32);
        const float inv = 1.f / lt;
        const int n = q0 + wid * 32 + f * 16 + lo;
        unsigned short* ob = obuf + ((size_t)(ks * 8 + bh) * N_TOK + n) * HD;
#pragma unroll
        for (int db = 0; db < 4; ++db) {
            u16x4v o;
#pragma unroll
            for (int i = 0; i < 4; ++i) o[i] = f2bf(acc[f][db][i] * inv);
            *(u16x4v*)(ob + db * 16 + hi * 4) = o;
        }
        if (hi == 0)
            rbuf[(size_t)(ks * 8 + bh) * N_TOK + n] = m[f] + __builtin_amdgcn_logf(lt);
    }
}

// ---------------------------------------------------------------------------
// Kernel 4: output projection + bias + residual, bf16 MFMA.
// K-split combine fused into the h staging (reads obuf/rbuf directly).
__global__ __launch_bounds__(256) void proj_kernel(
    const unsigned short* __restrict__ obuf, const float* __restrict__ rbuf,
    const float* __restrict__ proj_w, const float* __restrict__ proj_b,
    const float* __restrict__ x, float* __restrict__ out) {
    __shared__ unsigned short Ws[64][PSB];  // [o][c]
    __shared__ unsigned short Hs[64][PSB];  // [n][c-within-head]
    const int n0 = blockIdx.x * 64;
    const int o0 = blockIdx.y * 64;
    const int b  = blockIdx.z;
    const int tid = threadIdx.x;
    const int lane = tid & 63, w = tid >> 6;
    const int lo = lane & 15, hi = lane >> 4;
    f32x4 acc[4] = {};

    for (int k0 = 0; k0 < C_DIM; k0 += 64) {
#pragma unroll
        for (int r = 0; r < 4; ++r) {
            int idx = tid + (r << 8);
            int row = idx >> 4, col4 = (idx & 15) << 2;
            float4 wv = *(const float4*)(proj_w + (size_t)(o0 + row) * C_DIM + k0 + col4);
            u16x4v o;
            o[0] = f2bf(wv.x); o[1] = f2bf(wv.y); o[2] = f2bf(wv.z); o[3] = f2bf(wv.w);
            *(u16x4v*)&Ws[row][col4] = o;
        }
        // stage h[n][k0..k0+64): head = k0>>6; combine the 4 K-split partials
        {
            const int head = k0 >> 6;
            const int bh = b * HEADS + head;
#pragma unroll
            for (int r = 0; r < 2; ++r) {
                int idx = tid + (r << 8);
                int row = idx >> 3, blk = idx & 7;   // n-row in tile, 8-d chunk
                int n = n0 + row;
                float rr[KSPLIT], M = -1e30f;
#pragma unroll
                for (int k = 0; k < KSPLIT; ++k) {
                    rr[k] = rbuf[(size_t)(k * 8 + bh) * N_TOK + n];
                    M = fmaxf(M, rr[k]);
                }
                float wk[KSPLIT], tot = 0.f;
#pragma unroll
                for (int k = 0; k < KSPLIT; ++k) { wk[k] = exp2_fast(rr[k] - M); tot += wk[k]; }
                const float inv = 1.f / tot;
                float a[8] = {};
#pragma unroll
                for (int k = 0; k < KSPLIT; ++k) {
                    u16x8v v = *(const u16x8v*)(obuf
                        + ((size_t)(k * 8 + bh) * N_TOK + n) * HD + blk * 8);
#pragma unroll
                    for (int j = 0; j < 8; ++j) a[j] += wk[k] * bf2f(v[j]);
                }
                u16x8v o;
#pragma unroll
                for (int j = 0; j < 8; ++j) o[j] = f2bf(a[j] * inv);
                *(u16x8v*)&Hs[row][blk * 8] = o;
            }
        }
        __syncthreads();
#pragma unroll
        for (int ck = 0; ck < 2; ++ck) {
            bf16x8 aw = *(const bf16x8*)&Ws[w * 16 + lo][ck * 32 + hi * 8];
#pragma unroll
            for (int nb = 0; nb < 4; ++nb)
                acc[nb] = __builtin_amdgcn_mfma_f32_16x16x32_bf16(
                    aw, *(const bf16x8*)&Hs[nb * 16 + lo][ck * 32 + hi * 8], acc[nb], 0, 0, 0);
        }
        __syncthreads();
    }

#pragma unroll
    for (int nb = 0; nb < 4; ++nb) {
#pragma unroll
        for (int i = 0; i < 4; ++i) {
            int o = o0 + w * 16 + hi * 4 + i;
            size_t addr = ((size_t)b * C_DIM + o) * N_TOK + n0 + nb * 16 + lo;
            out[addr] = acc[nb][i] + proj_b[o] + x[addr];
        }
    }
}

// ---------------------------------------------------------------------------
extern "C" void kernel_launch(void* const* d_in, const int* in_sizes, int n_in,
                              void* d_out, int out_size, void* d_ws, size_t ws_size,
                              hipStream_t stream) {
    const float* x      = (const float*)d_in[0];
    const float* norm_w = (const float*)d_in[1];
    const float* norm_b = (const float*)d_in[2];
    const float* qkv_w  = (const float*)d_in[3];
    const float* qkv_b  = (const float*)d_in[4];
    const float* proj_w = (const float*)d_in[5];
    const float* proj_b = (const float*)d_in[6];
    float* out = (float*)d_out;

    // ws: partials f32[2048] | qkvb bf16 (12.6MB)
    //   | obuf bf16 [4][8][N][HD] (16.8MB) | rbuf f32 [4][8][N] (512KB) ~= 29.9MB
    float* partials = (float*)d_ws;
    unsigned short* qkvb = (unsigned short*)(partials + 2048);
    unsigned short* obuf = qkvb + (size_t)3 * B_DIM * HEADS * N_TOK * HD;
    float* rbuf = (float*)(obuf + (size_t)KSPLIT * B_DIM * HEADS * N_TOK * HD);

    gn_part_kernel<<<B_DIM * GROUPS * 64, 256, 0, stream>>>(x, partials);
    qkv_gemm_kernel<<<dim3(N_TOK / 64, 3 * C_DIM / 64, B_DIM), 256, 0, stream>>>(
        x, partials, norm_w, norm_b, qkv_w, qkv_b, qkvb);
    attn_kernel<<<(N_TOK / QBLK) * B_DIM * HEADS * KSPLIT, 512, 0, stream>>>(qkvb, obuf, rbuf);
    proj_kernel<<<dim3(N_TOK / 64, C_DIM / 64, B_DIM), 256, 0, stream>>>(
        obuf, rbuf, proj_w, proj_b, x, out);
}